// Round 5
// baseline (1755.169 us; speedup 1.0000x reference)
//
#include <hip/hip_runtime.h>
#include <hip/hip_bf16.h>
#include <cstdint>

#define B_    2
#define T_    1024
#define E_    1024
#define H_    16
#define HS_   64
#define L_    4
#define V_    32000
#define FF_   4096
#define BT_   2048
#define EPS_  1e-5f
#define SCALE_ 0.03125f   // 1/sqrt(E) = 1/32

typedef __bf16 bf16;
typedef bf16  bf16x4 __attribute__((ext_vector_type(4)));
typedef bf16  bf16x8 __attribute__((ext_vector_type(8)));
typedef float f32x4  __attribute__((ext_vector_type(4)));

#define GL2LDS(gp, lp) __builtin_amdgcn_global_load_lds( \
    (const __attribute__((address_space(1))) void*)(gp), \
    (__attribute__((address_space(3))) void*)(lp), 16, 0, 0)

// ---------------------------------------------------------------- embed
__global__ __launch_bounds__(256) void embed_kernel(
    const int* __restrict__ ids, const float* __restrict__ emb,
    const float* __restrict__ pos, float* __restrict__ x)
{
  int bt = blockIdx.x;
  int t  = bt & (T_ - 1);
  int id = ids[bt];
  f32x4 e = *(const f32x4*)(emb + (size_t)id * E_ + threadIdx.x * 4);
  f32x4 p = *(const f32x4*)(pos + (size_t)t  * E_ + threadIdx.x * 4);
  *(f32x4*)(x + (size_t)bt * E_ + threadIdx.x * 4) = e + p;
}

// ---------------------------------------------------------------- layernorm (f32 in, bf16 out)
__device__ __forceinline__ float wred_sum(float v) {
#pragma unroll
  for (int o = 32; o; o >>= 1) v += __shfl_xor(v, o, 64);
  return v;
}

__global__ __launch_bounds__(256) void ln_kernel(
    const float* __restrict__ x, const float* __restrict__ g,
    const float* __restrict__ b, bf16* __restrict__ h)
{
  int row = blockIdx.x, tid = threadIdx.x;
  f32x4 v = *(const f32x4*)(x + (size_t)row * E_ + tid * 4);
  float s  = v[0] + v[1] + v[2] + v[3];
  float sq = v[0]*v[0] + v[1]*v[1] + v[2]*v[2] + v[3]*v[3];
  s  = wred_sum(s);
  sq = wred_sum(sq);
  __shared__ float rs[4], rq[4];
  int w = tid >> 6, lane = tid & 63;
  if (lane == 0) { rs[w] = s; rq[w] = sq; }
  __syncthreads();
  float S = rs[0] + rs[1] + rs[2] + rs[3];
  float Q = rq[0] + rq[1] + rq[2] + rq[3];
  float mean = S * (1.0f / E_);
  float var  = Q * (1.0f / E_) - mean * mean;
  float rstd = rsqrtf(fmaxf(var, 0.0f) + EPS_);
  f32x4 gv = *(const f32x4*)(g + tid * 4);
  f32x4 bv = *(const f32x4*)(b + tid * 4);
  f32x4 o = (v - mean) * rstd * gv + bv;
  bf16x4 ob = { (bf16)o[0], (bf16)o[1], (bf16)o[2], (bf16)o[3] };
  *(bf16x4*)(h + (size_t)row * E_ + tid * 4) = ob;
}

// ---------------------------------------------------------------- weight transpose+convert
// W [K][N] f32 (row stride ldW) -> O [N][K] bf16   (used for proj weight)
__global__ __launch_bounds__(256) void convw_kernel(
    const float* __restrict__ W0, bf16* __restrict__ O0, int K, int ldW)
{
  __shared__ float tl[32][33];
  int n0 = blockIdx.x * 32, k0 = blockIdx.y * 32;
  int c = threadIdx.x & 31, r = threadIdx.x >> 5;
#pragma unroll
  for (int p = 0; p < 4; ++p)
    tl[r + p * 8][c] = W0[(size_t)(k0 + r + p * 8) * ldW + n0 + c];
  __syncthreads();
#pragma unroll
  for (int p = 0; p < 4; ++p)
    O0[(size_t)(n0 + r + p * 8) * K + k0 + c] = (bf16)tl[c][r + p * 8];
}

// ---------------------------------------------------------------- fused per-layer weight convert
// one launch converts wq,wk,wv (1024x1024), w1 (1024x4096), w2 (4096x1024)
// tiles: qkv 3*1024, w1 4096, w2 4096 -> 11264 blocks
__global__ __launch_bounds__(256) void convw_all(
    const float* __restrict__ wq, const float* __restrict__ wk,
    const float* __restrict__ wv, const float* __restrict__ w1,
    const float* __restrict__ w2,
    bf16* __restrict__ oq, bf16* __restrict__ ok, bf16* __restrict__ ov,
    bf16* __restrict__ o1, bf16* __restrict__ o2)
{
  int bid = blockIdx.x;
  const float* W; bf16* O; int K, ldW, nx, ny;
  if (bid < 3072) {
    int z = bid >> 10, rem = bid & 1023;
    W = (z == 0) ? wq : (z == 1) ? wk : wv;
    O = (z == 0) ? oq : (z == 1) ? ok : ov;
    K = 1024; ldW = 1024; nx = rem & 31; ny = rem >> 5;
  } else if (bid < 7168) {
    int idx = bid - 3072;
    W = w1; O = o1; K = 1024; ldW = 4096;
    nx = idx & 127; ny = idx >> 7;
  } else {
    int idx = bid - 7168;
    W = w2; O = o2; K = 4096; ldW = 1024;
    nx = idx & 31; ny = idx >> 5;
  }
  __shared__ float tl[32][33];
  int n0 = nx * 32, k0 = ny * 32;
  int c = threadIdx.x & 31, r = threadIdx.x >> 5;
#pragma unroll
  for (int p = 0; p < 4; ++p)
    tl[r + p * 8][c] = W[(size_t)(k0 + r + p * 8) * ldW + n0 + c];
  __syncthreads();
#pragma unroll
  for (int p = 0; p < 4; ++p)
    O[(size_t)(n0 + r + p * 8) * K + k0 + c] = (bf16)tl[c][r + p * 8];
}

// ---------------------------------------------------------------- GEMM bf16 MFMA 128x128 (m97-style)
// A [M][K] bf16, B [N][K] bf16. BK=32, global_load_lds staging with
// XOR-pre-swizzled global source, double-buffered LDS, barrier/K-step.
// bf16 out (+bias, optional exact GELU).
template <int ACT>
__global__ __launch_bounds__(256) void gemm_bf16(
    const bf16* __restrict__ A,
    const bf16* __restrict__ B0, const bf16* __restrict__ B1, const bf16* __restrict__ B2,
    const float* __restrict__ bi0, const float* __restrict__ bi1, const float* __restrict__ bi2,
    bf16* __restrict__ Cb0, bf16* __restrict__ Cb1, bf16* __restrict__ Cb2,
    int K, int ldc)
{
  int z = blockIdx.z;
  const bf16*  Bm = (z == 0) ? B0 : (z == 1) ? B1 : B2;
  const float* bi = (z == 0) ? bi0 : (z == 1) ? bi1 : bi2;
  bf16*        Cb = (z == 0) ? Cb0 : (z == 1) ? Cb1 : Cb2;

  // chunked XCD swizzle
  int nb  = (int)(gridDim.x * gridDim.y);      // multiple of 8
  int lin = blockIdx.x + gridDim.x * blockIdx.y;
  int per = nb >> 3;
  int b   = (lin & 7) * per + (lin >> 3);
  int mi  = b & 15;            // gridDim.x == 16 always
  int ni  = b >> 4;

  __shared__ __align__(16) char lds[2][16384];  // [buf][A 8KB | B 8KB]

  int tid = threadIdx.x;
  int lane = tid & 63, wid = tid >> 6;
  int wm = (wid >> 1) * 64, wn = (wid & 1) * 64;
  int fr = lane & 15, fb = lane >> 4;

  const bf16* Asrc = A  + (size_t)(mi * 128) * K;
  const bf16* Bsrc = Bm + (size_t)(ni * 128) * K;

  int NT = K >> 5;

#define STAGE(buf, kk)                                                          \
  {                                                                             \
    _Pragma("unroll")                                                           \
    for (int is = 0; is < 2; ++is) {                                            \
      int rl = is * 64 + (tid >> 2);                                            \
      int key = (rl >> 1) & 3;                                                  \
      int ck  = ((tid & 3) ^ key) * 8;                                          \
      GL2LDS(Asrc + (size_t)rl * K + (kk) + ck,                                 \
             lds[buf] + is * 4096 + tid * 16);                                  \
      GL2LDS(Bsrc + (size_t)rl * K + (kk) + ck,                                 \
             lds[buf] + 8192 + is * 4096 + tid * 16);                           \
    }                                                                           \
  }

  f32x4 acc[4][4];
#pragma unroll
  for (int i = 0; i < 4; ++i)
#pragma unroll
    for (int j = 0; j < 4; ++j) acc[i][j] = (f32x4){0.f, 0.f, 0.f, 0.f};

  STAGE(0, 0);
  int cur = 0;

  for (int t = 0; t < NT; ++t) {
    __syncthreads();                       // drains vmcnt -> buf[cur] ready
    if (t + 1 < NT) STAGE(cur ^ 1, (t + 1) << 5);

    const char* Ab = lds[cur];
    const char* Bb = lds[cur] + 8192;
    bf16x8 af[4], bfr[4];
#pragma unroll
    for (int i = 0; i < 4; ++i) {
      int rl = wm + i * 16 + fr;
      af[i] = *(const bf16x8*)(Ab + rl * 64 + ((fb ^ ((rl >> 1) & 3)) * 16));
    }
#pragma unroll
    for (int j = 0; j < 4; ++j) {
      int rl = wn + j * 16 + fr;
      bfr[j] = *(const bf16x8*)(Bb + rl * 64 + ((fb ^ ((rl >> 1) & 3)) * 16));
    }
#pragma unroll
    for (int i = 0; i < 4; ++i)
#pragma unroll
      for (int j = 0; j < 4; ++j)
        acc[i][j] = __builtin_amdgcn_mfma_f32_16x16x32_bf16(af[i], bfr[j], acc[i][j], 0, 0, 0);
    cur ^= 1;
  }
#undef STAGE

  // epilogue: C/D layout col = lane&15, row = (lane>>4)*4 + reg
#pragma unroll
  for (int i = 0; i < 4; ++i) {
#pragma unroll
    for (int j = 0; j < 4; ++j) {
      int gc = ni * 128 + wn + j * 16 + fr;
      float bv = bi[gc];
#pragma unroll
      for (int r = 0; r < 4; ++r) {
        int gr = mi * 128 + wm + i * 16 + fb * 4 + r;
        float vv = acc[i][j][r] + bv;
        if (ACT == 1) vv = 0.5f * vv * (1.0f + erff(vv * 0.70710678118654752f));
        Cb[(size_t)gr * ldc + gc] = (bf16)vv;
      }
    }
  }
}

// ---------------------------------------------------------------- FFN2 GEMM 128x64, BK=32
// A [M][4096] bf16 (ff), B [1024][4096] bf16 (w2t). 256 blocks (16M x 16N),
// epilogue fuses bias + residual(x) -> x (f32) and xb (bf16).
__global__ __launch_bounds__(256) void ffn2_kernel(
    const bf16* __restrict__ A, const bf16* __restrict__ Bm,
    const float* __restrict__ bi, float* __restrict__ x,
    bf16* __restrict__ xb, int K)
{
  int nb  = (int)(gridDim.x * gridDim.y);      // 256
  int lin = blockIdx.x + gridDim.x * blockIdx.y;
  int per = nb >> 3;
  int b   = (lin & 7) * per + (lin >> 3);
  int mi  = b & 15, ni = b >> 4;

  __shared__ __align__(16) char lds[2][12288];  // [buf][A 8KB | B 4KB]

  int tid = threadIdx.x;
  int lane = tid & 63, wid = tid >> 6;
  int wm = (wid >> 1) * 64, wn = (wid & 1) * 32;
  int fr = lane & 15, fb = lane >> 4;

  const bf16* Asrc = A  + (size_t)(mi * 128) * K;
  const bf16* Bsrc = Bm + (size_t)(ni * 64) * K;

  int NT = K >> 5;   // 128

#define STAGEF(buf, kk)                                                         \
  {                                                                             \
    _Pragma("unroll")                                                           \
    for (int is = 0; is < 2; ++is) {                                            \
      int c   = is * 256 + tid;                                                 \
      int row = c >> 2;                                                         \
      int ck  = ((c & 3) ^ ((row >> 1) & 3)) * 8;                               \
      GL2LDS(Asrc + (size_t)row * K + (kk) + ck, lds[buf] + c * 16);            \
    }                                                                           \
    {                                                                           \
      int c   = tid;                                                            \
      int row = c >> 2;                                                         \
      int ck  = ((c & 3) ^ ((row >> 1) & 3)) * 8;                               \
      GL2LDS(Bsrc + (size_t)row * K + (kk) + ck, lds[buf] + 8192 + c * 16);     \
    }                                                                           \
  }

  f32x4 acc[4][2];
#pragma unroll
  for (int i = 0; i < 4; ++i)
#pragma unroll
    for (int j = 0; j < 2; ++j) acc[i][j] = (f32x4){0.f, 0.f, 0.f, 0.f};

  STAGEF(0, 0);
  int cur = 0;

  for (int t = 0; t < NT; ++t) {
    __syncthreads();
    if (t + 1 < NT) STAGEF(cur ^ 1, (t + 1) << 5);

    const char* Ab = lds[cur];
    const char* Bb = lds[cur] + 8192;
    bf16x8 af[4], bfr[2];
#pragma unroll
    for (int i = 0; i < 4; ++i) {
      int rl = wm + i * 16 + fr;
      af[i] = *(const bf16x8*)(Ab + rl * 64 + ((fb ^ ((rl >> 1) & 3)) * 16));
    }
#pragma unroll
    for (int j = 0; j < 2; ++j) {
      int rl = wn + j * 16 + fr;
      bfr[j] = *(const bf16x8*)(Bb + rl * 64 + ((fb ^ ((rl >> 1) & 3)) * 16));
    }
#pragma unroll
    for (int i = 0; i < 4; ++i)
#pragma unroll
      for (int j = 0; j < 2; ++j)
        acc[i][j] = __builtin_amdgcn_mfma_f32_16x16x32_bf16(af[i], bfr[j], acc[i][j], 0, 0, 0);
    cur ^= 1;
  }
#undef STAGEF

#pragma unroll
  for (int i = 0; i < 4; ++i) {
#pragma unroll
    for (int j = 0; j < 2; ++j) {
      int gc = ni * 64 + wn + j * 16 + fr;
      float bv = bi[gc];
#pragma unroll
      for (int r = 0; r < 4; ++r) {
        int gr = mi * 128 + wm + i * 16 + fb * 4 + r;
        size_t off = (size_t)gr * E_ + gc;
        float nv = acc[i][j][r] + bv + x[off];
        x[off]  = nv;
        xb[off] = (bf16)nv;
      }
    }
  }
}

// ---------------------------------------------------------------- GEMM bf16 MFMA 256x256, BK=32
// 512 thr (8 waves, 2Mx4N). LDS 64 KiB (2 buf x (A 16KB | B 16KB)) ->
// 2 blocks/CU co-resident: one block's staging/epilogue overlaps the
// other's MFMA (TLP pipelining). Counted vmcnt(4) keeps next-tile loads
// in flight across the barrier. Swizzle involution chunk^=(row>>1)&3.
__global__ __launch_bounds__(512, 4) void gemm256_kernel(
    const bf16* __restrict__ A, const bf16* __restrict__ Bm,
    const float* __restrict__ bi, float* __restrict__ C, int K, int N)
{
  int nwg = (int)gridDim.x;
  int per = nwg >> 3;
  int bid = (int)blockIdx.x;
  int tl  = (bid & 7) * per + (bid >> 3);   // chunked XCD swizzle (nwg%8==0)
  int mi  = tl & 7, ni = tl >> 3;           // M=2048 -> 8 M-blocks, mi fastest

  __shared__ __align__(16) char lds[2][32768];

  int tid = threadIdx.x;
  int lane = tid & 63, wid = tid >> 6;
  int wr = wid >> 2, wc = wid & 3;          // 2 x 4 waves
  int fr = lane & 15, fb = lane >> 4;

  const bf16* Asrc = A  + (size_t)(mi * 256) * K;
  const bf16* Bsrc = Bm + (size_t)(ni * 256) * K;

  int NT = K >> 5;

#define STAGE256(buf, kk)                                                  \
  { _Pragma("unroll")                                                      \
    for (int is = 0; is < 2; ++is) {                                       \
      int c   = is * 512 + tid;                                            \
      int row = c >> 2;                                                    \
      int ck  = ((c & 3) ^ ((row >> 1) & 3)) * 8;                          \
      GL2LDS(Asrc + (size_t)row * K + (kk) + ck,                           \
             lds[buf] + c * 16);                                           \
      GL2LDS(Bsrc + (size_t)row * K + (kk) + ck,                           \
             lds[buf] + 16384 + c * 16);                                   \
    } }

  f32x4 acc[8][4];
#pragma unroll
  for (int i = 0; i < 8; ++i)
#pragma unroll
    for (int j = 0; j < 4; ++j) acc[i][j] = (f32x4){0.f, 0.f, 0.f, 0.f};

  STAGE256(0, 0);

  for (int t = 0; t < NT; ++t) {
    int buf = t & 1;
    if (t + 1 < NT) {
      STAGE256(buf ^ 1, (t + 1) << 5);
      asm volatile("s_waitcnt vmcnt(4)" ::: "memory");   // tile t landed; t+1 in flight
    } else {
      asm volatile("s_waitcnt vmcnt(0)" ::: "memory");
    }
    __builtin_amdgcn_s_barrier();
    asm volatile("" ::: "memory");

    const char* Ab = lds[buf];
    const char* Bb = lds[buf] + 16384;

    bf16x8 bfr[4];
#pragma unroll
    for (int n2 = 0; n2 < 4; ++n2) {
      int row = wc * 64 + n2 * 16 + fr;
      bfr[n2] = *(const bf16x8*)(Bb + row * 64 + ((fb ^ ((row >> 1) & 3)) << 4));
    }
#pragma unroll
    for (int q = 0; q < 4; ++q) {
      bf16x8 af[2];
#pragma unroll
      for (int m2 = 0; m2 < 2; ++m2) {
        int row = wr * 128 + (q * 2 + m2) * 16 + fr;
        af[m2] = *(const bf16x8*)(Ab + row * 64 + ((fb ^ ((row >> 1) & 3)) << 4));
      }
      __builtin_amdgcn_s_setprio(1);
#pragma unroll
      for (int m2 = 0; m2 < 2; ++m2)
#pragma unroll
        for (int n2 = 0; n2 < 4; ++n2)
          acc[q * 2 + m2][n2] = __builtin_amdgcn_mfma_f32_16x16x32_bf16(
              af[m2], bfr[n2], acc[q * 2 + m2][n2], 0, 0, 0);
      __builtin_amdgcn_s_setprio(0);
    }
    asm volatile("" ::: "memory");
    __builtin_amdgcn_s_barrier();            // reads done before next stage overwrites
  }
#undef STAGE256

#pragma unroll
  for (int i = 0; i < 8; ++i) {
#pragma unroll
    for (int j = 0; j < 4; ++j) {
      int gc = ni * 256 + wc * 64 + j * 16 + fr;
      float bv = bi[gc];
#pragma unroll
      for (int r = 0; r < 4; ++r) {
        int gr = mi * 256 + wr * 128 + i * 16 + fb * 4 + r;
        C[(size_t)gr * N + gc] = acc[i][j][r] + bv;
      }
    }
  }
}

// ---------------------------------------------------------------- attention (bf16 MFMA flash)
__global__ __launch_bounds__(256) void attn_kernel(
    const bf16* __restrict__ q, const bf16* __restrict__ k,
    const bf16* __restrict__ v, float* __restrict__ x)
{
  __shared__ __align__(16) char Ks[8192];
  __shared__ __align__(16) char Vs[8192];
  __shared__ __align__(16) char Ps[8192];

  int tid = threadIdx.x, lane = tid & 63, w = tid >> 6;
  int qt = blockIdx.x, bh = blockIdx.y;
  int b = bh >> 4, h = bh & 15;
  size_t hoff = (size_t)b * T_ * E_ + h * HS_;
  int fr = lane & 15, fb = lane >> 4;

  bf16x8 qa[2];
  {
    const bf16* qp = q + hoff + (size_t)(qt * 64 + w * 16 + fr) * E_ + fb * 8;
    qa[0] = *(const bf16x8*)qp;
    qa[1] = *(const bf16x8*)(qp + 32);
  }

  f32x4 O[4];
  float m_[4], l_[4];
#pragma unroll
  for (int i = 0; i < 4; ++i) { O[i] = (f32x4){0.f,0.f,0.f,0.f}; m_[i] = -1e30f; l_[i] = 0.f; }

  for (int kt = 0; kt <= qt; ++kt) {
    __syncthreads();
    {
      const bf16* kbase = k + hoff + (size_t)(kt * 64) * E_;
#pragma unroll
      for (int is = 0; is < 2; ++is) {
        int c = is * 32 + (tid >> 3);
        int key = ((c & 7) ^ (c >> 3)) & 7;
        GL2LDS(kbase + (size_t)c * E_ + (((tid & 7) ^ key) * 8),
               Ks + is * 4096 + tid * 16);
      }
    }
#pragma unroll
    for (int p = 0; p < 2; ++p) {
      int row = tid >> 2;
      int d0 = (tid & 3) * 8 + p * 32;
      bf16x8 vv = *(const bf16x8*)(v + hoff + (size_t)(kt * 64 + row) * E_ + d0);
#pragma unroll
      for (int e = 0; e < 8; ++e) {
        int d = d0 + e;
        int key = ((d & 7) ^ (d >> 3)) & 7;
        *(bf16*)(Vs + d * 128 + ((row * 2) ^ (key << 4))) = vv[e];
      }
    }
    __syncthreads();

    f32x4 s[4];
#pragma unroll
    for (int jc = 0; jc < 4; ++jc) {
      s[jc] = (f32x4){0.f, 0.f, 0.f, 0.f};
#pragma unroll
      for (int kc = 0; kc < 2; ++kc) {
        int c = jc * 16 + fr;
        int key = ((c & 7) ^ (c >> 3)) & 7;
        bf16x8 kf = *(const bf16x8*)(Ks + c * 128 + ((kc * 64 + fb * 16) ^ (key << 4)));
        s[jc] = __builtin_amdgcn_mfma_f32_16x16x32_bf16(qa[kc], kf, s[jc], 0, 0, 0);
      }
    }

    char* pbase = Ps + w * 2048;
#pragma unroll
    for (int r = 0; r < 4; ++r) {
      float s0 = s[0][r] * SCALE_, s1 = s[1][r] * SCALE_;
      float s2 = s[2][r] * SCALE_, s3 = s[3][r] * SCALE_;
      int qrow = qt * 64 + w * 16 + fb * 4 + r;
      if (kt == qt) {
        int kc0 = kt * 64 + fr;
        if (kc0      > qrow) s0 = -1e30f;
        if (kc0 + 16 > qrow) s1 = -1e30f;
        if (kc0 + 32 > qrow) s2 = -1e30f;
        if (kc0 + 48 > qrow) s3 = -1e30f;
      }
      float mx = fmaxf(fmaxf(s0, s1), fmaxf(s2, s3));
      mx = fmaxf(mx, __shfl_xor(mx, 1, 16));
      mx = fmaxf(mx, __shfl_xor(mx, 2, 16));
      mx = fmaxf(mx, __shfl_xor(mx, 4, 16));
      mx = fmaxf(mx, __shfl_xor(mx, 8, 16));
      float mnew = fmaxf(m_[r], mx);
      float p0 = __expf(s0 - mnew), p1 = __expf(s1 - mnew);
      float p2 = __expf(s2 - mnew), p3 = __expf(s3 - mnew);
      float rs = p0 + p1 + p2 + p3;
      rs += __shfl_xor(rs, 1, 16);
      rs += __shfl_xor(rs, 2, 16);
      rs += __shfl_xor(rs, 4, 16);
      rs += __shfl_xor(rs, 8, 16);
      float scl = __expf(m_[r] - mnew);
      l_[r] = l_[r] * scl + rs;
      m_[r] = mnew;
#pragma unroll
      for (int jd = 0; jd < 4; ++jd) O[jd][r] *= scl;
      int key2 = (r << 4) ^ (fb << 5);
      char* pr_ = pbase + (fb * 4 + r) * 128;
      *(bf16*)(pr_ + (( 0 + fr * 2) ^ key2)) = (bf16)p0;
      *(bf16*)(pr_ + ((32 + fr * 2) ^ key2)) = (bf16)p1;
      *(bf16*)(pr_ + ((64 + fr * 2) ^ key2)) = (bf16)p2;
      *(bf16*)(pr_ + ((96 + fr * 2) ^ key2)) = (bf16)p3;
    }

#pragma unroll
    for (int kc = 0; kc < 2; ++kc) {
      int key2 = ((fr & 3) << 4) ^ ((fr >> 2) << 5);
      bf16x8 pa = *(const bf16x8*)(pbase + fr * 128 + ((kc * 64 + fb * 16) ^ key2));
#pragma unroll
      for (int jd = 0; jd < 4; ++jd) {
        int d = jd * 16 + fr;
        int key = ((d & 7) ^ (d >> 3)) & 7;
        bf16x8 vf = *(const bf16x8*)(Vs + d * 128 + ((kc * 64 + fb * 16) ^ (key << 4)));
        O[jd] = __builtin_amdgcn_mfma_f32_16x16x32_bf16(pa, vf, O[jd], 0, 0, 0);
      }
    }
  }

#pragma unroll
  for (int r = 0; r < 4; ++r) {
    float inv = 1.0f / l_[r];
    float* xp = x + hoff + (size_t)(qt * 64 + w * 16 + fb * 4 + r) * E_;
#pragma unroll
    for (int jd = 0; jd < 4; ++jd) {
      int d = jd * 16 + fr;
      xp[d] += O[jd][r] * inv;
    }
  }
}

// ---------------------------------------------------------------- launch
extern "C" void kernel_launch(void* const* d_in, const int* in_sizes, int n_in,
                              void* d_out, int out_size, void* d_ws, size_t ws_size,
                              hipStream_t stream)
{
  const int*   ids  = (const int*)  d_in[0];
  const float* emb  = (const float*)d_in[1];
  const float* pos  = (const float*)d_in[2];
  const float* wq   = (const float*)d_in[3];
  const float* bq   = (const float*)d_in[4];
  const float* wk   = (const float*)d_in[5];
  const float* bk   = (const float*)d_in[6];
  const float* wv   = (const float*)d_in[7];
  const float* bv   = (const float*)d_in[8];
  const float* w1   = (const float*)d_in[9];
  const float* b1   = (const float*)d_in[10];
  const float* w2   = (const float*)d_in[11];
  const float* b2   = (const float*)d_in[12];
  const float* ln1g = (const float*)d_in[13];
  const float* ln1b = (const float*)d_in[14];
  const float* ln2g = (const float*)d_in[15];
  const float* ln2b = (const float*)d_in[16];
  const float* pw   = (const float*)d_in[17];
  const float* pb   = (const float*)d_in[18];
  float* out = (float*)d_out;

  // ws layout (f32 units), non-overlapping in time:
  //   x   [ 0M,  2M)  f32  BTxE
  //   hb  [ 2M,  3M)  bf16 BTxE
  //   qb  [ 3M,  4M)  bf16 BTxE
  //   kb  [ 4M,  5M)  bf16 BTxE
  //   vb  [ 5M,  6M)  bf16 BTxE
  //   ffb [ 6M, 10M)  bf16 BTxFF
  //   lwb [10M,15.5M) bf16 layer weights (qkv 0.5M f32 each, w1/w2 2M f32)
  //   xb  [16M, 17M)  bf16 BTxE
  //   pwb [ 0M,15.625M) bf16 proj weight 32000x1024 (65.536 MB < xb@64 MiB;
  //                    x/hb/.../lwb all dead at projection time)
  // peak = 17M f32 = 68 MiB (round 1 proved ws >= 72 MiB)
  if (ws_size < (size_t)17 * 1024 * 1024 * 4) return;
  float* ws = (float*)d_ws;
  float* x   = ws;
  bf16*  hb  = (bf16*)(ws + (size_t) 2 * 1024 * 1024);
  bf16*  qb  = (bf16*)(ws + (size_t) 3 * 1024 * 1024);
  bf16*  kb  = (bf16*)(ws + (size_t) 4 * 1024 * 1024);
  bf16*  vb  = (bf16*)(ws + (size_t) 5 * 1024 * 1024);
  bf16*  ffb = (bf16*)(ws + (size_t) 6 * 1024 * 1024);
  bf16*  lwb = (bf16*)(ws + (size_t)10 * 1024 * 1024);
  bf16*  xb  = (bf16*)(ws + (size_t)16 * 1024 * 1024);
  bf16*  pwb = (bf16*)ws;
  bf16*  wqt = lwb;
  bf16*  wkt = lwb + (size_t)1 * 1024 * 1024;
  bf16*  wvt = lwb + (size_t)2 * 1024 * 1024;
  bf16*  w1t = lwb + (size_t)3 * 1024 * 1024;
  bf16*  w2t = lwb + (size_t)7 * 1024 * 1024;

  embed_kernel<<<BT_, 256, 0, stream>>>(ids, emb, pos, x);

  for (int l = 0; l < L_; ++l) {
    const size_t lEE = (size_t)l * E_ * E_;
    const size_t lEF = (size_t)l * E_ * FF_;

    convw_all<<<11264, 256, 0, stream>>>(
        wq + lEE, wk + lEE, wv + lEE, w1 + lEF, w2 + lEF,
        wqt, wkt, wvt, w1t, w2t);

    ln_kernel<<<BT_, 256, 0, stream>>>(x, ln1g + l*E_, ln1b + l*E_, hb);

    gemm_bf16<0><<<dim3(16, E_/128, 3), 256, 0, stream>>>(
        hb, wqt, wkt, wvt, bq + l*E_, bk + l*E_, bv + l*E_,
        qb, kb, vb, E_, E_);

    attn_kernel<<<dim3(T_/64, B_*H_), 256, 0, stream>>>(qb, kb, vb, x);

    ln_kernel<<<BT_, 256, 0, stream>>>(x, ln2g + l*E_, ln2b + l*E_, hb);

    gemm_bf16<1><<<dim3(16, FF_/128, 1), 256, 0, stream>>>(
        hb, w1t, nullptr, nullptr, b1 + (size_t)l*FF_, nullptr, nullptr,
        ffb, nullptr, nullptr, E_, FF_);

    // FFN2: 128x64 tiles -> 256 blocks, bias+residual+bf16 fused
    ffn2_kernel<<<dim3(16, 16), 256, 0, stream>>>(
        ffb, w2t, b2 + l*E_, x, xb, FF_);
  }

  // final projection: whole weight converted, 256^2 BK=32 2-block/CU GEMM
  convw_kernel<<<dim3(V_/32, E_/32), 256, 0, stream>>>(pw, pwb, E_, V_);
  gemm256_kernel<<<(V_/256) * 8, 512, 0, stream>>>(
      xb, pwb, pb, out, E_, V_);
}

// Round 6
// 923.058 us; speedup vs baseline: 1.9015x; 1.9015x over previous
//
#include <hip/hip_runtime.h>
#include <hip/hip_bf16.h>
#include <cstdint>

#define B_    2
#define T_    1024
#define E_    1024
#define H_    16
#define HS_   64
#define L_    4
#define V_    32000
#define FF_   4096
#define BT_   2048
#define QKV_  3072
#define EPS_  1e-5f
#define SCALE_ 0.03125f   // 1/sqrt(E) = 1/32

typedef __bf16 bf16;
typedef bf16  bf16x4 __attribute__((ext_vector_type(4)));
typedef bf16  bf16x8 __attribute__((ext_vector_type(8)));
typedef float f32x4  __attribute__((ext_vector_type(4)));

#define GL2LDS(gp, lp) __builtin_amdgcn_global_load_lds( \
    (const __attribute__((address_space(1))) void*)(gp), \
    (__attribute__((address_space(3))) void*)(lp), 16, 0, 0)

// ---------------------------------------------------------------- embed
__global__ __launch_bounds__(256) void embed_kernel(
    const int* __restrict__ ids, const float* __restrict__ emb,
    const float* __restrict__ pos, float* __restrict__ x)
{
  int bt = blockIdx.x;
  int t  = bt & (T_ - 1);
  int id = ids[bt];
  f32x4 e = *(const f32x4*)(emb + (size_t)id * E_ + threadIdx.x * 4);
  f32x4 p = *(const f32x4*)(pos + (size_t)t  * E_ + threadIdx.x * 4);
  *(f32x4*)(x + (size_t)bt * E_ + threadIdx.x * 4) = e + p;
}

// ---------------------------------------------------------------- layernorm (f32 in, bf16 out)
__device__ __forceinline__ float wred_sum(float v) {
#pragma unroll
  for (int o = 32; o; o >>= 1) v += __shfl_xor(v, o, 64);
  return v;
}

__global__ __launch_bounds__(256) void ln_kernel(
    const float* __restrict__ x, const float* __restrict__ g,
    const float* __restrict__ b, bf16* __restrict__ h)
{
  int row = blockIdx.x, tid = threadIdx.x;
  f32x4 v = *(const f32x4*)(x + (size_t)row * E_ + tid * 4);
  float s  = v[0] + v[1] + v[2] + v[3];
  float sq = v[0]*v[0] + v[1]*v[1] + v[2]*v[2] + v[3]*v[3];
  s  = wred_sum(s);
  sq = wred_sum(sq);
  __shared__ float rs[4], rq[4];
  int w = tid >> 6, lane = tid & 63;
  if (lane == 0) { rs[w] = s; rq[w] = sq; }
  __syncthreads();
  float S = rs[0] + rs[1] + rs[2] + rs[3];
  float Q = rq[0] + rq[1] + rq[2] + rq[3];
  float mean = S * (1.0f / E_);
  float var  = Q * (1.0f / E_) - mean * mean;
  float rstd = rsqrtf(fmaxf(var, 0.0f) + EPS_);
  f32x4 gv = *(const f32x4*)(g + tid * 4);
  f32x4 bv = *(const f32x4*)(b + tid * 4);
  f32x4 o = (v - mean) * rstd * gv + bv;
  bf16x4 ob = { (bf16)o[0], (bf16)o[1], (bf16)o[2], (bf16)o[3] };
  *(bf16x4*)(h + (size_t)row * E_ + tid * 4) = ob;
}

// ---------------------------------------------------------------- weight transpose+convert
// W [K][N] f32 (row stride ldW) -> O [N][K] bf16   (proj weight)
__global__ __launch_bounds__(256) void convw_kernel(
    const float* __restrict__ W0, bf16* __restrict__ O0, int K, int ldW)
{
  __shared__ float tl[32][33];
  int n0 = blockIdx.x * 32, k0 = blockIdx.y * 32;
  int c = threadIdx.x & 31, r = threadIdx.x >> 5;
#pragma unroll
  for (int p = 0; p < 4; ++p)
    tl[r + p * 8][c] = W0[(size_t)(k0 + r + p * 8) * ldW + n0 + c];
  __syncthreads();
#pragma unroll
  for (int p = 0; p < 4; ++p)
    O0[(size_t)(n0 + r + p * 8) * K + k0 + c] = (bf16)tl[c][r + p * 8];
}

// ---------------------------------------------------------------- fused per-layer weight convert
// one launch converts wq,wk,wv (1024x1024), w1 (1024x4096), w2 (4096x1024)
__global__ __launch_bounds__(256) void convw_all(
    const float* __restrict__ wq, const float* __restrict__ wk,
    const float* __restrict__ wv, const float* __restrict__ w1,
    const float* __restrict__ w2,
    bf16* __restrict__ oq, bf16* __restrict__ ok, bf16* __restrict__ ov,
    bf16* __restrict__ o1, bf16* __restrict__ o2)
{
  int bid = blockIdx.x;
  const float* W; bf16* O; int K, ldW, nx, ny;
  if (bid < 3072) {
    int z = bid >> 10, rem = bid & 1023;
    W = (z == 0) ? wq : (z == 1) ? wk : wv;
    O = (z == 0) ? oq : (z == 1) ? ok : ov;
    K = 1024; ldW = 1024; nx = rem & 31; ny = rem >> 5;
  } else if (bid < 7168) {
    int idx = bid - 3072;
    W = w1; O = o1; K = 1024; ldW = 4096;
    nx = idx & 127; ny = idx >> 7;
  } else {
    int idx = bid - 7168;
    W = w2; O = o2; K = 4096; ldW = 1024;
    nx = idx & 31; ny = idx >> 5;
  }
  __shared__ float tl[32][33];
  int n0 = nx * 32, k0 = ny * 32;
  int c = threadIdx.x & 31, r = threadIdx.x >> 5;
#pragma unroll
  for (int p = 0; p < 4; ++p)
    tl[r + p * 8][c] = W[(size_t)(k0 + r + p * 8) * ldW + n0 + c];
  __syncthreads();
#pragma unroll
  for (int p = 0; p < 4; ++p)
    O[(size_t)(n0 + r + p * 8) * K + k0 + c] = (bf16)tl[c][r + p * 8];
}

// ---------------------------------------------------------------- GEMM bf16 MFMA 128x128 (m97-style)
// A [M][LDK] bf16, B [N][LDK] bf16. BK=32, global_load_lds staging with
// XOR-pre-swizzled global source, double-buffered LDS, barrier/K-step.
// MODE 1: bf16 out (+bias, opt GELU). MODE 3: f32 split-K partial (blockIdx.z).
// B3: bias from 3 concatenated 1024-segments (merged QKV).
template <int ACT, int MODE, int B3>
__global__ __launch_bounds__(256) void gemm_bf16(
    const bf16* __restrict__ A, const bf16* __restrict__ Bm,
    const float* __restrict__ bi0, const float* __restrict__ bi1, const float* __restrict__ bi2,
    bf16* __restrict__ Cb, float* __restrict__ Cf,
    int K, int ldc, int LDK)
{
  int koff = (MODE == 3) ? (int)blockIdx.z * K : 0;

  // chunked XCD swizzle (nb multiple of 8)
  int nb  = (int)(gridDim.x * gridDim.y);
  int lin = blockIdx.x + gridDim.x * blockIdx.y;
  int per = nb >> 3;
  int b   = (lin & 7) * per + (lin >> 3);
  int mi  = b & 15;            // gridDim.x == 16 always
  int ni  = b >> 4;

  __shared__ __align__(16) char lds[2][16384];  // [buf][A 8KB | B 8KB]

  int tid = threadIdx.x;
  int lane = tid & 63, wid = tid >> 6;
  int wm = (wid >> 1) * 64, wn = (wid & 1) * 64;
  int fr = lane & 15, fb = lane >> 4;

  const bf16* Asrc = A  + (size_t)(mi * 128) * LDK + koff;
  const bf16* Bsrc = Bm + (size_t)(ni * 128) * LDK + koff;

  int NT = K >> 5;

#define STAGE(buf, kk)                                                          \
  {                                                                             \
    _Pragma("unroll")                                                           \
    for (int is = 0; is < 2; ++is) {                                            \
      int rl = is * 64 + (tid >> 2);                                            \
      int key = (rl >> 1) & 3;                                                  \
      int ck  = ((tid & 3) ^ key) * 8;                                          \
      GL2LDS(Asrc + (size_t)rl * LDK + (kk) + ck,                               \
             lds[buf] + is * 4096 + tid * 16);                                  \
      GL2LDS(Bsrc + (size_t)rl * LDK + (kk) + ck,                               \
             lds[buf] + 8192 + is * 4096 + tid * 16);                           \
    }                                                                           \
  }

  f32x4 acc[4][4];
#pragma unroll
  for (int i = 0; i < 4; ++i)
#pragma unroll
    for (int j = 0; j < 4; ++j) acc[i][j] = (f32x4){0.f, 0.f, 0.f, 0.f};

  STAGE(0, 0);
  int cur = 0;

  for (int t = 0; t < NT; ++t) {
    __syncthreads();                       // drains vmcnt -> buf[cur] ready
    if (t + 1 < NT) STAGE(cur ^ 1, (t + 1) << 5);

    const char* Ab = lds[cur];
    const char* Bb = lds[cur] + 8192;
    bf16x8 af[4], bfr[4];
#pragma unroll
    for (int i = 0; i < 4; ++i) {
      int rl = wm + i * 16 + fr;
      af[i] = *(const bf16x8*)(Ab + rl * 64 + ((fb ^ ((rl >> 1) & 3)) * 16));
    }
#pragma unroll
    for (int j = 0; j < 4; ++j) {
      int rl = wn + j * 16 + fr;
      bfr[j] = *(const bf16x8*)(Bb + rl * 64 + ((fb ^ ((rl >> 1) & 3)) * 16));
    }
#pragma unroll
    for (int i = 0; i < 4; ++i)
#pragma unroll
      for (int j = 0; j < 4; ++j)
        acc[i][j] = __builtin_amdgcn_mfma_f32_16x16x32_bf16(af[i], bfr[j], acc[i][j], 0, 0, 0);
    cur ^= 1;
  }
#undef STAGE

  // epilogue: C/D layout col = lane&15, row = (lane>>4)*4 + reg
#pragma unroll
  for (int i = 0; i < 4; ++i) {
#pragma unroll
    for (int j = 0; j < 4; ++j) {
      int gc = ni * 128 + wn + j * 16 + fr;
      float bv;
      if (MODE == 3)      bv = 0.f;
      else if (B3)        bv = (gc < 1024) ? bi0[gc]
                             : (gc < 2048) ? bi1[gc - 1024] : bi2[gc - 2048];
      else                bv = bi0[gc];
#pragma unroll
      for (int r = 0; r < 4; ++r) {
        int gr = mi * 128 + wm + i * 16 + fb * 4 + r;
        float vv = acc[i][j][r] + bv;
        if (ACT == 1) vv = 0.5f * vv * (1.0f + erff(vv * 0.70710678118654752f));
        if (MODE == 1) {
          Cb[(size_t)gr * ldc + gc] = (bf16)vv;
        } else {
          Cf[(size_t)(blockIdx.z * BT_ + gr) * ldc + gc] = vv;
        }
      }
    }
  }
}

// ---------------------------------------------------------------- FFN2 split-K combine
// x += p0 + p1 + bias ; xb = bf16(x)
__global__ __launch_bounds__(256) void combine_kernel(
    const float* __restrict__ p, const float* __restrict__ bi,
    float* __restrict__ x, bf16* __restrict__ xb)
{
  int row = blockIdx.x, tid = threadIdx.x;
  size_t off = (size_t)row * E_ + tid * 4;
  f32x4 a = *(const f32x4*)(p + off);
  f32x4 c = *(const f32x4*)(p + (size_t)BT_ * E_ + off);
  f32x4 bv = *(const f32x4*)(bi + tid * 4);
  f32x4 xv = *(const f32x4*)(x + off);
  f32x4 nv = xv + a + c + bv;
  *(f32x4*)(x + off) = nv;
  bf16x4 ob = { (bf16)nv[0], (bf16)nv[1], (bf16)nv[2], (bf16)nv[3] };
  *(bf16x4*)(xb + off) = ob;
}

// ---------------------------------------------------------------- GEMM bf16 MFMA 256x256, BK=64
// (round-4 proven version) 512 thr (8 waves, 2Mx4N), counted vmcnt(8), setprio.
__global__ __launch_bounds__(512, 2) void gemm256_kernel(
    const bf16* __restrict__ A, const bf16* __restrict__ Bm,
    const float* __restrict__ bi, float* __restrict__ C, int K, int N)
{
  int nwg = (int)gridDim.x;
  int per = nwg >> 3;
  int bid = (int)blockIdx.x;
  int tl  = (bid & 7) * per + (bid >> 3);   // chunked XCD swizzle (nwg%8==0)
  int mi  = tl & 7, ni = tl >> 3;

  __shared__ __align__(16) char lds[2][65536];

  int tid = threadIdx.x;
  int lane = tid & 63, wid = tid >> 6;
  int wr = wid >> 2, wc = wid & 3;          // 2 x 4 waves
  int fr = lane & 15, fb = lane >> 4;

  const bf16* Asrc = A  + (size_t)(mi * 256) * K;
  const bf16* Bsrc = Bm + (size_t)(ni * 256) * K;

  int NT = K >> 6;

#define STAGE256(buf, kk)                                                  \
  { _Pragma("unroll")                                                      \
    for (int h = 0; h < 2; ++h) {                                          \
      _Pragma("unroll")                                                    \
      for (int is = 0; is < 2; ++is) {                                     \
        int ri  = is * 64 + (tid >> 3);                                    \
        int ck  = (tid & 7) ^ (ri & 7);                                    \
        int row = h * 128 + ri;                                            \
        GL2LDS(Asrc + (size_t)row * K + (kk) + ck * 8,                     \
               lds[buf] + h * 16384 + is * 8192 + tid * 16);               \
        GL2LDS(Bsrc + (size_t)row * K + (kk) + ck * 8,                     \
               lds[buf] + 32768 + h * 16384 + is * 8192 + tid * 16);       \
      }                                                                    \
    } }

  f32x4 acc[8][4];
#pragma unroll
  for (int i = 0; i < 8; ++i)
#pragma unroll
    for (int j = 0; j < 4; ++j) acc[i][j] = (f32x4){0.f, 0.f, 0.f, 0.f};

  STAGE256(0, 0);

  for (int t = 0; t < NT; ++t) {
    int buf = t & 1;
    if (t + 1 < NT) {
      STAGE256(buf ^ 1, (t + 1) << 6);
      asm volatile("s_waitcnt vmcnt(8)" ::: "memory");   // tile t landed; t+1 in flight
    } else {
      asm volatile("s_waitcnt vmcnt(0)" ::: "memory");
    }
    __builtin_amdgcn_s_barrier();
    asm volatile("" ::: "memory");

    const char* Ab = lds[buf];
    const char* Bb = lds[buf] + 32768;

    bf16x8 bfr[4][2];
#pragma unroll
    for (int n2 = 0; n2 < 4; ++n2) {
      int row = wc * 64 + n2 * 16 + fr;
#pragma unroll
      for (int ks = 0; ks < 2; ++ks)
        bfr[n2][ks] = *(const bf16x8*)(Bb + (row >> 7) * 16384 + (row & 127) * 128
                                          + ((((ks * 4 + fb) ^ (fr & 7))) << 4));
    }
#pragma unroll
    for (int q = 0; q < 4; ++q) {
      bf16x8 af[2][2];
#pragma unroll
      for (int m2 = 0; m2 < 2; ++m2) {
        int ri = (q * 2 + m2) * 16 + fr;
#pragma unroll
        for (int ks = 0; ks < 2; ++ks)
          af[m2][ks] = *(const bf16x8*)(Ab + wr * 16384 + ri * 128
                                           + ((((ks * 4 + fb) ^ (fr & 7))) << 4));
      }
      __builtin_amdgcn_s_setprio(1);
#pragma unroll
      for (int m2 = 0; m2 < 2; ++m2)
#pragma unroll
        for (int n2 = 0; n2 < 4; ++n2)
#pragma unroll
          for (int ks = 0; ks < 2; ++ks)
            acc[q * 2 + m2][n2] = __builtin_amdgcn_mfma_f32_16x16x32_bf16(
                af[m2][ks], bfr[n2][ks], acc[q * 2 + m2][n2], 0, 0, 0);
      __builtin_amdgcn_s_setprio(0);
    }
    asm volatile("" ::: "memory");
    __builtin_amdgcn_s_barrier();            // reads done before next stage overwrites
  }
#undef STAGE256

#pragma unroll
  for (int i = 0; i < 8; ++i) {
#pragma unroll
    for (int j = 0; j < 4; ++j) {
      int gc = ni * 256 + wc * 64 + j * 16 + fr;
      float bv = bi[gc];
#pragma unroll
      for (int r = 0; r < 4; ++r) {
        int gr = mi * 256 + wr * 128 + i * 16 + fb * 4 + r;
        C[(size_t)gr * N + gc] = acc[i][j][r] + bv;
      }
    }
  }
}

// ---------------------------------------------------------------- attention (bf16 MFMA flash)
// reads merged qkv [BT][3072]: q at col 0, k at +1024, v at +2048
__global__ __launch_bounds__(256) void attn_kernel(
    const bf16* __restrict__ qkv, float* __restrict__ x)
{
  __shared__ __align__(16) char Ks[8192];
  __shared__ __align__(16) char Vs[8192];
  __shared__ __align__(16) char Ps[8192];

  int tid = threadIdx.x, lane = tid & 63, w = tid >> 6;
  int qt = blockIdx.x, bh = blockIdx.y;
  int b = bh >> 4, h = bh & 15;
  size_t hq = (size_t)b * T_ * QKV_ + h * HS_;
  const bf16* qp0 = qkv + hq;
  const bf16* kp0 = qkv + hq + 1024;
  const bf16* vp0 = qkv + hq + 2048;
  size_t hx = (size_t)b * T_ * E_ + h * HS_;
  int fr = lane & 15, fb = lane >> 4;

  bf16x8 qa[2];
  {
    const bf16* qp = qp0 + (size_t)(qt * 64 + w * 16 + fr) * QKV_ + fb * 8;
    qa[0] = *(const bf16x8*)qp;
    qa[1] = *(const bf16x8*)(qp + 32);
  }

  f32x4 O[4];
  float m_[4], l_[4];
#pragma unroll
  for (int i = 0; i < 4; ++i) { O[i] = (f32x4){0.f,0.f,0.f,0.f}; m_[i] = -1e30f; l_[i] = 0.f; }

  for (int kt = 0; kt <= qt; ++kt) {
    __syncthreads();
    {
      const bf16* kbase = kp0 + (size_t)(kt * 64) * QKV_;
#pragma unroll
      for (int is = 0; is < 2; ++is) {
        int c = is * 32 + (tid >> 3);
        int key = ((c & 7) ^ (c >> 3)) & 7;
        GL2LDS(kbase + (size_t)c * QKV_ + (((tid & 7) ^ key) * 8),
               Ks + is * 4096 + tid * 16);
      }
    }
#pragma unroll
    for (int p = 0; p < 2; ++p) {
      int row = tid >> 2;
      int d0 = (tid & 3) * 8 + p * 32;
      bf16x8 vv = *(const bf16x8*)(vp0 + (size_t)(kt * 64 + row) * QKV_ + d0);
#pragma unroll
      for (int e = 0; e < 8; ++e) {
        int d = d0 + e;
        int key = ((d & 7) ^ (d >> 3)) & 7;
        *(bf16*)(Vs + d * 128 + ((row * 2) ^ (key << 4))) = vv[e];
      }
    }
    __syncthreads();

    f32x4 s[4];
#pragma unroll
    for (int jc = 0; jc < 4; ++jc) {
      s[jc] = (f32x4){0.f, 0.f, 0.f, 0.f};
#pragma unroll
      for (int kc = 0; kc < 2; ++kc) {
        int c = jc * 16 + fr;
        int key = ((c & 7) ^ (c >> 3)) & 7;
        bf16x8 kf = *(const bf16x8*)(Ks + c * 128 + ((kc * 64 + fb * 16) ^ (key << 4)));
        s[jc] = __builtin_amdgcn_mfma_f32_16x16x32_bf16(qa[kc], kf, s[jc], 0, 0, 0);
      }
    }

    char* pbase = Ps + w * 2048;
#pragma unroll
    for (int r = 0; r < 4; ++r) {
      float s0 = s[0][r] * SCALE_, s1 = s[1][r] * SCALE_;
      float s2 = s[2][r] * SCALE_, s3 = s[3][r] * SCALE_;
      int qrow = qt * 64 + w * 16 + fb * 4 + r;
      if (kt == qt) {
        int kc0 = kt * 64 + fr;
        if (kc0      > qrow) s0 = -1e30f;
        if (kc0 + 16 > qrow) s1 = -1e30f;
        if (kc0 + 32 > qrow) s2 = -1e30f;
        if (kc0 + 48 > qrow) s3 = -1e30f;
      }
      float mx = fmaxf(fmaxf(s0, s1), fmaxf(s2, s3));
      mx = fmaxf(mx, __shfl_xor(mx, 1, 16));
      mx = fmaxf(mx, __shfl_xor(mx, 2, 16));
      mx = fmaxf(mx, __shfl_xor(mx, 4, 16));
      mx = fmaxf(mx, __shfl_xor(mx, 8, 16));
      float mnew = fmaxf(m_[r], mx);
      float p0 = __expf(s0 - mnew), p1 = __expf(s1 - mnew);
      float p2 = __expf(s2 - mnew), p3 = __expf(s3 - mnew);
      float rs = p0 + p1 + p2 + p3;
      rs += __shfl_xor(rs, 1, 16);
      rs += __shfl_xor(rs, 2, 16);
      rs += __shfl_xor(rs, 4, 16);
      rs += __shfl_xor(rs, 8, 16);
      float scl = __expf(m_[r] - mnew);
      l_[r] = l_[r] * scl + rs;
      m_[r] = mnew;
#pragma unroll
      for (int jd = 0; jd < 4; ++jd) O[jd][r] *= scl;
      int key2 = (r << 4) ^ (fb << 5);
      char* pr_ = pbase + (fb * 4 + r) * 128;
      *(bf16*)(pr_ + (( 0 + fr * 2) ^ key2)) = (bf16)p0;
      *(bf16*)(pr_ + ((32 + fr * 2) ^ key2)) = (bf16)p1;
      *(bf16*)(pr_ + ((64 + fr * 2) ^ key2)) = (bf16)p2;
      *(bf16*)(pr_ + ((96 + fr * 2) ^ key2)) = (bf16)p3;
    }

#pragma unroll
    for (int kc = 0; kc < 2; ++kc) {
      int key2 = ((fr & 3) << 4) ^ ((fr >> 2) << 5);
      bf16x8 pa = *(const bf16x8*)(pbase + fr * 128 + ((kc * 64 + fb * 16) ^ key2));
#pragma unroll
      for (int jd = 0; jd < 4; ++jd) {
        int d = jd * 16 + fr;
        int key = ((d & 7) ^ (d >> 3)) & 7;
        bf16x8 vf = *(const bf16x8*)(Vs + d * 128 + ((kc * 64 + fb * 16) ^ (key << 4)));
        O[jd] = __builtin_amdgcn_mfma_f32_16x16x32_bf16(pa, vf, O[jd], 0, 0, 0);
      }
    }
  }

#pragma unroll
  for (int r = 0; r < 4; ++r) {
    float inv = 1.0f / l_[r];
    float* xp = x + hx + (size_t)(qt * 64 + w * 16 + fb * 4 + r) * E_;
#pragma unroll
    for (int jd = 0; jd < 4; ++jd) {
      int d = jd * 16 + fr;
      xp[d] += O[jd][r] * inv;
    }
  }
}

// ---------------------------------------------------------------- launch
extern "C" void kernel_launch(void* const* d_in, const int* in_sizes, int n_in,
                              void* d_out, int out_size, void* d_ws, size_t ws_size,
                              hipStream_t stream)
{
  const int*   ids  = (const int*)  d_in[0];
  const float* emb  = (const float*)d_in[1];
  const float* pos  = (const float*)d_in[2];
  const float* wq   = (const float*)d_in[3];
  const float* bq   = (const float*)d_in[4];
  const float* wk   = (const float*)d_in[5];
  const float* bk   = (const float*)d_in[6];
  const float* wv   = (const float*)d_in[7];
  const float* bv   = (const float*)d_in[8];
  const float* w1   = (const float*)d_in[9];
  const float* b1   = (const float*)d_in[10];
  const float* w2   = (const float*)d_in[11];
  const float* b2   = (const float*)d_in[12];
  const float* ln1g = (const float*)d_in[13];
  const float* ln1b = (const float*)d_in[14];
  const float* ln2g = (const float*)d_in[15];
  const float* ln2b = (const float*)d_in[16];
  const float* pw   = (const float*)d_in[17];
  const float* pb   = (const float*)d_in[18];
  float* out = (float*)d_out;

  // ws layout (f32 units), non-overlapping in time:
  //   x    [ 0M,  2M)  f32  BTxE
  //   hb   [ 2M,  3M)  bf16 BTxE      } fp [2M,6M) aliases hb+qkvb
  //   qkvb [ 3M,  6M)  bf16 BTx3072   }   (both dead at FFN2 time)
  //   ffb  [ 6M, 10M)  bf16 BTxFF
  //   lwb  [10M,15.5M) bf16 layer weights (wqkvt 3M bf16 contiguous, w1 4M, w2 4M)
  //   xb   [16M, 17M)  bf16 BTxE
  //   pwb  [ 0M,15.625M) bf16 proj weight (everything below dead at proj time)
  // peak = 17M f32 = 68 MiB (round 1 proved ws >= 72 MiB)
  if (ws_size < (size_t)17 * 1024 * 1024 * 4) return;
  float* ws = (float*)d_ws;
  float* x    = ws;
  bf16*  hb   = (bf16*)(ws + (size_t) 2 * 1024 * 1024);
  bf16*  qkvb = (bf16*)(ws + (size_t) 3 * 1024 * 1024);
  bf16*  ffb  = (bf16*)(ws + (size_t) 6 * 1024 * 1024);
  float* fp   = ws + (size_t)2 * 1024 * 1024;          // 2 partials, 2M f32 each
  bf16*  lwb  = (bf16*)(ws + (size_t)10 * 1024 * 1024);
  bf16*  xb   = (bf16*)(ws + (size_t)16 * 1024 * 1024);
  bf16*  pwb  = (bf16*)ws;
  bf16*  wqkvt = lwb;                                 // 3M bf16 contiguous [3072][1024]
  bf16*  wqt = lwb;
  bf16*  wkt = lwb + (size_t)1 * 1024 * 1024;
  bf16*  wvt = lwb + (size_t)2 * 1024 * 1024;
  bf16*  w1t = lwb + (size_t)3 * 1024 * 1024;
  bf16*  w2t = lwb + (size_t)7 * 1024 * 1024;

  embed_kernel<<<BT_, 256, 0, stream>>>(ids, emb, pos, x);

  for (int l = 0; l < L_; ++l) {
    const size_t lEE = (size_t)l * E_ * E_;
    const size_t lEF = (size_t)l * E_ * FF_;

    convw_all<<<11264, 256, 0, stream>>>(
        wq + lEE, wk + lEE, wv + lEE, w1 + lEF, w2 + lEF,
        wqt, wkt, wvt, w1t, w2t);

    ln_kernel<<<BT_, 256, 0, stream>>>(x, ln1g + l*E_, ln1b + l*E_, hb);

    // merged QKV: one GEMM 2048x3072, out row-stride 3072
    gemm_bf16<0,1,1><<<dim3(16, QKV_/128, 1), 256, 0, stream>>>(
        hb, wqkvt, bq + l*E_, bk + l*E_, bv + l*E_,
        qkvb, nullptr, E_, QKV_, E_);

    attn_kernel<<<dim3(T_/64, B_*H_), 256, 0, stream>>>(qkvb, x);

    ln_kernel<<<BT_, 256, 0, stream>>>(x, ln2g + l*E_, ln2b + l*E_, hb);

    gemm_bf16<1,1,0><<<dim3(16, FF_/128, 1), 256, 0, stream>>>(
        hb, w1t, b1 + (size_t)l*FF_, nullptr, nullptr,
        ffb, nullptr, E_, FF_, E_);

    // FFN2: split-K=2 over blockIdx.z -> 256 blocks, then combine
    gemm_bf16<0,3,0><<<dim3(16, E_/128, 2), 256, 0, stream>>>(
        ffb, w2t, nullptr, nullptr, nullptr,
        nullptr, fp, FF_/2, E_, FF_);
    combine_kernel<<<BT_, 256, 0, stream>>>(fp, b2 + l*E_, x, xb);
  }

  // final projection: whole weight converted, 256^2 BK=64 counted-vmcnt GEMM
  convw_kernel<<<dim3(V_/32, E_/32), 256, 0, stream>>>(pw, pwb, E_, V_);
  gemm256_kernel<<<(V_/256) * 8, 512, 0, stream>>>(
      xb, pwb, pb, out, E_, V_);
}

// Round 7
// 872.096 us; speedup vs baseline: 2.0126x; 1.0584x over previous
//
#include <hip/hip_runtime.h>
#include <hip/hip_bf16.h>
#include <cstdint>

#define B_    2
#define T_    1024
#define E_    1024
#define H_    16
#define HS_   64
#define L_    4
#define V_    32000
#define FF_   4096
#define BT_   2048
#define EPS_  1e-5f
#define SCALE_ 0.03125f   // 1/sqrt(E) = 1/32

typedef __bf16 bf16;
typedef bf16  bf16x4 __attribute__((ext_vector_type(4)));
typedef bf16  bf16x8 __attribute__((ext_vector_type(8)));
typedef float f32x4  __attribute__((ext_vector_type(4)));

#define GL2LDS(gp, lp) __builtin_amdgcn_global_load_lds( \
    (const __attribute__((address_space(1))) void*)(gp), \
    (__attribute__((address_space(3))) void*)(lp), 16, 0, 0)

// ---------------------------------------------------------------- embed
__global__ __launch_bounds__(256) void embed_kernel(
    const int* __restrict__ ids, const float* __restrict__ emb,
    const float* __restrict__ pos, float* __restrict__ x)
{
  int bt = blockIdx.x;
  int t  = bt & (T_ - 1);
  int id = ids[bt];
  f32x4 e = *(const f32x4*)(emb + (size_t)id * E_ + threadIdx.x * 4);
  f32x4 p = *(const f32x4*)(pos + (size_t)t  * E_ + threadIdx.x * 4);
  *(f32x4*)(x + (size_t)bt * E_ + threadIdx.x * 4) = e + p;
}

// ---------------------------------------------------------------- layernorm (f32 in, bf16 out)
__device__ __forceinline__ float wred_sum(float v) {
#pragma unroll
  for (int o = 32; o; o >>= 1) v += __shfl_xor(v, o, 64);
  return v;
}

__global__ __launch_bounds__(256) void ln_kernel(
    const float* __restrict__ x, const float* __restrict__ g,
    const float* __restrict__ b, bf16* __restrict__ h)
{
  int row = blockIdx.x, tid = threadIdx.x;
  f32x4 v = *(const f32x4*)(x + (size_t)row * E_ + tid * 4);
  float s  = v[0] + v[1] + v[2] + v[3];
  float sq = v[0]*v[0] + v[1]*v[1] + v[2]*v[2] + v[3]*v[3];
  s  = wred_sum(s);
  sq = wred_sum(sq);
  __shared__ float rs[4], rq[4];
  int w = tid >> 6, lane = tid & 63;
  if (lane == 0) { rs[w] = s; rq[w] = sq; }
  __syncthreads();
  float S = rs[0] + rs[1] + rs[2] + rs[3];
  float Q = rq[0] + rq[1] + rq[2] + rq[3];
  float mean = S * (1.0f / E_);
  float var  = Q * (1.0f / E_) - mean * mean;
  float rstd = rsqrtf(fmaxf(var, 0.0f) + EPS_);
  f32x4 gv = *(const f32x4*)(g + tid * 4);
  f32x4 bv = *(const f32x4*)(b + tid * 4);
  f32x4 o = (v - mean) * rstd * gv + bv;
  bf16x4 ob = { (bf16)o[0], (bf16)o[1], (bf16)o[2], (bf16)o[3] };
  *(bf16x4*)(h + (size_t)row * E_ + tid * 4) = ob;
}

// ---------------------------------------------------------------- weight transpose+convert
// W [K][N] f32 (row stride ldW) -> O [N][K] bf16
__global__ __launch_bounds__(256) void convw_kernel(
    const float* __restrict__ W0, const float* __restrict__ W1, const float* __restrict__ W2,
    bf16* __restrict__ O0, bf16* __restrict__ O1, bf16* __restrict__ O2,
    int K, int ldW)
{
  int z = blockIdx.z;
  const float* W = (z == 0) ? W0 : (z == 1) ? W1 : W2;
  bf16*        O = (z == 0) ? O0 : (z == 1) ? O1 : O2;
  __shared__ float tl[32][33];
  int n0 = blockIdx.x * 32, k0 = blockIdx.y * 32;
  int c = threadIdx.x & 31, r = threadIdx.x >> 5;
#pragma unroll
  for (int p = 0; p < 4; ++p)
    tl[r + p * 8][c] = W[(size_t)(k0 + r + p * 8) * ldW + n0 + c];
  __syncthreads();
#pragma unroll
  for (int p = 0; p < 4; ++p)
    O[(size_t)(n0 + r + p * 8) * K + k0 + c] = (bf16)tl[c][r + p * 8];
}

// ---------------------------------------------------------------- GEMM bf16 MFMA 128x128 (m97-style)
// A [M][LDK] bf16, B [N][LDK] bf16. BK=32, global_load_lds staging with
// XOR-pre-swizzled global source, double-buffered LDS, barrier/K-step.
// MODE 1: bf16 out (+bias, opt GELU). MODE 3: f32 split-K partial (blockIdx.z).
template <int ACT, int MODE>
__global__ __launch_bounds__(256) void gemm_bf16(
    const bf16* __restrict__ A,
    const bf16* __restrict__ B0, const bf16* __restrict__ B1, const bf16* __restrict__ B2,
    const float* __restrict__ bi0, const float* __restrict__ bi1, const float* __restrict__ bi2,
    bf16* __restrict__ Cb0, bf16* __restrict__ Cb1, bf16* __restrict__ Cb2,
    float* __restrict__ Cf,
    int K, int ldc, int LDK)
{
  int z = blockIdx.z;
  const bf16*  Bm = (MODE == 3) ? B0 : (z == 0) ? B0 : (z == 1) ? B1 : B2;
  const float* bi = (z == 0) ? bi0 : (z == 1) ? bi1 : bi2;
  bf16*        Cb = (z == 0) ? Cb0 : (z == 1) ? Cb1 : Cb2;
  int koff = (MODE == 3) ? z * K : 0;

  // chunked XCD swizzle (nb multiple of 8)
  int nb  = (int)(gridDim.x * gridDim.y);
  int lin = blockIdx.x + gridDim.x * blockIdx.y;
  int per = nb >> 3;
  int b   = (lin & 7) * per + (lin >> 3);
  int mi  = b & 15;            // gridDim.x == 16 always
  int ni  = b >> 4;

  __shared__ __align__(16) char lds[2][16384];  // [buf][A 8KB | B 8KB]

  int tid = threadIdx.x;
  int lane = tid & 63, wid = tid >> 6;
  int wm = (wid >> 1) * 64, wn = (wid & 1) * 64;
  int fr = lane & 15, fb = lane >> 4;

  const bf16* Asrc = A  + (size_t)(mi * 128) * LDK + koff;
  const bf16* Bsrc = Bm + (size_t)(ni * 128) * LDK + koff;

  int NT = K >> 5;

#define STAGE(buf, kk)                                                          \
  {                                                                             \
    _Pragma("unroll")                                                           \
    for (int is = 0; is < 2; ++is) {                                            \
      int rl = is * 64 + (tid >> 2);                                            \
      int key = (rl >> 1) & 3;                                                  \
      int ck  = ((tid & 3) ^ key) * 8;                                          \
      GL2LDS(Asrc + (size_t)rl * LDK + (kk) + ck,                               \
             lds[buf] + is * 4096 + tid * 16);                                  \
      GL2LDS(Bsrc + (size_t)rl * LDK + (kk) + ck,                               \
             lds[buf] + 8192 + is * 4096 + tid * 16);                           \
    }                                                                           \
  }

  f32x4 acc[4][4];
#pragma unroll
  for (int i = 0; i < 4; ++i)
#pragma unroll
    for (int j = 0; j < 4; ++j) acc[i][j] = (f32x4){0.f, 0.f, 0.f, 0.f};

  STAGE(0, 0);
  int cur = 0;

  for (int t = 0; t < NT; ++t) {
    __syncthreads();                       // drains vmcnt -> buf[cur] ready
    if (t + 1 < NT) STAGE(cur ^ 1, (t + 1) << 5);

    const char* Ab = lds[cur];
    const char* Bb = lds[cur] + 8192;
    bf16x8 af[4], bfr[4];
#pragma unroll
    for (int i = 0; i < 4; ++i) {
      int rl = wm + i * 16 + fr;
      af[i] = *(const bf16x8*)(Ab + rl * 64 + ((fb ^ ((rl >> 1) & 3)) * 16));
    }
#pragma unroll
    for (int j = 0; j < 4; ++j) {
      int rl = wn + j * 16 + fr;
      bfr[j] = *(const bf16x8*)(Bb + rl * 64 + ((fb ^ ((rl >> 1) & 3)) * 16));
    }
#pragma unroll
    for (int i = 0; i < 4; ++i)
#pragma unroll
      for (int j = 0; j < 4; ++j)
        acc[i][j] = __builtin_amdgcn_mfma_f32_16x16x32_bf16(af[i], bfr[j], acc[i][j], 0, 0, 0);
    cur ^= 1;
  }
#undef STAGE

  // epilogue: C/D layout col = lane&15, row = (lane>>4)*4 + reg
#pragma unroll
  for (int i = 0; i < 4; ++i) {
#pragma unroll
    for (int j = 0; j < 4; ++j) {
      int gc = ni * 128 + wn + j * 16 + fr;
      float bv = (MODE == 3) ? 0.f : bi[gc];
#pragma unroll
      for (int r = 0; r < 4; ++r) {
        int gr = mi * 128 + wm + i * 16 + fb * 4 + r;
        float vv = acc[i][j][r] + bv;
        if (ACT == 1) vv = 0.5f * vv * (1.0f + erff(vv * 0.70710678118654752f));
        if (MODE == 1) {
          Cb[(size_t)gr * ldc + gc] = (bf16)vv;
        } else {
          Cf[(size_t)(blockIdx.z * BT_ + gr) * ldc + gc] = vv;
        }
      }
    }
  }
}

// ---------------------------------------------------------------- FFN2 split-K combine
// x += p0 + p1 + bias ; xb = bf16(x)
__global__ __launch_bounds__(256) void combine_kernel(
    const float* __restrict__ p, const float* __restrict__ bi,
    float* __restrict__ x, bf16* __restrict__ xb)
{
  int row = blockIdx.x, tid = threadIdx.x;
  size_t off = (size_t)row * E_ + tid * 4;
  f32x4 a = *(const f32x4*)(p + off);
  f32x4 c = *(const f32x4*)(p + (size_t)BT_ * E_ + off);
  f32x4 bv = *(const f32x4*)(bi + tid * 4);
  f32x4 xv = *(const f32x4*)(x + off);
  f32x4 nv = xv + a + c + bv;
  *(f32x4*)(x + off) = nv;
  bf16x4 ob = { (bf16)nv[0], (bf16)nv[1], (bf16)nv[2], (bf16)nv[3] };
  *(bf16x4*)(xb + off) = ob;
}

// ---------------------------------------------------------------- GEMM bf16 MFMA 256x256, BK=32
// 512 thr (8 waves, 2Mx4N). 4 LDS buffers x 32KB = 128 KiB -> prefetch
// depth 3: at step t, tile t+3 is issued and vmcnt(12) waits only for
// tile t (issued 3 steps = ~6000 cyc earlier) -> JIT-latency stall ~0.
// Race-safety: buffer (t+3)&3 was last ds_read in step t-1; those reads
// are lgkm-consumed by MFMAs before step t-1's end barrier, which
// precedes this step's stage issue. Swizzle involution chunk^=(row>>1)&3
// (pre-applied on global source, re-applied on ds_read; measured 0 conflicts).
__global__ __launch_bounds__(512, 2) void gemm256_kernel(
    const bf16* __restrict__ A, const bf16* __restrict__ Bm,
    const float* __restrict__ bi, float* __restrict__ C, int K, int N)
{
  int nwg = (int)gridDim.x;
  int per = nwg >> 3;
  int bid = (int)blockIdx.x;
  int tl  = (bid & 7) * per + (bid >> 3);   // chunked XCD swizzle (nwg%8==0)
  int mi  = tl & 7, ni = tl >> 3;

  __shared__ __align__(16) char lds[4][32768];   // [buf][A 16KB | B 16KB]

  int tid = threadIdx.x;
  int lane = tid & 63, wid = tid >> 6;
  int wr = wid >> 2, wc = wid & 3;          // 2 x 4 waves
  int fr = lane & 15, fb = lane >> 4;

  const bf16* Asrc = A  + (size_t)(mi * 256) * K;
  const bf16* Bsrc = Bm + (size_t)(ni * 256) * K;

  int NT = K >> 5;   // 32

#define STG(buf, kk)                                                       \
  { _Pragma("unroll")                                                      \
    for (int is = 0; is < 2; ++is) {                                       \
      int c   = is * 512 + tid;                                            \
      int row = c >> 2;                                                    \
      int ck  = ((c & 3) ^ ((row >> 1) & 3)) * 8;                          \
      GL2LDS(Asrc + (size_t)row * K + (kk) + ck,                           \
             lds[buf] + c * 16);                                           \
      GL2LDS(Bsrc + (size_t)row * K + (kk) + ck,                           \
             lds[buf] + 16384 + c * 16);                                   \
    } }

  f32x4 acc[8][4];
#pragma unroll
  for (int i = 0; i < 8; ++i)
#pragma unroll
    for (int j = 0; j < 4; ++j) acc[i][j] = (f32x4){0.f, 0.f, 0.f, 0.f};

  // prologue: 3 tiles in flight
  STG(0, 0);
  STG(1, 32);
  STG(2, 64);

  for (int t = 0; t < NT; ++t) {
    int buf = t & 3;
    if (t + 3 < NT) {
      STG((t + 3) & 3, (t + 3) << 5);
      asm volatile("s_waitcnt vmcnt(12)" ::: "memory");  // t+1..t+3 in flight
    } else if (t + 2 < NT) {
      asm volatile("s_waitcnt vmcnt(8)" ::: "memory");
    } else if (t + 1 < NT) {
      asm volatile("s_waitcnt vmcnt(4)" ::: "memory");
    } else {
      asm volatile("s_waitcnt vmcnt(0)" ::: "memory");
    }
    __builtin_amdgcn_s_barrier();
    asm volatile("" ::: "memory");

    const char* Ab = lds[buf];
    const char* Bb = lds[buf] + 16384;

    bf16x8 bfr[4];
#pragma unroll
    for (int n2 = 0; n2 < 4; ++n2) {
      int row = wc * 64 + n2 * 16 + fr;
      bfr[n2] = *(const bf16x8*)(Bb + row * 64 + ((fb ^ ((row >> 1) & 3)) << 4));
    }
    // phase A: A rows wr*128 + [0,64)
    {
      bf16x8 af[4];
#pragma unroll
      for (int i = 0; i < 4; ++i) {
        int row = wr * 128 + i * 16 + fr;
        af[i] = *(const bf16x8*)(Ab + row * 64 + ((fb ^ ((row >> 1) & 3)) << 4));
      }
      __builtin_amdgcn_s_setprio(1);
#pragma unroll
      for (int i = 0; i < 4; ++i)
#pragma unroll
        for (int n2 = 0; n2 < 4; ++n2)
          acc[i][n2] = __builtin_amdgcn_mfma_f32_16x16x32_bf16(
              af[i], bfr[n2], acc[i][n2], 0, 0, 0);
      __builtin_amdgcn_s_setprio(0);
    }
    // phase B: A rows wr*128 + [64,128)
    {
      bf16x8 af[4];
#pragma unroll
      for (int i = 0; i < 4; ++i) {
        int row = wr * 128 + 64 + i * 16 + fr;
        af[i] = *(const bf16x8*)(Ab + row * 64 + ((fb ^ ((row >> 1) & 3)) << 4));
      }
      __builtin_amdgcn_s_setprio(1);
#pragma unroll
      for (int i = 0; i < 4; ++i)
#pragma unroll
        for (int n2 = 0; n2 < 4; ++n2)
          acc[4 + i][n2] = __builtin_amdgcn_mfma_f32_16x16x32_bf16(
              af[i], bfr[n2], acc[4 + i][n2], 0, 0, 0);
      __builtin_amdgcn_s_setprio(0);
    }
    asm volatile("" ::: "memory");
    __builtin_amdgcn_s_barrier();   // all reads of buf done before its re-stage
  }
#undef STG

#pragma unroll
  for (int i = 0; i < 8; ++i) {
#pragma unroll
    for (int j = 0; j < 4; ++j) {
      int gc = ni * 256 + wc * 64 + j * 16 + fr;
      float bv = bi[gc];
#pragma unroll
      for (int r = 0; r < 4; ++r) {
        int gr = mi * 256 + wr * 128 + i * 16 + fb * 4 + r;
        C[(size_t)gr * N + gc] = acc[i][j][r] + bv;
      }
    }
  }
}

// ---------------------------------------------------------------- attention (bf16 MFMA flash)
__global__ __launch_bounds__(256) void attn_kernel(
    const bf16* __restrict__ q, const bf16* __restrict__ k,
    const bf16* __restrict__ v, float* __restrict__ x)
{
  __shared__ __align__(16) char Ks[8192];
  __shared__ __align__(16) char Vs[8192];
  __shared__ __align__(16) char Ps[8192];

  int tid = threadIdx.x, lane = tid & 63, w = tid >> 6;
  int qt = blockIdx.x, bh = blockIdx.y;
  int b = bh >> 4, h = bh & 15;
  size_t hoff = (size_t)b * T_ * E_ + h * HS_;
  int fr = lane & 15, fb = lane >> 4;

  bf16x8 qa[2];
  {
    const bf16* qp = q + hoff + (size_t)(qt * 64 + w * 16 + fr) * E_ + fb * 8;
    qa[0] = *(const bf16x8*)qp;
    qa[1] = *(const bf16x8*)(qp + 32);
  }

  f32x4 O[4];
  float m_[4], l_[4];
#pragma unroll
  for (int i = 0; i < 4; ++i) { O[i] = (f32x4){0.f,0.f,0.f,0.f}; m_[i] = -1e30f; l_[i] = 0.f; }

  for (int kt = 0; kt <= qt; ++kt) {
    __syncthreads();
    {
      const bf16* kbase = k + hoff + (size_t)(kt * 64) * E_;
#pragma unroll
      for (int is = 0; is < 2; ++is) {
        int c = is * 32 + (tid >> 3);
        int key = ((c & 7) ^ (c >> 3)) & 7;
        GL2LDS(kbase + (size_t)c * E_ + (((tid & 7) ^ key) * 8),
               Ks + is * 4096 + tid * 16);
      }
    }
#pragma unroll
    for (int p = 0; p < 2; ++p) {
      int row = tid >> 2;
      int d0 = (tid & 3) * 8 + p * 32;
      bf16x8 vv = *(const bf16x8*)(v + hoff + (size_t)(kt * 64 + row) * E_ + d0);
#pragma unroll
      for (int e = 0; e < 8; ++e) {
        int d = d0 + e;
        int key = ((d & 7) ^ (d >> 3)) & 7;
        *(bf16*)(Vs + d * 128 + ((row * 2) ^ (key << 4))) = vv[e];
      }
    }
    __syncthreads();

    f32x4 s[4];
#pragma unroll
    for (int jc = 0; jc < 4; ++jc) {
      s[jc] = (f32x4){0.f, 0.f, 0.f, 0.f};
#pragma unroll
      for (int kc = 0; kc < 2; ++kc) {
        int c = jc * 16 + fr;
        int key = ((c & 7) ^ (c >> 3)) & 7;
        bf16x8 kf = *(const bf16x8*)(Ks + c * 128 + ((kc * 64 + fb * 16) ^ (key << 4)));
        s[jc] = __builtin_amdgcn_mfma_f32_16x16x32_bf16(qa[kc], kf, s[jc], 0, 0, 0);
      }
    }

    char* pbase = Ps + w * 2048;
#pragma unroll
    for (int r = 0; r < 4; ++r) {
      float s0 = s[0][r] * SCALE_, s1 = s[1][r] * SCALE_;
      float s2 = s[2][r] * SCALE_, s3 = s[3][r] * SCALE_;
      int qrow = qt * 64 + w * 16 + fb * 4 + r;
      if (kt == qt) {
        int kc0 = kt * 64 + fr;
        if (kc0      > qrow) s0 = -1e30f;
        if (kc0 + 16 > qrow) s1 = -1e30f;
        if (kc0 + 32 > qrow) s2 = -1e30f;
        if (kc0 + 48 > qrow) s3 = -1e30f;
      }
      float mx = fmaxf(fmaxf(s0, s1), fmaxf(s2, s3));
      mx = fmaxf(mx, __shfl_xor(mx, 1, 16));
      mx = fmaxf(mx, __shfl_xor(mx, 2, 16));
      mx = fmaxf(mx, __shfl_xor(mx, 4, 16));
      mx = fmaxf(mx, __shfl_xor(mx, 8, 16));
      float mnew = fmaxf(m_[r], mx);
      float p0 = __expf(s0 - mnew), p1 = __expf(s1 - mnew);
      float p2 = __expf(s2 - mnew), p3 = __expf(s3 - mnew);
      float rs = p0 + p1 + p2 + p3;
      rs += __shfl_xor(rs, 1, 16);
      rs += __shfl_xor(rs, 2, 16);
      rs += __shfl_xor(rs, 4, 16);
      rs += __shfl_xor(rs, 8, 16);
      float scl = __expf(m_[r] - mnew);
      l_[r] = l_[r] * scl + rs;
      m_[r] = mnew;
#pragma unroll
      for (int jd = 0; jd < 4; ++jd) O[jd][r] *= scl;
      int key2 = (r << 4) ^ (fb << 5);
      char* pr_ = pbase + (fb * 4 + r) * 128;
      *(bf16*)(pr_ + (( 0 + fr * 2) ^ key2)) = (bf16)p0;
      *(bf16*)(pr_ + ((32 + fr * 2) ^ key2)) = (bf16)p1;
      *(bf16*)(pr_ + ((64 + fr * 2) ^ key2)) = (bf16)p2;
      *(bf16*)(pr_ + ((96 + fr * 2) ^ key2)) = (bf16)p3;
    }

#pragma unroll
    for (int kc = 0; kc < 2; ++kc) {
      int key2 = ((fr & 3) << 4) ^ ((fr >> 2) << 5);
      bf16x8 pa = *(const bf16x8*)(pbase + fr * 128 + ((kc * 64 + fb * 16) ^ key2));
#pragma unroll
      for (int jd = 0; jd < 4; ++jd) {
        int d = jd * 16 + fr;
        int key = ((d & 7) ^ (d >> 3)) & 7;
        bf16x8 vf = *(const bf16x8*)(Vs + d * 128 + ((kc * 64 + fb * 16) ^ (key << 4)));
        O[jd] = __builtin_amdgcn_mfma_f32_16x16x32_bf16(pa, vf, O[jd], 0, 0, 0);
      }
    }
  }

#pragma unroll
  for (int r = 0; r < 4; ++r) {
    float inv = 1.0f / l_[r];
    float* xp = x + hoff + (size_t)(qt * 64 + w * 16 + fb * 4 + r) * E_;
#pragma unroll
    for (int jd = 0; jd < 4; ++jd) {
      int d = jd * 16 + fr;
      xp[d] += O[jd][r] * inv;
    }
  }
}

// ---------------------------------------------------------------- launch
extern "C" void kernel_launch(void* const* d_in, const int* in_sizes, int n_in,
                              void* d_out, int out_size, void* d_ws, size_t ws_size,
                              hipStream_t stream)
{
  const int*   ids  = (const int*)  d_in[0];
  const float* emb  = (const float*)d_in[1];
  const float* pos  = (const float*)d_in[2];
  const float* wq   = (const float*)d_in[3];
  const float* bq   = (const float*)d_in[4];
  const float* wk   = (const float*)d_in[5];
  const float* bk   = (const float*)d_in[6];
  const float* wv   = (const float*)d_in[7];
  const float* bv   = (const float*)d_in[8];
  const float* w1   = (const float*)d_in[9];
  const float* b1   = (const float*)d_in[10];
  const float* w2   = (const float*)d_in[11];
  const float* b2   = (const float*)d_in[12];
  const float* ln1g = (const float*)d_in[13];
  const float* ln1b = (const float*)d_in[14];
  const float* ln2g = (const float*)d_in[15];
  const float* ln2b = (const float*)d_in[16];
  const float* pw   = (const float*)d_in[17];
  const float* pb   = (const float*)d_in[18];
  float* out = (float*)d_out;

  // ws layout (f32 units), non-overlapping in time (round-4-proven):
  //   x   [ 0M,  2M)  f32  BTxE
  //   hb  [ 2M,  3M)  bf16 BTxE      } fp [2M,6M) aliases hb..vb
  //   qb  [ 3M,  4M)  bf16 BTxE      }   (dead at FFN2 time)
  //   kb  [ 4M,  5M)  bf16 BTxE
  //   vb  [ 5M,  6M)  bf16 BTxE
  //   ffb [ 6M, 10M)  bf16 BTxFF
  //   lwb [10M,15.5M) bf16 layer weights
  //   xb  [16M, 17M)  bf16 BTxE
  //   pwb [ 0M,15.625M) bf16 proj weight (all below dead at proj time)
  // peak = 17M f32 = 68 MiB (round 1 proved ws >= 72 MiB)
  if (ws_size < (size_t)17 * 1024 * 1024 * 4) return;
  float* ws = (float*)d_ws;
  float* x   = ws;
  bf16*  hb  = (bf16*)(ws + (size_t) 2 * 1024 * 1024);
  bf16*  qb  = (bf16*)(ws + (size_t) 3 * 1024 * 1024);
  bf16*  kb  = (bf16*)(ws + (size_t) 4 * 1024 * 1024);
  bf16*  vb  = (bf16*)(ws + (size_t) 5 * 1024 * 1024);
  bf16*  ffb = (bf16*)(ws + (size_t) 6 * 1024 * 1024);
  float* fp  = ws + (size_t)2 * 1024 * 1024;          // 2 partials, 2M f32 each
  bf16*  lwb = (bf16*)(ws + (size_t)10 * 1024 * 1024);
  bf16*  xb  = (bf16*)(ws + (size_t)16 * 1024 * 1024);
  bf16*  pwb = (bf16*)ws;
  bf16*  wqt = lwb;
  bf16*  wkt = lwb + (size_t)1 * 1024 * 1024;
  bf16*  wvt = lwb + (size_t)2 * 1024 * 1024;
  bf16*  w1t = lwb + (size_t)3 * 1024 * 1024;
  bf16*  w2t = lwb + (size_t)7 * 1024 * 1024;

  embed_kernel<<<BT_, 256, 0, stream>>>(ids, emb, pos, x);

  for (int l = 0; l < L_; ++l) {
    const size_t lEE = (size_t)l * E_ * E_;
    const size_t lEF = (size_t)l * E_ * FF_;

    convw_kernel<<<dim3(E_/32, E_/32, 3), 256, 0, stream>>>(
        wq + lEE, wk + lEE, wv + lEE, wqt, wkt, wvt, E_, E_);
    convw_kernel<<<dim3(FF_/32, E_/32, 1), 256, 0, stream>>>(
        w1 + lEF, nullptr, nullptr, w1t, nullptr, nullptr, E_, FF_);
    convw_kernel<<<dim3(E_/32, FF_/32, 1), 256, 0, stream>>>(
        w2 + lEF, nullptr, nullptr, w2t, nullptr, nullptr, FF_, E_);

    ln_kernel<<<BT_, 256, 0, stream>>>(x, ln1g + l*E_, ln1b + l*E_, hb);

    gemm_bf16<0,1><<<dim3(16, E_/128, 3), 256, 0, stream>>>(
        hb, wqt, wkt, wvt, bq + l*E_, bk + l*E_, bv + l*E_,
        qb, kb, vb, nullptr, E_, E_, E_);

    attn_kernel<<<dim3(T_/64, B_*H_), 256, 0, stream>>>(qb, kb, vb, x);

    ln_kernel<<<BT_, 256, 0, stream>>>(x, ln2g + l*E_, ln2b + l*E_, hb);

    gemm_bf16<1,1><<<dim3(16, FF_/128, 1), 256, 0, stream>>>(
        hb, w1t, nullptr, nullptr, b1 + (size_t)l*FF_, nullptr, nullptr,
        ffb, nullptr, nullptr, nullptr, E_, FF_, E_);

    // FFN2: split-K=2 over blockIdx.z -> 256 blocks, then combine
    gemm_bf16<0,3><<<dim3(16, E_/128, 2), 256, 0, stream>>>(
        ffb, w2t, nullptr, nullptr, nullptr, nullptr, nullptr,
        nullptr, nullptr, nullptr, fp, FF_/2, E_, FF_);
    combine_kernel<<<BT_, 256, 0, stream>>>(fp, b2 + l*E_, x, xb);
  }

  // final projection: whole weight converted, 256^2 BK=32 depth-3 GEMM
  convw_kernel<<<dim3(V_/32, E_/32, 1), 256, 0, stream>>>(
      pw, nullptr, nullptr, pwb, nullptr, nullptr, E_, V_);
  gemm256_kernel<<<(V_/256) * 8, 512, 0, stream>>>(
      xb, pwb, pb, out, E_, V_);
}

// Round 8
// 852.777 us; speedup vs baseline: 2.0582x; 1.0227x over previous
//
#include <hip/hip_runtime.h>
#include <hip/hip_bf16.h>
#include <cstdint>

#define B_    2
#define T_    1024
#define E_    1024
#define H_    16
#define HS_   64
#define L_    4
#define V_    32000
#define FF_   4096
#define BT_   2048
#define EPS_  1e-5f
#define SCALE_ 0.03125f   // 1/sqrt(E) = 1/32

typedef __bf16 bf16;
typedef bf16  bf16x4 __attribute__((ext_vector_type(4)));
typedef bf16  bf16x8 __attribute__((ext_vector_type(8)));
typedef float f32x4  __attribute__((ext_vector_type(4)));

#define GL2LDS(gp, lp) __builtin_amdgcn_global_load_lds( \
    (const __attribute__((address_space(1))) void*)(gp), \
    (__attribute__((address_space(3))) void*)(lp), 16, 0, 0)

// ---------------------------------------------------------------- embed
__global__ __launch_bounds__(256) void embed_kernel(
    const int* __restrict__ ids, const float* __restrict__ emb,
    const float* __restrict__ pos, float* __restrict__ x)
{
  int bt = blockIdx.x;
  int t  = bt & (T_ - 1);
  int id = ids[bt];
  f32x4 e = *(const f32x4*)(emb + (size_t)id * E_ + threadIdx.x * 4);
  f32x4 p = *(const f32x4*)(pos + (size_t)t  * E_ + threadIdx.x * 4);
  *(f32x4*)(x + (size_t)bt * E_ + threadIdx.x * 4) = e + p;
}

// ---------------------------------------------------------------- layernorm (f32 in, bf16 out)
__device__ __forceinline__ float wred_sum(float v) {
#pragma unroll
  for (int o = 32; o; o >>= 1) v += __shfl_xor(v, o, 64);
  return v;
}

__global__ __launch_bounds__(256) void ln_kernel(
    const float* __restrict__ x, const float* __restrict__ g,
    const float* __restrict__ b, bf16* __restrict__ h)
{
  int row = blockIdx.x, tid = threadIdx.x;
  f32x4 v = *(const f32x4*)(x + (size_t)row * E_ + tid * 4);
  float s  = v[0] + v[1] + v[2] + v[3];
  float sq = v[0]*v[0] + v[1]*v[1] + v[2]*v[2] + v[3]*v[3];
  s  = wred_sum(s);
  sq = wred_sum(sq);
  __shared__ float rs[4], rq[4];
  int w = tid >> 6, lane = tid & 63;
  if (lane == 0) { rs[w] = s; rq[w] = sq; }
  __syncthreads();
  float S = rs[0] + rs[1] + rs[2] + rs[3];
  float Q = rq[0] + rq[1] + rq[2] + rq[3];
  float mean = S * (1.0f / E_);
  float var  = Q * (1.0f / E_) - mean * mean;
  float rstd = rsqrtf(fmaxf(var, 0.0f) + EPS_);
  f32x4 gv = *(const f32x4*)(g + tid * 4);
  f32x4 bv = *(const f32x4*)(b + tid * 4);
  f32x4 o = (v - mean) * rstd * gv + bv;
  bf16x4 ob = { (bf16)o[0], (bf16)o[1], (bf16)o[2], (bf16)o[3] };
  *(bf16x4*)(h + (size_t)row * E_ + tid * 4) = ob;
}

// ---------------------------------------------------------------- weight transpose+convert
// W [K][N] f32 (row stride ldW) -> O [N][K] bf16
__global__ __launch_bounds__(256) void convw_kernel(
    const float* __restrict__ W0, const float* __restrict__ W1, const float* __restrict__ W2,
    bf16* __restrict__ O0, bf16* __restrict__ O1, bf16* __restrict__ O2,
    int K, int ldW)
{
  int z = blockIdx.z;
  const float* W = (z == 0) ? W0 : (z == 1) ? W1 : W2;
  bf16*        O = (z == 0) ? O0 : (z == 1) ? O1 : O2;
  __shared__ float tl[32][33];
  int n0 = blockIdx.x * 32, k0 = blockIdx.y * 32;
  int c = threadIdx.x & 31, r = threadIdx.x >> 5;
#pragma unroll
  for (int p = 0; p < 4; ++p)
    tl[r + p * 8][c] = W[(size_t)(k0 + r + p * 8) * ldW + n0 + c];
  __syncthreads();
#pragma unroll
  for (int p = 0; p < 4; ++p)
    O[(size_t)(n0 + r + p * 8) * K + k0 + c] = (bf16)tl[c][r + p * 8];
}

// ---------------------------------------------------------------- GEMM bf16 MFMA 128x128 (m97-style)
// A [M][LDK] bf16, B [N][LDK] bf16. BK=32, global_load_lds staging with
// XOR-pre-swizzled global source, double-buffered LDS, barrier/K-step.
// MODE 1: bf16 out (+bias, opt GELU). MODE 3: f32 split-K partial (blockIdx.z).
template <int ACT, int MODE>
__global__ __launch_bounds__(256) void gemm_bf16(
    const bf16* __restrict__ A,
    const bf16* __restrict__ B0, const bf16* __restrict__ B1, const bf16* __restrict__ B2,
    const float* __restrict__ bi0, const float* __restrict__ bi1, const float* __restrict__ bi2,
    bf16* __restrict__ Cb0, bf16* __restrict__ Cb1, bf16* __restrict__ Cb2,
    float* __restrict__ Cf,
    int K, int ldc, int LDK)
{
  int z = blockIdx.z;
  const bf16*  Bm = (MODE == 3) ? B0 : (z == 0) ? B0 : (z == 1) ? B1 : B2;
  const float* bi = (z == 0) ? bi0 : (z == 1) ? bi1 : bi2;
  bf16*        Cb = (z == 0) ? Cb0 : (z == 1) ? Cb1 : Cb2;
  int koff = (MODE == 3) ? z * K : 0;

  // chunked XCD swizzle (nb multiple of 8)
  int nb  = (int)(gridDim.x * gridDim.y);
  int lin = blockIdx.x + gridDim.x * blockIdx.y;
  int per = nb >> 3;
  int b   = (lin & 7) * per + (lin >> 3);
  int mi  = b & 15;            // gridDim.x == 16 always
  int ni  = b >> 4;

  __shared__ __align__(16) char lds[2][16384];  // [buf][A 8KB | B 8KB]

  int tid = threadIdx.x;
  int lane = tid & 63, wid = tid >> 6;
  int wm = (wid >> 1) * 64, wn = (wid & 1) * 64;
  int fr = lane & 15, fb = lane >> 4;

  const bf16* Asrc = A  + (size_t)(mi * 128) * LDK + koff;
  const bf16* Bsrc = Bm + (size_t)(ni * 128) * LDK + koff;

  int NT = K >> 5;

#define STAGE(buf, kk)                                                          \
  {                                                                             \
    _Pragma("unroll")                                                           \
    for (int is = 0; is < 2; ++is) {                                            \
      int rl = is * 64 + (tid >> 2);                                            \
      int key = (rl >> 1) & 3;                                                  \
      int ck  = ((tid & 3) ^ key) * 8;                                          \
      GL2LDS(Asrc + (size_t)rl * LDK + (kk) + ck,                               \
             lds[buf] + is * 4096 + tid * 16);                                  \
      GL2LDS(Bsrc + (size_t)rl * LDK + (kk) + ck,                               \
             lds[buf] + 8192 + is * 4096 + tid * 16);                           \
    }                                                                           \
  }

  f32x4 acc[4][4];
#pragma unroll
  for (int i = 0; i < 4; ++i)
#pragma unroll
    for (int j = 0; j < 4; ++j) acc[i][j] = (f32x4){0.f, 0.f, 0.f, 0.f};

  STAGE(0, 0);
  int cur = 0;

  for (int t = 0; t < NT; ++t) {
    __syncthreads();                       // drains vmcnt -> buf[cur] ready
    if (t + 1 < NT) STAGE(cur ^ 1, (t + 1) << 5);

    const char* Ab = lds[cur];
    const char* Bb = lds[cur] + 8192;
    bf16x8 af[4], bfr[4];
#pragma unroll
    for (int i = 0; i < 4; ++i) {
      int rl = wm + i * 16 + fr;
      af[i] = *(const bf16x8*)(Ab + rl * 64 + ((fb ^ ((rl >> 1) & 3)) * 16));
    }
#pragma unroll
    for (int j = 0; j < 4; ++j) {
      int rl = wn + j * 16 + fr;
      bfr[j] = *(const bf16x8*)(Bb + rl * 64 + ((fb ^ ((rl >> 1) & 3)) * 16));
    }
#pragma unroll
    for (int i = 0; i < 4; ++i)
#pragma unroll
      for (int j = 0; j < 4; ++j)
        acc[i][j] = __builtin_amdgcn_mfma_f32_16x16x32_bf16(af[i], bfr[j], acc[i][j], 0, 0, 0);
    cur ^= 1;
  }
#undef STAGE

  // epilogue: C/D layout col = lane&15, row = (lane>>4)*4 + reg
#pragma unroll
  for (int i = 0; i < 4; ++i) {
#pragma unroll
    for (int j = 0; j < 4; ++j) {
      int gc = ni * 128 + wn + j * 16 + fr;
      float bv = (MODE == 3) ? 0.f : bi[gc];
#pragma unroll
      for (int r = 0; r < 4; ++r) {
        int gr = mi * 128 + wm + i * 16 + fb * 4 + r;
        float vv = acc[i][j][r] + bv;
        if (ACT == 1) vv = 0.5f * vv * (1.0f + erff(vv * 0.70710678118654752f));
        if (MODE == 1) {
          Cb[(size_t)gr * ldc + gc] = (bf16)vv;
        } else {
          Cf[(size_t)(blockIdx.z * BT_ + gr) * ldc + gc] = vv;
        }
      }
    }
  }
}

// ---------------------------------------------------------------- FFN2 split-K combine
// x += p0 + p1 + bias ; xb = bf16(x)
__global__ __launch_bounds__(256) void combine_kernel(
    const float* __restrict__ p, const float* __restrict__ bi,
    float* __restrict__ x, bf16* __restrict__ xb)
{
  int row = blockIdx.x, tid = threadIdx.x;
  size_t off = (size_t)row * E_ + tid * 4;
  f32x4 a = *(const f32x4*)(p + off);
  f32x4 c = *(const f32x4*)(p + (size_t)BT_ * E_ + off);
  f32x4 bv = *(const f32x4*)(bi + tid * 4);
  f32x4 xv = *(const f32x4*)(x + off);
  f32x4 nv = xv + a + c + bv;
  *(f32x4*)(x + off) = nv;
  bf16x4 ob = { (bf16)nv[0], (bf16)nv[1], (bf16)nv[2], (bf16)nv[3] };
  *(bf16x4*)(xb + off) = ob;
}

// ---------------------------------------------------------------- GEMM bf16 MFMA 256x256, BK=64
// 512 thr (8 waves, 2Mx4N), 2 LDS buffers (128 KiB). 4-phase interleaved
// K-step: stage quarters of tile t+1 are issued BETWEEN the 16-MFMA phase
// clusters, so DMA-writes / ds_reads / MFMA overlap in one wave's program
// order instead of bursting at the barrier.
// Wait discipline: vmcnt(2) = {8 loads of tile t issued last step} landed,
// {2 loads of quarter0(t+1) just issued} in flight; the s_barrier AFTER the
// wait makes the per-wave guarantee collective. Stages only write buf^1;
// readers of buf^1 finished before the PREVIOUS step's end barrier.
__global__ __launch_bounds__(512, 2) void gemm256_kernel(
    const bf16* __restrict__ A, const bf16* __restrict__ Bm,
    const float* __restrict__ bi, float* __restrict__ C, int K, int N)
{
  int nwg = (int)gridDim.x;
  int per = nwg >> 3;
  int bid = (int)blockIdx.x;
  int tl  = (bid & 7) * per + (bid >> 3);   // chunked XCD swizzle (nwg%8==0)
  int mi  = tl & 7, ni = tl >> 3;

  __shared__ __align__(16) char lds[2][65536];

  int tid = threadIdx.x;
  int lane = tid & 63, wid = tid >> 6;
  int wr = wid >> 2, wc = wid & 3;          // 2 x 4 waves
  int fr = lane & 15, fb = lane >> 4;

  const bf16* Asrc = A  + (size_t)(mi * 256) * K;
  const bf16* Bsrc = Bm + (size_t)(ni * 256) * K;

  int NT = K >> 6;   // 16

  // one quarter = (h, is): 64 rows x 64 cols of A and of B (8 KB each)
#define STGQ(buf, kk, h, is)                                               \
  {                                                                        \
    int ri  = (is) * 64 + (tid >> 3);                                      \
    int ck  = (tid & 7) ^ (ri & 7);                                        \
    int row = (h) * 128 + ri;                                              \
    GL2LDS(Asrc + (size_t)row * K + (kk) + ck * 8,                         \
           lds[buf] + (h) * 16384 + (is) * 8192 + tid * 16);               \
    GL2LDS(Bsrc + (size_t)row * K + (kk) + ck * 8,                         \
           lds[buf] + 32768 + (h) * 16384 + (is) * 8192 + tid * 16);       \
  }

  f32x4 acc[8][4];
#pragma unroll
  for (int i = 0; i < 8; ++i)
#pragma unroll
    for (int j = 0; j < 4; ++j) acc[i][j] = (f32x4){0.f, 0.f, 0.f, 0.f};

  // prologue: stage tile 0 fully (8 loads)
  STGQ(0, 0, 0, 0); STGQ(0, 0, 0, 1); STGQ(0, 0, 1, 0); STGQ(0, 0, 1, 1);

  for (int t = 0; t < NT; ++t) {
    int buf = t & 1;
    int nk  = (t + 1) << 6;
    bool pf = (t + 1 < NT);

    if (pf) {
      STGQ(buf ^ 1, nk, 0, 0);
      asm volatile("s_waitcnt vmcnt(2)" ::: "memory");   // tile t landed
    } else {
      asm volatile("s_waitcnt vmcnt(0)" ::: "memory");
    }
    __builtin_amdgcn_s_barrier();
    asm volatile("" ::: "memory");

    const char* Ab = lds[buf];
    const char* Bb = lds[buf] + 32768;

    bf16x8 bfr[4][2];
#pragma unroll
    for (int n2 = 0; n2 < 4; ++n2) {
      int row = wc * 64 + n2 * 16 + fr;
#pragma unroll
      for (int ks = 0; ks < 2; ++ks)
        bfr[n2][ks] = *(const bf16x8*)(Bb + (row >> 7) * 16384 + (row & 127) * 128
                                          + ((((ks * 4 + fb) ^ (fr & 7))) << 4));
    }

#pragma unroll
    for (int q = 0; q < 4; ++q) {
      bf16x8 af[2][2];
#pragma unroll
      for (int m2 = 0; m2 < 2; ++m2) {
        int ri = (q * 2 + m2) * 16 + fr;    // within half wr
#pragma unroll
        for (int ks = 0; ks < 2; ++ks)
          af[m2][ks] = *(const bf16x8*)(Ab + wr * 16384 + ri * 128
                                           + ((((ks * 4 + fb) ^ (fr & 7))) << 4));
      }
      __builtin_amdgcn_s_setprio(1);
#pragma unroll
      for (int m2 = 0; m2 < 2; ++m2)
#pragma unroll
        for (int n2 = 0; n2 < 4; ++n2)
#pragma unroll
          for (int ks = 0; ks < 2; ++ks)
            acc[q * 2 + m2][n2] = __builtin_amdgcn_mfma_f32_16x16x32_bf16(
                af[m2][ks], bfr[n2][ks], acc[q * 2 + m2][n2], 0, 0, 0);
      __builtin_amdgcn_s_setprio(0);
      // interleave the next stage quarter between MFMA clusters
      if (pf && q == 0) STGQ(buf ^ 1, nk, 0, 1);
      if (pf && q == 1) STGQ(buf ^ 1, nk, 1, 0);
      if (pf && q == 2) STGQ(buf ^ 1, nk, 1, 1);
    }
    asm volatile("" ::: "memory");
    __builtin_amdgcn_s_barrier();   // reads of buf done before next step stages over it
  }
#undef STGQ

#pragma unroll
  for (int i = 0; i < 8; ++i) {
#pragma unroll
    for (int j = 0; j < 4; ++j) {
      int gc = ni * 256 + wc * 64 + j * 16 + fr;
      float bv = bi[gc];
#pragma unroll
      for (int r = 0; r < 4; ++r) {
        int gr = mi * 256 + wr * 128 + i * 16 + fb * 4 + r;
        C[(size_t)gr * N + gc] = acc[i][j][r] + bv;
      }
    }
  }
}

// ---------------------------------------------------------------- attention (bf16 MFMA flash)
__global__ __launch_bounds__(256) void attn_kernel(
    const bf16* __restrict__ q, const bf16* __restrict__ k,
    const bf16* __restrict__ v, float* __restrict__ x)
{
  __shared__ __align__(16) char Ks[8192];
  __shared__ __align__(16) char Vs[8192];
  __shared__ __align__(16) char Ps[8192];

  int tid = threadIdx.x, lane = tid & 63, w = tid >> 6;
  int qt = blockIdx.x, bh = blockIdx.y;
  int b = bh >> 4, h = bh & 15;
  size_t hoff = (size_t)b * T_ * E_ + h * HS_;
  int fr = lane & 15, fb = lane >> 4;

  bf16x8 qa[2];
  {
    const bf16* qp = q + hoff + (size_t)(qt * 64 + w * 16 + fr) * E_ + fb * 8;
    qa[0] = *(const bf16x8*)qp;
    qa[1] = *(const bf16x8*)(qp + 32);
  }

  f32x4 O[4];
  float m_[4], l_[4];
#pragma unroll
  for (int i = 0; i < 4; ++i) { O[i] = (f32x4){0.f,0.f,0.f,0.f}; m_[i] = -1e30f; l_[i] = 0.f; }

  for (int kt = 0; kt <= qt; ++kt) {
    __syncthreads();
    {
      const bf16* kbase = k + hoff + (size_t)(kt * 64) * E_;
#pragma unroll
      for (int is = 0; is < 2; ++is) {
        int c = is * 32 + (tid >> 3);
        int key = ((c & 7) ^ (c >> 3)) & 7;
        GL2LDS(kbase + (size_t)c * E_ + (((tid & 7) ^ key) * 8),
               Ks + is * 4096 + tid * 16);
      }
    }
#pragma unroll
    for (int p = 0; p < 2; ++p) {
      int row = tid >> 2;
      int d0 = (tid & 3) * 8 + p * 32;
      bf16x8 vv = *(const bf16x8*)(v + hoff + (size_t)(kt * 64 + row) * E_ + d0);
#pragma unroll
      for (int e = 0; e < 8; ++e) {
        int d = d0 + e;
        int key = ((d & 7) ^ (d >> 3)) & 7;
        *(bf16*)(Vs + d * 128 + ((row * 2) ^ (key << 4))) = vv[e];
      }
    }
    __syncthreads();

    f32x4 s[4];
#pragma unroll
    for (int jc = 0; jc < 4; ++jc) {
      s[jc] = (f32x4){0.f, 0.f, 0.f, 0.f};
#pragma unroll
      for (int kc = 0; kc < 2; ++kc) {
        int c = jc * 16 + fr;
        int key = ((c & 7) ^ (c >> 3)) & 7;
        bf16x8 kf = *(const bf16x8*)(Ks + c * 128 + ((kc * 64 + fb * 16) ^ (key << 4)));
        s[jc] = __builtin_amdgcn_mfma_f32_16x16x32_bf16(qa[kc], kf, s[jc], 0, 0, 0);
      }
    }

    char* pbase = Ps + w * 2048;
#pragma unroll
    for (int r = 0; r < 4; ++r) {
      float s0 = s[0][r] * SCALE_, s1 = s[1][r] * SCALE_;
      float s2 = s[2][r] * SCALE_, s3 = s[3][r] * SCALE_;
      int qrow = qt * 64 + w * 16 + fb * 4 + r;
      if (kt == qt) {
        int kc0 = kt * 64 + fr;
        if (kc0      > qrow) s0 = -1e30f;
        if (kc0 + 16 > qrow) s1 = -1e30f;
        if (kc0 + 32 > qrow) s2 = -1e30f;
        if (kc0 + 48 > qrow) s3 = -1e30f;
      }
      float mx = fmaxf(fmaxf(s0, s1), fmaxf(s2, s3));
      mx = fmaxf(mx, __shfl_xor(mx, 1, 16));
      mx = fmaxf(mx, __shfl_xor(mx, 2, 16));
      mx = fmaxf(mx, __shfl_xor(mx, 4, 16));
      mx = fmaxf(mx, __shfl_xor(mx, 8, 16));
      float mnew = fmaxf(m_[r], mx);
      float p0 = __expf(s0 - mnew), p1 = __expf(s1 - mnew);
      float p2 = __expf(s2 - mnew), p3 = __expf(s3 - mnew);
      float rs = p0 + p1 + p2 + p3;
      rs += __shfl_xor(rs, 1, 16);
      rs += __shfl_xor(rs, 2, 16);
      rs += __shfl_xor(rs, 4, 16);
      rs += __shfl_xor(rs, 8, 16);
      float scl = __expf(m_[r] - mnew);
      l_[r] = l_[r] * scl + rs;
      m_[r] = mnew;
#pragma unroll
      for (int jd = 0; jd < 4; ++jd) O[jd][r] *= scl;
      int key2 = (r << 4) ^ (fb << 5);
      char* pr_ = pbase + (fb * 4 + r) * 128;
      *(bf16*)(pr_ + (( 0 + fr * 2) ^ key2)) = (bf16)p0;
      *(bf16*)(pr_ + ((32 + fr * 2) ^ key2)) = (bf16)p1;
      *(bf16*)(pr_ + ((64 + fr * 2) ^ key2)) = (bf16)p2;
      *(bf16*)(pr_ + ((96 + fr * 2) ^ key2)) = (bf16)p3;
    }

#pragma unroll
    for (int kc = 0; kc < 2; ++kc) {
      int key2 = ((fr & 3) << 4) ^ ((fr >> 2) << 5);
      bf16x8 pa = *(const bf16x8*)(pbase + fr * 128 + ((kc * 64 + fb * 16) ^ key2));
#pragma unroll
      for (int jd = 0; jd < 4; ++jd) {
        int d = jd * 16 + fr;
        int key = ((d & 7) ^ (d >> 3)) & 7;
        bf16x8 vf = *(const bf16x8*)(Vs + d * 128 + ((kc * 64 + fb * 16) ^ (key << 4)));
        O[jd] = __builtin_amdgcn_mfma_f32_16x16x32_bf16(pa, vf, O[jd], 0, 0, 0);
      }
    }
  }

#pragma unroll
  for (int r = 0; r < 4; ++r) {
    float inv = 1.0f / l_[r];
    float* xp = x + hoff + (size_t)(qt * 64 + w * 16 + fb * 4 + r) * E_;
#pragma unroll
    for (int jd = 0; jd < 4; ++jd) {
      int d = jd * 16 + fr;
      xp[d] += O[jd][r] * inv;
    }
  }
}

// ---------------------------------------------------------------- launch
extern "C" void kernel_launch(void* const* d_in, const int* in_sizes, int n_in,
                              void* d_out, int out_size, void* d_ws, size_t ws_size,
                              hipStream_t stream)
{
  const int*   ids  = (const int*)  d_in[0];
  const float* emb  = (const float*)d_in[1];
  const float* pos  = (const float*)d_in[2];
  const float* wq   = (const float*)d_in[3];
  const float* bq   = (const float*)d_in[4];
  const float* wk   = (const float*)d_in[5];
  const float* bk   = (const float*)d_in[6];
  const float* wv   = (const float*)d_in[7];
  const float* bv   = (const float*)d_in[8];
  const float* w1   = (const float*)d_in[9];
  const float* b1   = (const float*)d_in[10];
  const float* w2   = (const float*)d_in[11];
  const float* b2   = (const float*)d_in[12];
  const float* ln1g = (const float*)d_in[13];
  const float* ln1b = (const float*)d_in[14];
  const float* ln2g = (const float*)d_in[15];
  const float* ln2b = (const float*)d_in[16];
  const float* pw   = (const float*)d_in[17];
  const float* pb   = (const float*)d_in[18];
  float* out = (float*)d_out;

  // ws layout (f32 units), non-overlapping in time (round-4-proven):
  //   x   [ 0M,  2M)  f32  BTxE
  //   hb  [ 2M,  3M)  bf16 BTxE      } fp [2M,6M) aliases hb..vb
  //   qb  [ 3M,  4M)  bf16 BTxE      }   (dead at FFN2 time)
  //   kb  [ 4M,  5M)  bf16 BTxE
  //   vb  [ 5M,  6M)  bf16 BTxE
  //   ffb [ 6M, 10M)  bf16 BTxFF
  //   lwb [10M,15.5M) bf16 layer weights
  //   xb  [16M, 17M)  bf16 BTxE
  //   pwb [ 0M,15.625M) bf16 proj weight (all below dead at proj time)
  // peak = 17M f32 = 68 MiB (round 1 proved ws >= 72 MiB)
  if (ws_size < (size_t)17 * 1024 * 1024 * 4) return;
  float* ws = (float*)d_ws;
  float* x   = ws;
  bf16*  hb  = (bf16*)(ws + (size_t) 2 * 1024 * 1024);
  bf16*  qb  = (bf16*)(ws + (size_t) 3 * 1024 * 1024);
  bf16*  kb  = (bf16*)(ws + (size_t) 4 * 1024 * 1024);
  bf16*  vb  = (bf16*)(ws + (size_t) 5 * 1024 * 1024);
  bf16*  ffb = (bf16*)(ws + (size_t) 6 * 1024 * 1024);
  float* fp  = ws + (size_t)2 * 1024 * 1024;          // 2 partials, 2M f32 each
  bf16*  lwb = (bf16*)(ws + (size_t)10 * 1024 * 1024);
  bf16*  xb  = (bf16*)(ws + (size_t)16 * 1024 * 1024);
  bf16*  pwb = (bf16*)ws;
  bf16*  wqt = lwb;
  bf16*  wkt = lwb + (size_t)1 * 1024 * 1024;
  bf16*  wvt = lwb + (size_t)2 * 1024 * 1024;
  bf16*  w1t = lwb + (size_t)3 * 1024 * 1024;
  bf16*  w2t = lwb + (size_t)7 * 1024 * 1024;

  embed_kernel<<<BT_, 256, 0, stream>>>(ids, emb, pos, x);

  for (int l = 0; l < L_; ++l) {
    const size_t lEE = (size_t)l * E_ * E_;
    const size_t lEF = (size_t)l * E_ * FF_;

    convw_kernel<<<dim3(E_/32, E_/32, 3), 256, 0, stream>>>(
        wq + lEE, wk + lEE, wv + lEE, wqt, wkt, wvt, E_, E_);
    convw_kernel<<<dim3(FF_/32, E_/32, 1), 256, 0, stream>>>(
        w1 + lEF, nullptr, nullptr, w1t, nullptr, nullptr, E_, FF_);
    convw_kernel<<<dim3(E_/32, FF_/32, 1), 256, 0, stream>>>(
        w2 + lEF, nullptr, nullptr, w2t, nullptr, nullptr, FF_, E_);

    ln_kernel<<<BT_, 256, 0, stream>>>(x, ln1g + l*E_, ln1b + l*E_, hb);

    gemm_bf16<0,1><<<dim3(16, E_/128, 3), 256, 0, stream>>>(
        hb, wqt, wkt, wvt, bq + l*E_, bk + l*E_, bv + l*E_,
        qb, kb, vb, nullptr, E_, E_, E_);

    attn_kernel<<<dim3(T_/64, B_*H_), 256, 0, stream>>>(qb, kb, vb, x);

    ln_kernel<<<BT_, 256, 0, stream>>>(x, ln2g + l*E_, ln2b + l*E_, hb);

    gemm_bf16<1,1><<<dim3(16, FF_/128, 1), 256, 0, stream>>>(
        hb, w1t, nullptr, nullptr, b1 + (size_t)l*FF_, nullptr, nullptr,
        ffb, nullptr, nullptr, nullptr, E_, FF_, E_);

    // FFN2: split-K=2 over blockIdx.z -> 256 blocks, then combine
    gemm_bf16<0,3><<<dim3(16, E_/128, 2), 256, 0, stream>>>(
        ffb, w2t, nullptr, nullptr, nullptr, nullptr, nullptr,
        nullptr, nullptr, nullptr, fp, FF_/2, E_, FF_);
    combine_kernel<<<BT_, 256, 0, stream>>>(fp, b2 + l*E_, x, xb);
  }

  // final projection: whole weight converted, 256^2 BK=64 4-phase GEMM
  convw_kernel<<<dim3(V_/32, E_/32, 1), 256, 0, stream>>>(
      pw, nullptr, nullptr, pwb, nullptr, nullptr, E_, V_);
  gemm256_kernel<<<(V_/256) * 8, 512, 0, stream>>>(
      xb, pwb, pb, out, E_, V_);
}

// Round 9
// 839.675 us; speedup vs baseline: 2.0903x; 1.0156x over previous
//
#include <hip/hip_runtime.h>
#include <hip/hip_bf16.h>
#include <cstdint>

#define B_    2
#define T_    1024
#define E_    1024
#define H_    16
#define HS_   64
#define L_    4
#define V_    32000
#define FF_   4096
#define BT_   2048
#define EPS_  1e-5f
#define SCALE_ 0.03125f   // 1/sqrt(E) = 1/32

typedef __bf16 bf16;
typedef bf16  bf16x4 __attribute__((ext_vector_type(4)));
typedef bf16  bf16x8 __attribute__((ext_vector_type(8)));
typedef float f32x4  __attribute__((ext_vector_type(4)));

#define GL2LDS(gp, lp) __builtin_amdgcn_global_load_lds( \
    (const __attribute__((address_space(1))) void*)(gp), \
    (__attribute__((address_space(3))) void*)(lp), 16, 0, 0)

// ---------------------------------------------------------------- embed
__global__ __launch_bounds__(256) void embed_kernel(
    const int* __restrict__ ids, const float* __restrict__ emb,
    const float* __restrict__ pos, float* __restrict__ x)
{
  int bt = blockIdx.x;
  int t  = bt & (T_ - 1);
  int id = ids[bt];
  f32x4 e = *(const f32x4*)(emb + (size_t)id * E_ + threadIdx.x * 4);
  f32x4 p = *(const f32x4*)(pos + (size_t)t  * E_ + threadIdx.x * 4);
  *(f32x4*)(x + (size_t)bt * E_ + threadIdx.x * 4) = e + p;
}

// ---------------------------------------------------------------- layernorm (f32 in, bf16 out)
__device__ __forceinline__ float wred_sum(float v) {
#pragma unroll
  for (int o = 32; o; o >>= 1) v += __shfl_xor(v, o, 64);
  return v;
}

__global__ __launch_bounds__(256) void ln_kernel(
    const float* __restrict__ x, const float* __restrict__ g,
    const float* __restrict__ b, bf16* __restrict__ h)
{
  int row = blockIdx.x, tid = threadIdx.x;
  f32x4 v = *(const f32x4*)(x + (size_t)row * E_ + tid * 4);
  float s  = v[0] + v[1] + v[2] + v[3];
  float sq = v[0]*v[0] + v[1]*v[1] + v[2]*v[2] + v[3]*v[3];
  s  = wred_sum(s);
  sq = wred_sum(sq);
  __shared__ float rs[4], rq[4];
  int w = tid >> 6, lane = tid & 63;
  if (lane == 0) { rs[w] = s; rq[w] = sq; }
  __syncthreads();
  float S = rs[0] + rs[1] + rs[2] + rs[3];
  float Q = rq[0] + rq[1] + rq[2] + rq[3];
  float mean = S * (1.0f / E_);
  float var  = Q * (1.0f / E_) - mean * mean;
  float rstd = rsqrtf(fmaxf(var, 0.0f) + EPS_);
  f32x4 gv = *(const f32x4*)(g + tid * 4);
  f32x4 bv = *(const f32x4*)(b + tid * 4);
  f32x4 o = (v - mean) * rstd * gv + bv;
  bf16x4 ob = { (bf16)o[0], (bf16)o[1], (bf16)o[2], (bf16)o[3] };
  *(bf16x4*)(h + (size_t)row * E_ + tid * 4) = ob;
}

// ---------------------------------------------------------------- weight transpose+convert
// W [K][N] f32 (row stride ldW) -> O [N][K] bf16
__global__ __launch_bounds__(256) void convw_kernel(
    const float* __restrict__ W0, const float* __restrict__ W1, const float* __restrict__ W2,
    bf16* __restrict__ O0, bf16* __restrict__ O1, bf16* __restrict__ O2,
    int K, int ldW)
{
  int z = blockIdx.z;
  const float* W = (z == 0) ? W0 : (z == 1) ? W1 : W2;
  bf16*        O = (z == 0) ? O0 : (z == 1) ? O1 : O2;
  __shared__ float tl[32][33];
  int n0 = blockIdx.x * 32, k0 = blockIdx.y * 32;
  int c = threadIdx.x & 31, r = threadIdx.x >> 5;
#pragma unroll
  for (int p = 0; p < 4; ++p)
    tl[r + p * 8][c] = W[(size_t)(k0 + r + p * 8) * ldW + n0 + c];
  __syncthreads();
#pragma unroll
  for (int p = 0; p < 4; ++p)
    O[(size_t)(n0 + r + p * 8) * K + k0 + c] = (bf16)tl[c][r + p * 8];
}

// ---------------------------------------------------------------- GEMM bf16 MFMA 128x128 (m97-style)
// A [M][LDK] bf16, B [N][LDK] bf16. BK=32, global_load_lds staging with
// XOR-pre-swizzled global source, double-buffered LDS, barrier/K-step.
// MODE 1: bf16 out (+bias, opt GELU). MODE 3: f32 split-K partial (blockIdx.z).
template <int ACT, int MODE>
__global__ __launch_bounds__(256) void gemm_bf16(
    const bf16* __restrict__ A,
    const bf16* __restrict__ B0, const bf16* __restrict__ B1, const bf16* __restrict__ B2,
    const float* __restrict__ bi0, const float* __restrict__ bi1, const float* __restrict__ bi2,
    bf16* __restrict__ Cb0, bf16* __restrict__ Cb1, bf16* __restrict__ Cb2,
    float* __restrict__ Cf,
    int K, int ldc, int LDK)
{
  int z = blockIdx.z;
  const bf16*  Bm = (MODE == 3) ? B0 : (z == 0) ? B0 : (z == 1) ? B1 : B2;
  const float* bi = (z == 0) ? bi0 : (z == 1) ? bi1 : bi2;
  bf16*        Cb = (z == 0) ? Cb0 : (z == 1) ? Cb1 : Cb2;
  int koff = (MODE == 3) ? z * K : 0;

  // chunked XCD swizzle (nb multiple of 8)
  int nb  = (int)(gridDim.x * gridDim.y);
  int lin = blockIdx.x + gridDim.x * blockIdx.y;
  int per = nb >> 3;
  int b   = (lin & 7) * per + (lin >> 3);
  int mi  = b & 15;            // gridDim.x == 16 always
  int ni  = b >> 4;

  __shared__ __align__(16) char lds[2][16384];  // [buf][A 8KB | B 8KB]

  int tid = threadIdx.x;
  int lane = tid & 63, wid = tid >> 6;
  int wm = (wid >> 1) * 64, wn = (wid & 1) * 64;
  int fr = lane & 15, fb = lane >> 4;

  const bf16* Asrc = A  + (size_t)(mi * 128) * LDK + koff;
  const bf16* Bsrc = Bm + (size_t)(ni * 128) * LDK + koff;

  int NT = K >> 5;

#define STAGE(buf, kk)                                                          \
  {                                                                             \
    _Pragma("unroll")                                                           \
    for (int is = 0; is < 2; ++is) {                                            \
      int rl = is * 64 + (tid >> 2);                                            \
      int key = (rl >> 1) & 3;                                                  \
      int ck  = ((tid & 3) ^ key) * 8;                                          \
      GL2LDS(Asrc + (size_t)rl * LDK + (kk) + ck,                               \
             lds[buf] + is * 4096 + tid * 16);                                  \
      GL2LDS(Bsrc + (size_t)rl * LDK + (kk) + ck,                               \
             lds[buf] + 8192 + is * 4096 + tid * 16);                           \
    }                                                                           \
  }

  f32x4 acc[4][4];
#pragma unroll
  for (int i = 0; i < 4; ++i)
#pragma unroll
    for (int j = 0; j < 4; ++j) acc[i][j] = (f32x4){0.f, 0.f, 0.f, 0.f};

  STAGE(0, 0);
  int cur = 0;

  for (int t = 0; t < NT; ++t) {
    __syncthreads();                       // drains vmcnt -> buf[cur] ready
    if (t + 1 < NT) STAGE(cur ^ 1, (t + 1) << 5);

    const char* Ab = lds[cur];
    const char* Bb = lds[cur] + 8192;
    bf16x8 af[4], bfr[4];
#pragma unroll
    for (int i = 0; i < 4; ++i) {
      int rl = wm + i * 16 + fr;
      af[i] = *(const bf16x8*)(Ab + rl * 64 + ((fb ^ ((rl >> 1) & 3)) * 16));
    }
#pragma unroll
    for (int j = 0; j < 4; ++j) {
      int rl = wn + j * 16 + fr;
      bfr[j] = *(const bf16x8*)(Bb + rl * 64 + ((fb ^ ((rl >> 1) & 3)) * 16));
    }
#pragma unroll
    for (int i = 0; i < 4; ++i)
#pragma unroll
      for (int j = 0; j < 4; ++j)
        acc[i][j] = __builtin_amdgcn_mfma_f32_16x16x32_bf16(af[i], bfr[j], acc[i][j], 0, 0, 0);
    cur ^= 1;
  }
#undef STAGE

  // epilogue: C/D layout col = lane&15, row = (lane>>4)*4 + reg
#pragma unroll
  for (int i = 0; i < 4; ++i) {
#pragma unroll
    for (int j = 0; j < 4; ++j) {
      int gc = ni * 128 + wn + j * 16 + fr;
      float bv = (MODE == 3) ? 0.f : bi[gc];
#pragma unroll
      for (int r = 0; r < 4; ++r) {
        int gr = mi * 128 + wm + i * 16 + fb * 4 + r;
        float vv = acc[i][j][r] + bv;
        if (ACT == 1) vv = 0.5f * vv * (1.0f + erff(vv * 0.70710678118654752f));
        if (MODE == 1) {
          Cb[(size_t)gr * ldc + gc] = (bf16)vv;
        } else {
          Cf[(size_t)(blockIdx.z * BT_ + gr) * ldc + gc] = vv;
        }
      }
    }
  }
}

// ---------------------------------------------------------------- FFN2 split-K combine (last layer)
// x += p0 + p1 + bias ; xb = bf16(x)
__global__ __launch_bounds__(256) void combine_kernel(
    const float* __restrict__ p, const float* __restrict__ bi,
    float* __restrict__ x, bf16* __restrict__ xb)
{
  int row = blockIdx.x, tid = threadIdx.x;
  size_t off = (size_t)row * E_ + tid * 4;
  f32x4 a = *(const f32x4*)(p + off);
  f32x4 c = *(const f32x4*)(p + (size_t)BT_ * E_ + off);
  f32x4 bv = *(const f32x4*)(bi + tid * 4);
  f32x4 xv = *(const f32x4*)(x + off);
  f32x4 nv = xv + a + c + bv;
  *(f32x4*)(x + off) = nv;
  bf16x4 ob = { (bf16)nv[0], (bf16)nv[1], (bf16)nv[2], (bf16)nv[3] };
  *(bf16x4*)(xb + off) = ob;
}

// ---------------------------------------------------------------- combine + next-layer ln1 fused
// x += p0+p1+bias ; h = LN(x_new) with next layer's gamma/beta
__global__ __launch_bounds__(256) void combine_ln_kernel(
    const float* __restrict__ p, const float* __restrict__ bi,
    const float* __restrict__ g, const float* __restrict__ b,
    float* __restrict__ x, bf16* __restrict__ h)
{
  int row = blockIdx.x, tid = threadIdx.x;
  size_t off = (size_t)row * E_ + tid * 4;
  f32x4 a = *(const f32x4*)(p + off);
  f32x4 c = *(const f32x4*)(p + (size_t)BT_ * E_ + off);
  f32x4 bv = *(const f32x4*)(bi + tid * 4);
  f32x4 xv = *(const f32x4*)(x + off);
  f32x4 nv = xv + a + c + bv;
  *(f32x4*)(x + off) = nv;

  float s  = nv[0] + nv[1] + nv[2] + nv[3];
  float sq = nv[0]*nv[0] + nv[1]*nv[1] + nv[2]*nv[2] + nv[3]*nv[3];
  s  = wred_sum(s);
  sq = wred_sum(sq);
  __shared__ float rs[4], rq[4];
  int w = tid >> 6, lane = tid & 63;
  if (lane == 0) { rs[w] = s; rq[w] = sq; }
  __syncthreads();
  float S = rs[0] + rs[1] + rs[2] + rs[3];
  float Q = rq[0] + rq[1] + rq[2] + rq[3];
  float mean = S * (1.0f / E_);
  float var  = Q * (1.0f / E_) - mean * mean;
  float rstd = rsqrtf(fmaxf(var, 0.0f) + EPS_);
  f32x4 gv = *(const f32x4*)(g + tid * 4);
  f32x4 bbv = *(const f32x4*)(b + tid * 4);
  f32x4 o = (nv - mean) * rstd * gv + bbv;
  bf16x4 ob = { (bf16)o[0], (bf16)o[1], (bf16)o[2], (bf16)o[3] };
  *(bf16x4*)(h + off) = ob;
}

// ---------------------------------------------------------------- GEMM bf16 MFMA 256x256, BK=64
// 512 thr (8 waves, 2Mx4N), 2 LDS buffers. Per-phase schedule (m201-style):
// each of 4 phases/tile = {ds_read frags ; stage half-unit ; [vmcnt at q3] ;
// s_barrier ; lgkmcnt(0)+sched_barrier ; setprio(1) 16xMFMA setprio(0) ;
// s_barrier}. Stage stream per tile: HB0,HB1,HA0,HA1 (2 loads each).
// During tile t: q0->(t+1).HA0, q1->(t+1).HA1, q2->(t+2).HB0, q3->(t+2).HB1.
// Safety (by region consumption): B rows of buf consumed at q0-mid;
// A-half rows offset [32q,32q+32) consumed at q-mid; every stage issues
// after its region's last reader + >=1 barrier. Publish tile t+1 at t.q3
// with vmcnt(4): the 4 loads of (t+2).HB0/HB1 stay in flight; (t+1).HA1
// has 2 phases (~700cy) of slack.
__global__ __launch_bounds__(512, 2) void gemm256_kernel(
    const bf16* __restrict__ A, const bf16* __restrict__ Bm,
    const float* __restrict__ bi, float* __restrict__ C, int K, int N)
{
  int nwg = (int)gridDim.x;
  int per = nwg >> 3;
  int bid = (int)blockIdx.x;
  int tl  = (bid & 7) * per + (bid >> 3);   // chunked XCD swizzle (nwg%8==0)
  int mi  = tl & 7, ni = tl >> 3;

  __shared__ __align__(16) char lds[2][65536];

  int tid = threadIdx.x;
  int lane = tid & 63, wid = tid >> 6;
  int wr = wid >> 2, wc = wid & 3;          // 2 x 4 waves
  int fr = lane & 15, fb = lane >> 4;

  const bf16* Asrc = A  + (size_t)(mi * 256) * K;
  const bf16* Bsrc = Bm + (size_t)(ni * 256) * K;

  int NT = K >> 6;   // 16

#define STG_A(buf, kk, h)                                                  \
  { _Pragma("unroll")                                                      \
    for (int is = 0; is < 2; ++is) {                                       \
      int ri  = is * 64 + (tid >> 3);                                      \
      int ck  = (tid & 7) ^ (ri & 7);                                      \
      int row = (h) * 128 + ri;                                            \
      GL2LDS(Asrc + (size_t)row * K + (kk) + ck * 8,                       \
             lds[buf] + (h) * 16384 + is * 8192 + tid * 16);               \
    } }
#define STG_B(buf, kk, h)                                                  \
  { _Pragma("unroll")                                                      \
    for (int is = 0; is < 2; ++is) {                                       \
      int ri  = is * 64 + (tid >> 3);                                      \
      int ck  = (tid & 7) ^ (ri & 7);                                      \
      int row = (h) * 128 + ri;                                            \
      GL2LDS(Bsrc + (size_t)row * K + (kk) + ck * 8,                       \
             lds[buf] + 32768 + (h) * 16384 + is * 8192 + tid * 16);       \
    } }

  f32x4 acc[8][4];
#pragma unroll
  for (int i = 0; i < 8; ++i)
#pragma unroll
    for (int j = 0; j < 4; ++j) acc[i][j] = (f32x4){0.f, 0.f, 0.f, 0.f};

  // prologue: tile0 full (B,B,A,A) + tile1's B halves; wait tile0 landed
  STG_B(0, 0, 0); STG_B(0, 0, 1); STG_A(0, 0, 0); STG_A(0, 0, 1);
  if (NT > 1) {
    STG_B(1, 64, 0); STG_B(1, 64, 1);
    asm volatile("s_waitcnt vmcnt(4)" ::: "memory");
  } else {
    asm volatile("s_waitcnt vmcnt(0)" ::: "memory");
  }
  __builtin_amdgcn_s_barrier();

  for (int t = 0; t < NT; ++t) {
    int buf = t & 1;
    int k1 = (t + 1) << 6, k2 = (t + 2) << 6;
    bool p1 = (t + 1 < NT), p2 = (t + 2 < NT);

    const char* Ab = lds[buf];
    const char* Bb = lds[buf] + 32768;

    bf16x8 bfr[4][2];
#pragma unroll
    for (int q = 0; q < 4; ++q) {
      if (q == 0) {
#pragma unroll
        for (int n2 = 0; n2 < 4; ++n2) {
          int row = wc * 64 + n2 * 16 + fr;
#pragma unroll
          for (int ks = 0; ks < 2; ++ks)
            bfr[n2][ks] = *(const bf16x8*)(Bb + (row >> 7) * 16384 + (row & 127) * 128
                                              + ((((ks * 4 + fb) ^ (fr & 7))) << 4));
        }
      }
      bf16x8 af[2][2];
#pragma unroll
      for (int m2 = 0; m2 < 2; ++m2) {
        int ri = (q * 2 + m2) * 16 + fr;
#pragma unroll
        for (int ks = 0; ks < 2; ++ks)
          af[m2][ks] = *(const bf16x8*)(Ab + wr * 16384 + ri * 128
                                           + ((((ks * 4 + fb) ^ (fr & 7))) << 4));
      }
      if (q == 0 && p1) STG_A(buf ^ 1, k1, 0);
      if (q == 1 && p1) STG_A(buf ^ 1, k1, 1);
      if (q == 2 && p2) STG_B(buf, k2, 0);
      if (q == 3 && p2) STG_B(buf, k2, 1);
      if (q == 3 && p1) {
        if (p2) asm volatile("s_waitcnt vmcnt(4)" ::: "memory");
        else    asm volatile("s_waitcnt vmcnt(0)" ::: "memory");
      }
      __builtin_amdgcn_s_barrier();
      asm volatile("s_waitcnt lgkmcnt(0)" ::: "memory");
      __builtin_amdgcn_sched_barrier(0);
      __builtin_amdgcn_s_setprio(1);
#pragma unroll
      for (int m2 = 0; m2 < 2; ++m2)
#pragma unroll
        for (int n2 = 0; n2 < 4; ++n2)
#pragma unroll
          for (int ks = 0; ks < 2; ++ks)
            acc[q * 2 + m2][n2] = __builtin_amdgcn_mfma_f32_16x16x32_bf16(
                af[m2][ks], bfr[n2][ks], acc[q * 2 + m2][n2], 0, 0, 0);
      __builtin_amdgcn_s_setprio(0);
      __builtin_amdgcn_s_barrier();
    }
  }
#undef STG_A
#undef STG_B

#pragma unroll
  for (int i = 0; i < 8; ++i) {
#pragma unroll
    for (int j = 0; j < 4; ++j) {
      int gc = ni * 256 + wc * 64 + j * 16 + fr;
      float bv = bi[gc];
#pragma unroll
      for (int r = 0; r < 4; ++r) {
        int gr = mi * 256 + wr * 128 + i * 16 + fb * 4 + r;
        C[(size_t)gr * N + gc] = acc[i][j][r] + bv;
      }
    }
  }
}

// ---------------------------------------------------------------- attention (bf16 MFMA flash)
__global__ __launch_bounds__(256) void attn_kernel(
    const bf16* __restrict__ q, const bf16* __restrict__ k,
    const bf16* __restrict__ v, float* __restrict__ x)
{
  __shared__ __align__(16) char Ks[8192];
  __shared__ __align__(16) char Vs[8192];
  __shared__ __align__(16) char Ps[8192];

  int tid = threadIdx.x, lane = tid & 63, w = tid >> 6;
  int qt = blockIdx.x, bh = blockIdx.y;
  int b = bh >> 4, h = bh & 15;
  size_t hoff = (size_t)b * T_ * E_ + h * HS_;
  int fr = lane & 15, fb = lane >> 4;

  bf16x8 qa[2];
  {
    const bf16* qp = q + hoff + (size_t)(qt * 64 + w * 16 + fr) * E_ + fb * 8;
    qa[0] = *(const bf16x8*)qp;
    qa[1] = *(const bf16x8*)(qp + 32);
  }

  f32x4 O[4];
  float m_[4], l_[4];
#pragma unroll
  for (int i = 0; i < 4; ++i) { O[i] = (f32x4){0.f,0.f,0.f,0.f}; m_[i] = -1e30f; l_[i] = 0.f; }

  for (int kt = 0; kt <= qt; ++kt) {
    __syncthreads();
    {
      const bf16* kbase = k + hoff + (size_t)(kt * 64) * E_;
#pragma unroll
      for (int is = 0; is < 2; ++is) {
        int c = is * 32 + (tid >> 3);
        int key = ((c & 7) ^ (c >> 3)) & 7;
        GL2LDS(kbase + (size_t)c * E_ + (((tid & 7) ^ key) * 8),
               Ks + is * 4096 + tid * 16);
      }
    }
#pragma unroll
    for (int p = 0; p < 2; ++p) {
      int row = tid >> 2;
      int d0 = (tid & 3) * 8 + p * 32;
      bf16x8 vv = *(const bf16x8*)(v + hoff + (size_t)(kt * 64 + row) * E_ + d0);
#pragma unroll
      for (int e = 0; e < 8; ++e) {
        int d = d0 + e;
        int key = ((d & 7) ^ (d >> 3)) & 7;
        *(bf16*)(Vs + d * 128 + ((row * 2) ^ (key << 4))) = vv[e];
      }
    }
    __syncthreads();

    f32x4 s[4];
#pragma unroll
    for (int jc = 0; jc < 4; ++jc) {
      s[jc] = (f32x4){0.f, 0.f, 0.f, 0.f};
#pragma unroll
      for (int kc = 0; kc < 2; ++kc) {
        int c = jc * 16 + fr;
        int key = ((c & 7) ^ (c >> 3)) & 7;
        bf16x8 kf = *(const bf16x8*)(Ks + c * 128 + ((kc * 64 + fb * 16) ^ (key << 4)));
        s[jc] = __builtin_amdgcn_mfma_f32_16x16x32_bf16(qa[kc], kf, s[jc], 0, 0, 0);
      }
    }

    char* pbase = Ps + w * 2048;
#pragma unroll
    for (int r = 0; r < 4; ++r) {
      float s0 = s[0][r] * SCALE_, s1 = s[1][r] * SCALE_;
      float s2 = s[2][r] * SCALE_, s3 = s[3][r] * SCALE_;
      int qrow = qt * 64 + w * 16 + fb * 4 + r;
      if (kt == qt) {
        int kc0 = kt * 64 + fr;
        if (kc0      > qrow) s0 = -1e30f;
        if (kc0 + 16 > qrow) s1 = -1e30f;
        if (kc0 + 32 > qrow) s2 = -1e30f;
        if (kc0 + 48 > qrow) s3 = -1e30f;
      }
      float mx = fmaxf(fmaxf(s0, s1), fmaxf(s2, s3));
      mx = fmaxf(mx, __shfl_xor(mx, 1, 16));
      mx = fmaxf(mx, __shfl_xor(mx, 2, 16));
      mx = fmaxf(mx, __shfl_xor(mx, 4, 16));
      mx = fmaxf(mx, __shfl_xor(mx, 8, 16));
      float mnew = fmaxf(m_[r], mx);
      float p0 = __expf(s0 - mnew), p1 = __expf(s1 - mnew);
      float p2 = __expf(s2 - mnew), p3 = __expf(s3 - mnew);
      float rs = p0 + p1 + p2 + p3;
      rs += __shfl_xor(rs, 1, 16);
      rs += __shfl_xor(rs, 2, 16);
      rs += __shfl_xor(rs, 4, 16);
      rs += __shfl_xor(rs, 8, 16);
      float scl = __expf(m_[r] - mnew);
      l_[r] = l_[r] * scl + rs;
      m_[r] = mnew;
#pragma unroll
      for (int jd = 0; jd < 4; ++jd) O[jd][r] *= scl;
      int key2 = (r << 4) ^ (fb << 5);
      char* pr_ = pbase + (fb * 4 + r) * 128;
      *(bf16*)(pr_ + (( 0 + fr * 2) ^ key2)) = (bf16)p0;
      *(bf16*)(pr_ + ((32 + fr * 2) ^ key2)) = (bf16)p1;
      *(bf16*)(pr_ + ((64 + fr * 2) ^ key2)) = (bf16)p2;
      *(bf16*)(pr_ + ((96 + fr * 2) ^ key2)) = (bf16)p3;
    }

#pragma unroll
    for (int kc = 0; kc < 2; ++kc) {
      int key2 = ((fr & 3) << 4) ^ ((fr >> 2) << 5);
      bf16x8 pa = *(const bf16x8*)(pbase + fr * 128 + ((kc * 64 + fb * 16) ^ key2));
#pragma unroll
      for (int jd = 0; jd < 4; ++jd) {
        int d = jd * 16 + fr;
        int key = ((d & 7) ^ (d >> 3)) & 7;
        bf16x8 vf = *(const bf16x8*)(Vs + d * 128 + ((kc * 64 + fb * 16) ^ (key << 4)));
        O[jd] = __builtin_amdgcn_mfma_f32_16x16x32_bf16(pa, vf, O[jd], 0, 0, 0);
      }
    }
  }

#pragma unroll
  for (int r = 0; r < 4; ++r) {
    float inv = 1.0f / l_[r];
    float* xp = x + hoff + (size_t)(qt * 64 + w * 16 + fb * 4 + r) * E_;
#pragma unroll
    for (int jd = 0; jd < 4; ++jd) {
      int d = jd * 16 + fr;
      xp[d] += O[jd][r] * inv;
    }
  }
}

// ---------------------------------------------------------------- launch
extern "C" void kernel_launch(void* const* d_in, const int* in_sizes, int n_in,
                              void* d_out, int out_size, void* d_ws, size_t ws_size,
                              hipStream_t stream)
{
  const int*   ids  = (const int*)  d_in[0];
  const float* emb  = (const float*)d_in[1];
  const float* pos  = (const float*)d_in[2];
  const float* wq   = (const float*)d_in[3];
  const float* bq   = (const float*)d_in[4];
  const float* wk   = (const float*)d_in[5];
  const float* bk   = (const float*)d_in[6];
  const float* wv   = (const float*)d_in[7];
  const float* bv   = (const float*)d_in[8];
  const float* w1   = (const float*)d_in[9];
  const float* b1   = (const float*)d_in[10];
  const float* w2   = (const float*)d_in[11];
  const float* b2   = (const float*)d_in[12];
  const float* ln1g = (const float*)d_in[13];
  const float* ln1b = (const float*)d_in[14];
  const float* ln2g = (const float*)d_in[15];
  const float* ln2b = (const float*)d_in[16];
  const float* pw   = (const float*)d_in[17];
  const float* pb   = (const float*)d_in[18];
  float* out = (float*)d_out;

  // ws layout (f32 units), non-overlapping in time (round-4-proven):
  //   x   [ 0M,  2M)  f32  BTxE
  //   hb  [ 2M,  3M)  bf16 BTxE      } fp [2M,6M) aliases hb..vb
  //   qb  [ 3M,  4M)  bf16 BTxE      }   (dead at FFN2 time; combine_ln
  //   kb  [ 4M,  5M)  bf16 BTxE      }    writes hb AFTER reading fp --
  //   vb  [ 5M,  6M)  bf16 BTxE      }    hb aliases fp0 -- see note)
  //   ffb [ 6M, 10M)  bf16 BTxFF
  //   lwb [10M,15.5M) bf16 layer weights
  //   xb  [16M, 17M)  bf16 BTxE
  //   pwb [ 0M,15.625M) bf16 proj weight (all below dead at proj time)
  // NOTE: combine_ln reads fp[row] fully into registers before writing
  // hb[row] (same kernel, same row, disjoint... hb overlaps fp0!). To be
  // safe, fp moved to [6M,10M)? ffb is ALSO dead at FFN2-output time? No:
  // ffb is the FFN2 INPUT (A matrix) -- live. fp stays at [2M,6M) but hb
  // must not alias fp: move hb usage for combine_ln output to qb region
  // is also fp... Instead fp uses [2M,6M) and combine_ln writes hb at
  // [2M,3M): row r reads fp0[r] (=[2M..)) then writes hb[r] -- PER-ROW
  // read-then-write within one thread, no cross-row deps: hb[r] bytes
  // [2M + r*512B) overlap fp0[r] bytes [2M + r*4KB).. different rows'
  // blocks overlap! UNSAFE. Fix: combine_ln writes hb2 at [15.5M,16M).
  if (ws_size < (size_t)17 * 1024 * 1024 * 4) return;
  float* ws = (float*)d_ws;
  float* x   = ws;
  bf16*  hb  = (bf16*)(ws + (size_t) 2 * 1024 * 1024);
  bf16*  qb  = (bf16*)(ws + (size_t) 3 * 1024 * 1024);
  bf16*  kb  = (bf16*)(ws + (size_t) 4 * 1024 * 1024);
  bf16*  vb  = (bf16*)(ws + (size_t) 5 * 1024 * 1024);
  bf16*  ffb = (bf16*)(ws + (size_t) 6 * 1024 * 1024);
  float* fp  = ws + (size_t)2 * 1024 * 1024;          // 2 partials, 2M f32 each
  bf16*  lwb = (bf16*)(ws + (size_t)10 * 1024 * 1024);
  bf16*  hb2 = (bf16*)(ws + (size_t)15 * 1024 * 1024 + 512 * 1024);  // [15.5M,16M)
  bf16*  xb  = (bf16*)(ws + (size_t)16 * 1024 * 1024);
  bf16*  pwb = (bf16*)ws;
  bf16*  wqt = lwb;
  bf16*  wkt = lwb + (size_t)1 * 1024 * 1024;
  bf16*  wvt = lwb + (size_t)2 * 1024 * 1024;
  bf16*  w1t = lwb + (size_t)3 * 1024 * 1024;
  bf16*  w2t = lwb + (size_t)7 * 1024 * 1024;
  // lwb holds: wqt 1M, wkt 1M, wvt 1M, w1t 4M, w2t 4M bf16 = 11M bf16 =
  // 5.5M f32 -> [10M, 15.5M). hb2 at [15.5M,16M) is free. pwb (proj, 16M
  // bf16 = 8M f32 = [0M,8M)... actually 32000*1024 bf16 = 15.625M f32
  // [0,15.625M) overlaps lwb tail! At proj time lwb is dead. hb2/xb above
  // 15.625M: hb2 [15.5M,16M) overlaps pwb tail [15.5M,15.625M)!! hb2 is
  // dead at proj time (only used between layers). xb at [16M,17M) safe.

  embed_kernel<<<BT_, 256, 0, stream>>>(ids, emb, pos, x);
  ln_kernel<<<BT_, 256, 0, stream>>>(x, ln1g, ln1b, hb);

  for (int l = 0; l < L_; ++l) {
    const size_t lEE = (size_t)l * E_ * E_;
    const size_t lEF = (size_t)l * E_ * FF_;
    const bf16* hcur = (l == 0) ? hb : hb2;   // layer-0 ln1 wrote hb; fused writes hb2

    convw_kernel<<<dim3(E_/32, E_/32, 3), 256, 0, stream>>>(
        wq + lEE, wk + lEE, wv + lEE, wqt, wkt, wvt, E_, E_);
    convw_kernel<<<dim3(FF_/32, E_/32, 1), 256, 0, stream>>>(
        w1 + lEF, nullptr, nullptr, w1t, nullptr, nullptr, E_, FF_);
    convw_kernel<<<dim3(E_/32, FF_/32, 1), 256, 0, stream>>>(
        w2 + lEF, nullptr, nullptr, w2t, nullptr, nullptr, FF_, E_);

    gemm_bf16<0,1><<<dim3(16, E_/128, 3), 256, 0, stream>>>(
        hcur, wqt, wkt, wvt, bq + l*E_, bk + l*E_, bv + l*E_,
        qb, kb, vb, nullptr, E_, E_, E_);

    attn_kernel<<<dim3(T_/64, B_*H_), 256, 0, stream>>>(qb, kb, vb, x);

    ln_kernel<<<BT_, 256, 0, stream>>>(x, ln2g + l*E_, ln2b + l*E_, hb);

    gemm_bf16<1,1><<<dim3(16, FF_/128, 1), 256, 0, stream>>>(
        hb, w1t, nullptr, nullptr, b1 + (size_t)l*FF_, nullptr, nullptr,
        ffb, nullptr, nullptr, nullptr, E_, FF_, E_);

    // FFN2: split-K=2 over blockIdx.z -> 256 blocks, then fused combine
    gemm_bf16<0,3><<<dim3(16, E_/128, 2), 256, 0, stream>>>(
        ffb, w2t, nullptr, nullptr, nullptr, nullptr, nullptr,
        nullptr, nullptr, nullptr, fp, FF_/2, E_, FF_);
    if (l < L_ - 1) {
      combine_ln_kernel<<<BT_, 256, 0, stream>>>(
          fp, b2 + l*E_, ln1g + (l+1)*E_, ln1b + (l+1)*E_, x, hb2);
    } else {
      combine_kernel<<<BT_, 256, 0, stream>>>(fp, b2 + l*E_, x, xb);
    }
  }

  // final projection: whole weight converted, 256^2 BK=64 per-phase GEMM
  convw_kernel<<<dim3(V_/32, E_/32, 1), 256, 0, stream>>>(
      pw, nullptr, nullptr, pwb, nullptr, nullptr, E_, V_);
  gemm256_kernel<<<(V_/256) * 8, 512, 0, stream>>>(
      xb, pwb, pb, out, E_, V_);
}

// Round 10
// 830.298 us; speedup vs baseline: 2.1139x; 1.0113x over previous
//
#include <hip/hip_runtime.h>
#include <hip/hip_bf16.h>
#include <cstdint>

#define B_    2
#define T_    1024
#define E_    1024
#define H_    16
#define HS_   64
#define L_    4
#define V_    32000
#define FF_   4096
#define BT_   2048
#define EPS_  1e-5f
#define SCALE_ 0.03125f   // 1/sqrt(E) = 1/32

typedef __bf16 bf16;
typedef bf16  bf16x4 __attribute__((ext_vector_type(4)));
typedef bf16  bf16x8 __attribute__((ext_vector_type(8)));
typedef float f32x4  __attribute__((ext_vector_type(4)));

#define GL2LDS(gp, lp) __builtin_amdgcn_global_load_lds( \
    (const __attribute__((address_space(1))) void*)(gp), \
    (__attribute__((address_space(3))) void*)(lp), 16, 0, 0)

// ---------------------------------------------------------------- layernorm helper
__device__ __forceinline__ float wred_sum(float v) {
#pragma unroll
  for (int o = 32; o; o >>= 1) v += __shfl_xor(v, o, 64);
  return v;
}

__device__ __forceinline__ void ln_body(
    f32x4 v, const float* g, const float* b, bf16* h, size_t off, int tid)
{
  float s  = v[0] + v[1] + v[2] + v[3];
  float sq = v[0]*v[0] + v[1]*v[1] + v[2]*v[2] + v[3]*v[3];
  s  = wred_sum(s);
  sq = wred_sum(sq);
  __shared__ float rs[4], rq[4];
  int w = tid >> 6, lane = tid & 63;
  if (lane == 0) { rs[w] = s; rq[w] = sq; }
  __syncthreads();
  float S = rs[0] + rs[1] + rs[2] + rs[3];
  float Q = rq[0] + rq[1] + rq[2] + rq[3];
  float mean = S * (1.0f / E_);
  float var  = Q * (1.0f / E_) - mean * mean;
  float rstd = rsqrtf(fmaxf(var, 0.0f) + EPS_);
  f32x4 gv = *(const f32x4*)(g + tid * 4);
  f32x4 bv = *(const f32x4*)(b + tid * 4);
  f32x4 o = (v - mean) * rstd * gv + bv;
  bf16x4 ob = { (bf16)o[0], (bf16)o[1], (bf16)o[2], (bf16)o[3] };
  *(bf16x4*)(h + off) = ob;
}

// ---------------------------------------------------------------- embed + ln1(layer0) fused
__global__ __launch_bounds__(256) void embed_ln_kernel(
    const int* __restrict__ ids, const float* __restrict__ emb,
    const float* __restrict__ pos, const float* __restrict__ g,
    const float* __restrict__ b, float* __restrict__ x, bf16* __restrict__ h)
{
  int bt = blockIdx.x, tid = threadIdx.x;
  int t  = bt & (T_ - 1);
  int id = ids[bt];
  f32x4 e = *(const f32x4*)(emb + (size_t)id * E_ + tid * 4);
  f32x4 p = *(const f32x4*)(pos + (size_t)t  * E_ + tid * 4);
  f32x4 v = e + p;
  size_t off = (size_t)bt * E_ + tid * 4;
  *(f32x4*)(x + off) = v;
  ln_body(v, g, b, h, off, tid);
}

// ---------------------------------------------------------------- layernorm (f32 in, bf16 out)
__global__ __launch_bounds__(256) void ln_kernel(
    const float* __restrict__ x, const float* __restrict__ g,
    const float* __restrict__ b, bf16* __restrict__ h)
{
  int row = blockIdx.x, tid = threadIdx.x;
  size_t off = (size_t)row * E_ + tid * 4;
  f32x4 v = *(const f32x4*)(x + off);
  ln_body(v, g, b, h, off, tid);
}

// ---------------------------------------------------------------- weight transpose+convert
// W [K][N] f32 (row stride ldW) -> O [N][K] bf16
__global__ __launch_bounds__(256) void convw_kernel(
    const float* __restrict__ W0, const float* __restrict__ W1, const float* __restrict__ W2,
    bf16* __restrict__ O0, bf16* __restrict__ O1, bf16* __restrict__ O2,
    int K, int ldW)
{
  int z = blockIdx.z;
  const float* W = (z == 0) ? W0 : (z == 1) ? W1 : W2;
  bf16*        O = (z == 0) ? O0 : (z == 1) ? O1 : O2;
  __shared__ float tl[32][33];
  int n0 = blockIdx.x * 32, k0 = blockIdx.y * 32;
  int c = threadIdx.x & 31, r = threadIdx.x >> 5;
#pragma unroll
  for (int p = 0; p < 4; ++p)
    tl[r + p * 8][c] = W[(size_t)(k0 + r + p * 8) * ldW + n0 + c];
  __syncthreads();
#pragma unroll
  for (int p = 0; p < 4; ++p)
    O[(size_t)(n0 + r + p * 8) * K + k0 + c] = (bf16)tl[c][r + p * 8];
}

// ---------------------------------------------------------------- GEMM bf16 MFMA 128x128 (m97-style)
// A [M][LDK] bf16, B [N][LDK] bf16. BK=32, global_load_lds staging with
// XOR-pre-swizzled global source, double-buffered LDS, barrier/K-step.
// MODE 1: bf16 out (+bias, opt GELU). MODE 3: f32 split-K partial (blockIdx.z).
template <int ACT, int MODE>
__global__ __launch_bounds__(256) void gemm_bf16(
    const bf16* __restrict__ A,
    const bf16* __restrict__ B0, const bf16* __restrict__ B1, const bf16* __restrict__ B2,
    const float* __restrict__ bi0, const float* __restrict__ bi1, const float* __restrict__ bi2,
    bf16* __restrict__ Cb0, bf16* __restrict__ Cb1, bf16* __restrict__ Cb2,
    float* __restrict__ Cf,
    int K, int ldc, int LDK)
{
  int z = blockIdx.z;
  const bf16*  Bm = (MODE == 3) ? B0 : (z == 0) ? B0 : (z == 1) ? B1 : B2;
  const float* bi = (z == 0) ? bi0 : (z == 1) ? bi1 : bi2;
  bf16*        Cb = (z == 0) ? Cb0 : (z == 1) ? Cb1 : Cb2;
  int koff = (MODE == 3) ? z * K : 0;

  // chunked XCD swizzle (nb multiple of 8)
  int nb  = (int)(gridDim.x * gridDim.y);
  int lin = blockIdx.x + gridDim.x * blockIdx.y;
  int per = nb >> 3;
  int b   = (lin & 7) * per + (lin >> 3);
  int mi  = b & 15;            // gridDim.x == 16 always
  int ni  = b >> 4;

  __shared__ __align__(16) char lds[2][16384];  // [buf][A 8KB | B 8KB]

  int tid = threadIdx.x;
  int lane = tid & 63, wid = tid >> 6;
  int wm = (wid >> 1) * 64, wn = (wid & 1) * 64;
  int fr = lane & 15, fb = lane >> 4;

  const bf16* Asrc = A  + (size_t)(mi * 128) * LDK + koff;
  const bf16* Bsrc = Bm + (size_t)(ni * 128) * LDK + koff;

  int NT = K >> 5;

#define STAGE(buf, kk)                                                          \
  {                                                                             \
    _Pragma("unroll")                                                           \
    for (int is = 0; is < 2; ++is) {                                            \
      int rl = is * 64 + (tid >> 2);                                            \
      int key = (rl >> 1) & 3;                                                  \
      int ck  = ((tid & 3) ^ key) * 8;                                          \
      GL2LDS(Asrc + (size_t)rl * LDK + (kk) + ck,                               \
             lds[buf] + is * 4096 + tid * 16);                                  \
      GL2LDS(Bsrc + (size_t)rl * LDK + (kk) + ck,                               \
             lds[buf] + 8192 + is * 4096 + tid * 16);                           \
    }                                                                           \
  }

  f32x4 acc[4][4];
#pragma unroll
  for (int i = 0; i < 4; ++i)
#pragma unroll
    for (int j = 0; j < 4; ++j) acc[i][j] = (f32x4){0.f, 0.f, 0.f, 0.f};

  STAGE(0, 0);
  int cur = 0;

  for (int t = 0; t < NT; ++t) {
    __syncthreads();                       // drains vmcnt -> buf[cur] ready
    if (t + 1 < NT) STAGE(cur ^ 1, (t + 1) << 5);

    const char* Ab = lds[cur];
    const char* Bb = lds[cur] + 8192;
    bf16x8 af[4], bfr[4];
#pragma unroll
    for (int i = 0; i < 4; ++i) {
      int rl = wm + i * 16 + fr;
      af[i] = *(const bf16x8*)(Ab + rl * 64 + ((fb ^ ((rl >> 1) & 3)) * 16));
    }
#pragma unroll
    for (int j = 0; j < 4; ++j) {
      int rl = wn + j * 16 + fr;
      bfr[j] = *(const bf16x8*)(Bb + rl * 64 + ((fb ^ ((rl >> 1) & 3)) * 16));
    }
#pragma unroll
    for (int i = 0; i < 4; ++i)
#pragma unroll
      for (int j = 0; j < 4; ++j)
        acc[i][j] = __builtin_amdgcn_mfma_f32_16x16x32_bf16(af[i], bfr[j], acc[i][j], 0, 0, 0);
    cur ^= 1;
  }
#undef STAGE

  // epilogue: C/D layout col = lane&15, row = (lane>>4)*4 + reg
#pragma unroll
  for (int i = 0; i < 4; ++i) {
#pragma unroll
    for (int j = 0; j < 4; ++j) {
      int gc = ni * 128 + wn + j * 16 + fr;
      float bv = (MODE == 3) ? 0.f : bi[gc];
#pragma unroll
      for (int r = 0; r < 4; ++r) {
        int gr = mi * 128 + wm + i * 16 + fb * 4 + r;
        float vv = acc[i][j][r] + bv;
        if (ACT == 1) vv = 0.5f * vv * (1.0f + erff(vv * 0.70710678118654752f));
        if (MODE == 1) {
          Cb[(size_t)gr * ldc + gc] = (bf16)vv;
        } else {
          Cf[(size_t)(blockIdx.z * BT_ + gr) * ldc + gc] = vv;
        }
      }
    }
  }
}

// ---------------------------------------------------------------- FFN2 split-K combine (last layer)
// x += p0 + p1 + bias ; xb = bf16(x)
__global__ __launch_bounds__(256) void combine_kernel(
    const float* __restrict__ p, const float* __restrict__ bi,
    float* __restrict__ x, bf16* __restrict__ xb)
{
  int row = blockIdx.x, tid = threadIdx.x;
  size_t off = (size_t)row * E_ + tid * 4;
  f32x4 a = *(const f32x4*)(p + off);
  f32x4 c = *(const f32x4*)(p + (size_t)BT_ * E_ + off);
  f32x4 bv = *(const f32x4*)(bi + tid * 4);
  f32x4 xv = *(const f32x4*)(x + off);
  f32x4 nv = xv + a + c + bv;
  *(f32x4*)(x + off) = nv;
  bf16x4 ob = { (bf16)nv[0], (bf16)nv[1], (bf16)nv[2], (bf16)nv[3] };
  *(bf16x4*)(xb + off) = ob;
}

// ---------------------------------------------------------------- combine + next-layer ln1 fused
// x += p0+p1+bias ; h = LN(x_new) with next layer's gamma/beta
__global__ __launch_bounds__(256) void combine_ln_kernel(
    const float* __restrict__ p, const float* __restrict__ bi,
    const float* __restrict__ g, const float* __restrict__ b,
    float* __restrict__ x, bf16* __restrict__ h)
{
  int row = blockIdx.x, tid = threadIdx.x;
  size_t off = (size_t)row * E_ + tid * 4;
  f32x4 a = *(const f32x4*)(p + off);
  f32x4 c = *(const f32x4*)(p + (size_t)BT_ * E_ + off);
  f32x4 bv = *(const f32x4*)(bi + tid * 4);
  f32x4 xv = *(const f32x4*)(x + off);
  f32x4 nv = xv + a + c + bv;
  *(f32x4*)(x + off) = nv;
  ln_body(nv, g, b, h, off, tid);
}

// ---------------------------------------------------------------- GEMM bf16 MFMA 256x256, BK=64
// (round-8 proven version, 157us / 35.5% MfmaUtil)
// 512 thr (8 waves, 2Mx4N), 2 LDS buffers (128 KiB). 4-phase interleaved
// K-step: stage quarters of tile t+1 are issued BETWEEN the 16-MFMA phase
// clusters. vmcnt(2) = tile t's 8 loads landed, quarter0(t+1) in flight;
// the s_barrier after the wait makes it collective. Stages only write
// buf^1; readers of buf^1 finished before the PREVIOUS step's end barrier.
__global__ __launch_bounds__(512, 2) void gemm256_kernel(
    const bf16* __restrict__ A, const bf16* __restrict__ Bm,
    const float* __restrict__ bi, float* __restrict__ C, int K, int N)
{
  int nwg = (int)gridDim.x;
  int per = nwg >> 3;
  int bid = (int)blockIdx.x;
  int tl  = (bid & 7) * per + (bid >> 3);   // chunked XCD swizzle (nwg%8==0)
  int mi  = tl & 7, ni = tl >> 3;

  __shared__ __align__(16) char lds[2][65536];

  int tid = threadIdx.x;
  int lane = tid & 63, wid = tid >> 6;
  int wr = wid >> 2, wc = wid & 3;          // 2 x 4 waves
  int fr = lane & 15, fb = lane >> 4;

  const bf16* Asrc = A  + (size_t)(mi * 256) * K;
  const bf16* Bsrc = Bm + (size_t)(ni * 256) * K;

  int NT = K >> 6;   // 16

  // one quarter = (h, is): 64 rows x 64 cols of A and of B (8 KB each)
#define STGQ(buf, kk, h, is)                                               \
  {                                                                        \
    int ri  = (is) * 64 + (tid >> 3);                                      \
    int ck  = (tid & 7) ^ (ri & 7);                                        \
    int row = (h) * 128 + ri;                                              \
    GL2LDS(Asrc + (size_t)row * K + (kk) + ck * 8,                         \
           lds[buf] + (h) * 16384 + (is) * 8192 + tid * 16);               \
    GL2LDS(Bsrc + (size_t)row * K + (kk) + ck * 8,                         \
           lds[buf] + 32768 + (h) * 16384 + (is) * 8192 + tid * 16);       \
  }

  f32x4 acc[8][4];
#pragma unroll
  for (int i = 0; i < 8; ++i)
#pragma unroll
    for (int j = 0; j < 4; ++j) acc[i][j] = (f32x4){0.f, 0.f, 0.f, 0.f};

  // prologue: stage tile 0 fully (8 loads)
  STGQ(0, 0, 0, 0); STGQ(0, 0, 0, 1); STGQ(0, 0, 1, 0); STGQ(0, 0, 1, 1);

  for (int t = 0; t < NT; ++t) {
    int buf = t & 1;
    int nk  = (t + 1) << 6;
    bool pf = (t + 1 < NT);

    if (pf) {
      STGQ(buf ^ 1, nk, 0, 0);
      asm volatile("s_waitcnt vmcnt(2)" ::: "memory");   // tile t landed
    } else {
      asm volatile("s_waitcnt vmcnt(0)" ::: "memory");
    }
    __builtin_amdgcn_s_barrier();
    asm volatile("" ::: "memory");

    const char* Ab = lds[buf];
    const char* Bb = lds[buf] + 32768;

    bf16x8 bfr[4][2];
#pragma unroll
    for (int n2 = 0; n2 < 4; ++n2) {
      int row = wc * 64 + n2 * 16 + fr;
#pragma unroll
      for (int ks = 0; ks < 2; ++ks)
        bfr[n2][ks] = *(const bf16x8*)(Bb + (row >> 7) * 16384 + (row & 127) * 128
                                          + ((((ks * 4 + fb) ^ (fr & 7))) << 4));
    }

#pragma unroll
    for (int q = 0; q < 4; ++q) {
      bf16x8 af[2][2];
#pragma unroll
      for (int m2 = 0; m2 < 2; ++m2) {
        int ri = (q * 2 + m2) * 16 + fr;    // within half wr
#pragma unroll
        for (int ks = 0; ks < 2; ++ks)
          af[m2][ks] = *(const bf16x8*)(Ab + wr * 16384 + ri * 128
                                           + ((((ks * 4 + fb) ^ (fr & 7))) << 4));
      }
      __builtin_amdgcn_s_setprio(1);
#pragma unroll
      for (int m2 = 0; m2 < 2; ++m2)
#pragma unroll
        for (int n2 = 0; n2 < 4; ++n2)
#pragma unroll
          for (int ks = 0; ks < 2; ++ks)
            acc[q * 2 + m2][n2] = __builtin_amdgcn_mfma_f32_16x16x32_bf16(
                af[m2][ks], bfr[n2][ks], acc[q * 2 + m2][n2], 0, 0, 0);
      __builtin_amdgcn_s_setprio(0);
      // interleave the next stage quarter between MFMA clusters
      if (pf && q == 0) STGQ(buf ^ 1, nk, 0, 1);
      if (pf && q == 1) STGQ(buf ^ 1, nk, 1, 0);
      if (pf && q == 2) STGQ(buf ^ 1, nk, 1, 1);
    }
    asm volatile("" ::: "memory");
    __builtin_amdgcn_s_barrier();   // reads of buf done before next step stages over it
  }
#undef STGQ

#pragma unroll
  for (int i = 0; i < 8; ++i) {
#pragma unroll
    for (int j = 0; j < 4; ++j) {
      int gc = ni * 256 + wc * 64 + j * 16 + fr;
      float bv = bi[gc];
#pragma unroll
      for (int r = 0; r < 4; ++r) {
        int gr = mi * 256 + wr * 128 + i * 16 + fb * 4 + r;
        C[(size_t)gr * N + gc] = acc[i][j][r] + bv;
      }
    }
  }
}

// ---------------------------------------------------------------- attention (bf16 MFMA flash)
// qt remapped descending: heavy (long-causal) blocks dispatch first ->
// better makespan under the 2-blocks/CU schedule.
__global__ __launch_bounds__(256) void attn_kernel(
    const bf16* __restrict__ q, const bf16* __restrict__ k,
    const bf16* __restrict__ v, float* __restrict__ x)
{
  __shared__ __align__(16) char Ks[8192];
  __shared__ __align__(16) char Vs[8192];
  __shared__ __align__(16) char Ps[8192];

  int tid = threadIdx.x, lane = tid & 63, w = tid >> 6;
  int qt = (int)gridDim.x - 1 - (int)blockIdx.x;   // heavy first
  int bh = blockIdx.y;
  int b = bh >> 4, h = bh & 15;
  size_t hoff = (size_t)b * T_ * E_ + h * HS_;
  int fr = lane & 15, fb = lane >> 4;

  bf16x8 qa[2];
  {
    const bf16* qp = q + hoff + (size_t)(qt * 64 + w * 16 + fr) * E_ + fb * 8;
    qa[0] = *(const bf16x8*)qp;
    qa[1] = *(const bf16x8*)(qp + 32);
  }

  f32x4 O[4];
  float m_[4], l_[4];
#pragma unroll
  for (int i = 0; i < 4; ++i) { O[i] = (f32x4){0.f,0.f,0.f,0.f}; m_[i] = -1e30f; l_[i] = 0.f; }

  for (int kt = 0; kt <= qt; ++kt) {
    __syncthreads();
    {
      const bf16* kbase = k + hoff + (size_t)(kt * 64) * E_;
#pragma unroll
      for (int is = 0; is < 2; ++is) {
        int c = is * 32 + (tid >> 3);
        int key = ((c & 7) ^ (c >> 3)) & 7;
        GL2LDS(kbase + (size_t)c * E_ + (((tid & 7) ^ key) * 8),
               Ks + is * 4096 + tid * 16);
      }
    }
#pragma unroll
    for (int p = 0; p < 2; ++p) {
      int row = tid >> 2;
      int d0 = (tid & 3) * 8 + p * 32;
      bf16x8 vv = *(const bf16x8*)(v + hoff + (size_t)(kt * 64 + row) * E_ + d0);
#pragma unroll
      for (int e = 0; e < 8; ++e) {
        int d = d0 + e;
        int key = ((d & 7) ^ (d >> 3)) & 7;
        *(bf16*)(Vs + d * 128 + ((row * 2) ^ (key << 4))) = vv[e];
      }
    }
    __syncthreads();

    f32x4 s[4];
#pragma unroll
    for (int jc = 0; jc < 4; ++jc) {
      s[jc] = (f32x4){0.f, 0.f, 0.f, 0.f};
#pragma unroll
      for (int kc = 0; kc < 2; ++kc) {
        int c = jc * 16 + fr;
        int key = ((c & 7) ^ (c >> 3)) & 7;
        bf16x8 kf = *(const bf16x8*)(Ks + c * 128 + ((kc * 64 + fb * 16) ^ (key << 4)));
        s[jc] = __builtin_amdgcn_mfma_f32_16x16x32_bf16(qa[kc], kf, s[jc], 0, 0, 0);
      }
    }

    char* pbase = Ps + w * 2048;
#pragma unroll
    for (int r = 0; r < 4; ++r) {
      float s0 = s[0][r] * SCALE_, s1 = s[1][r] * SCALE_;
      float s2 = s[2][r] * SCALE_, s3 = s[3][r] * SCALE_;
      int qrow = qt * 64 + w * 16 + fb * 4 + r;
      if (kt == qt) {
        int kc0 = kt * 64 + fr;
        if (kc0      > qrow) s0 = -1e30f;
        if (kc0 + 16 > qrow) s1 = -1e30f;
        if (kc0 + 32 > qrow) s2 = -1e30f;
        if (kc0 + 48 > qrow) s3 = -1e30f;
      }
      float mx = fmaxf(fmaxf(s0, s1), fmaxf(s2, s3));
      mx = fmaxf(mx, __shfl_xor(mx, 1, 16));
      mx = fmaxf(mx, __shfl_xor(mx, 2, 16));
      mx = fmaxf(mx, __shfl_xor(mx, 4, 16));
      mx = fmaxf(mx, __shfl_xor(mx, 8, 16));
      float mnew = fmaxf(m_[r], mx);
      float p0 = __expf(s0 - mnew), p1 = __expf(s1 - mnew);
      float p2 = __expf(s2 - mnew), p3 = __expf(s3 - mnew);
      float rs = p0 + p1 + p2 + p3;
      rs += __shfl_xor(rs, 1, 16);
      rs += __shfl_xor(rs, 2, 16);
      rs += __shfl_xor(rs, 4, 16);
      rs += __shfl_xor(rs, 8, 16);
      float scl = __expf(m_[r] - mnew);
      l_[r] = l_[r] * scl + rs;
      m_[r] = mnew;
#pragma unroll
      for (int jd = 0; jd < 4; ++jd) O[jd][r] *= scl;
      int key2 = (r << 4) ^ (fb << 5);
      char* pr_ = pbase + (fb * 4 + r) * 128;
      *(bf16*)(pr_ + (( 0 + fr * 2) ^ key2)) = (bf16)p0;
      *(bf16*)(pr_ + ((32 + fr * 2) ^ key2)) = (bf16)p1;
      *(bf16*)(pr_ + ((64 + fr * 2) ^ key2)) = (bf16)p2;
      *(bf16*)(pr_ + ((96 + fr * 2) ^ key2)) = (bf16)p3;
    }

#pragma unroll
    for (int kc = 0; kc < 2; ++kc) {
      int key2 = ((fr & 3) << 4) ^ ((fr >> 2) << 5);
      bf16x8 pa = *(const bf16x8*)(pbase + fr * 128 + ((kc * 64 + fb * 16) ^ key2));
#pragma unroll
      for (int jd = 0; jd < 4; ++jd) {
        int d = jd * 16 + fr;
        int key = ((d & 7) ^ (d >> 3)) & 7;
        bf16x8 vf = *(const bf16x8*)(Vs + d * 128 + ((kc * 64 + fb * 16) ^ (key << 4)));
        O[jd] = __builtin_amdgcn_mfma_f32_16x16x32_bf16(pa, vf, O[jd], 0, 0, 0);
      }
    }
  }

#pragma unroll
  for (int r = 0; r < 4; ++r) {
    float inv = 1.0f / l_[r];
    float* xp = x + hoff + (size_t)(qt * 64 + w * 16 + fb * 4 + r) * E_;
#pragma unroll
    for (int jd = 0; jd < 4; ++jd) {
      int d = jd * 16 + fr;
      xp[d] += O[jd][r] * inv;
    }
  }
}

// ---------------------------------------------------------------- launch
extern "C" void kernel_launch(void* const* d_in, const int* in_sizes, int n_in,
                              void* d_out, int out_size, void* d_ws, size_t ws_size,
                              hipStream_t stream)
{
  const int*   ids  = (const int*)  d_in[0];
  const float* emb  = (const float*)d_in[1];
  const float* pos  = (const float*)d_in[2];
  const float* wq   = (const float*)d_in[3];
  const float* bq   = (const float*)d_in[4];
  const float* wk   = (const float*)d_in[5];
  const float* bk   = (const float*)d_in[6];
  const float* wv   = (const float*)d_in[7];
  const float* bv   = (const float*)d_in[8];
  const float* w1   = (const float*)d_in[9];
  const float* b1   = (const float*)d_in[10];
  const float* w2   = (const float*)d_in[11];
  const float* b2   = (const float*)d_in[12];
  const float* ln1g = (const float*)d_in[13];
  const float* ln1b = (const float*)d_in[14];
  const float* ln2g = (const float*)d_in[15];
  const float* ln2b = (const float*)d_in[16];
  const float* pw   = (const float*)d_in[17];
  const float* pb   = (const float*)d_in[18];
  float* out = (float*)d_out;

  // ws layout (f32 units), non-overlapping in time (round-9-proven):
  //   x   [ 0M,  2M)  f32  BTxE
  //   hb  [ 2M,  3M)  bf16 BTxE      } fp [2M,6M) aliases hb..vb
  //   qb  [ 3M,  4M)  bf16 BTxE      }   (dead at FFN2 time)
  //   kb  [ 4M,  5M)  bf16 BTxE
  //   vb  [ 5M,  6M)  bf16 BTxE
  //   ffb [ 6M, 10M)  bf16 BTxFF
  //   lwb [10M,15.5M) bf16 layer weights
  //   hb2 [15.5M,16M) bf16 BTxE  (combine_ln output; dead at proj time)
  //   xb  [16M, 17M)  bf16 BTxE
  //   pwb [ 0M,15.625M) bf16 proj weight (all below dead at proj time)
  // peak = 17M f32 = 68 MiB (round 1 proved ws >= 72 MiB)
  if (ws_size < (size_t)17 * 1024 * 1024 * 4) return;
  float* ws = (float*)d_ws;
  float* x   = ws;
  bf16*  hb  = (bf16*)(ws + (size_t) 2 * 1024 * 1024);
  bf16*  qb  = (bf16*)(ws + (size_t) 3 * 1024 * 1024);
  bf16*  kb  = (bf16*)(ws + (size_t) 4 * 1024 * 1024);
  bf16*  vb  = (bf16*)(ws + (size_t) 5 * 1024 * 1024);
  bf16*  ffb = (bf16*)(ws + (size_t) 6 * 1024 * 1024);
  float* fp  = ws + (size_t)2 * 1024 * 1024;          // 2 partials, 2M f32 each
  bf16*  lwb = (bf16*)(ws + (size_t)10 * 1024 * 1024);
  bf16*  hb2 = (bf16*)(ws + (size_t)15 * 1024 * 1024 + 512 * 1024);  // [15.5M,16M)
  bf16*  xb  = (bf16*)(ws + (size_t)16 * 1024 * 1024);
  bf16*  pwb = (bf16*)ws;
  bf16*  wqt = lwb;
  bf16*  wkt = lwb + (size_t)1 * 1024 * 1024;
  bf16*  wvt = lwb + (size_t)2 * 1024 * 1024;
  bf16*  w1t = lwb + (size_t)3 * 1024 * 1024;
  bf16*  w2t = lwb + (size_t)7 * 1024 * 1024;

  embed_ln_kernel<<<BT_, 256, 0, stream>>>(ids, emb, pos, ln1g, ln1b, x, hb);

  for (int l = 0; l < L_; ++l) {
    const size_t lEE = (size_t)l * E_ * E_;
    const size_t lEF = (size_t)l * E_ * FF_;
    const bf16* hcur = (l == 0) ? hb : hb2;   // layer-0 ln1 wrote hb; fused writes hb2

    convw_kernel<<<dim3(E_/32, E_/32, 3), 256, 0, stream>>>(
        wq + lEE, wk + lEE, wv + lEE, wqt, wkt, wvt, E_, E_);
    convw_kernel<<<dim3(FF_/32, E_/32, 1), 256, 0, stream>>>(
        w1 + lEF, nullptr, nullptr, w1t, nullptr, nullptr, E_, FF_);
    convw_kernel<<<dim3(E_/32, FF_/32, 1), 256, 0, stream>>>(
        w2 + lEF, nullptr, nullptr, w2t, nullptr, nullptr, FF_, E_);

    gemm_bf16<0,1><<<dim3(16, E_/128, 3), 256, 0, stream>>>(
        hcur, wqt, wkt, wvt, bq + l*E_, bk + l*E_, bv + l*E_,
        qb, kb, vb, nullptr, E_, E_, E_);

    attn_kernel<<<dim3(T_/64, B_*H_), 256, 0, stream>>>(qb, kb, vb, x);

    ln_kernel<<<BT_, 256, 0, stream>>>(x, ln2g + l*E_, ln2b + l*E_, hb);

    gemm_bf16<1,1><<<dim3(16, FF_/128, 1), 256, 0, stream>>>(
        hb, w1t, nullptr, nullptr, b1 + (size_t)l*FF_, nullptr, nullptr,
        ffb, nullptr, nullptr, nullptr, E_, FF_, E_);

    // FFN2: split-K=2 over blockIdx.z -> 256 blocks, then fused combine
    gemm_bf16<0,3><<<dim3(16, E_/128, 2), 256, 0, stream>>>(
        ffb, w2t, nullptr, nullptr, nullptr, nullptr, nullptr,
        nullptr, nullptr, nullptr, fp, FF_/2, E_, FF_);
    if (l < L_ - 1) {
      combine_ln_kernel<<<BT_, 256, 0, stream>>>(
          fp, b2 + l*E_, ln1g + (l+1)*E_, ln1b + (l+1)*E_, x, hb2);
    } else {
      combine_kernel<<<BT_, 256, 0, stream>>>(fp, b2 + l*E_, x, xb);
    }
  }

  // final projection: whole weight converted, 256^2 BK=64 4-phase GEMM
  convw_kernel<<<dim3(V_/32, E_/32, 1), 256, 0, stream>>>(
      pw, nullptr, nullptr, pwb, nullptr, nullptr, E_, V_);
  gemm256_kernel<<<(V_/256) * 8, 512, 0, stream>>>(
      xb, pwb, pb, out, E_, V_);
}

// Round 11
// 823.704 us; speedup vs baseline: 2.1308x; 1.0080x over previous
//
#include <hip/hip_runtime.h>
#include <hip/hip_bf16.h>
#include <cstdint>

#define B_    2
#define T_    1024
#define E_    1024
#define H_    16
#define HS_   64
#define L_    4
#define V_    32000
#define FF_   4096
#define BT_   2048
#define EPS_  1e-5f
#define SCALE_ 0.03125f   // 1/sqrt(E) = 1/32

typedef __bf16 bf16;
typedef bf16  bf16x4 __attribute__((ext_vector_type(4)));
typedef bf16  bf16x8 __attribute__((ext_vector_type(8)));
typedef float f32x4  __attribute__((ext_vector_type(4)));

#define GL2LDS(gp, lp) __builtin_amdgcn_global_load_lds( \
    (const __attribute__((address_space(1))) void*)(gp), \
    (__attribute__((address_space(3))) void*)(lp), 16, 0, 0)

// ---------------------------------------------------------------- layernorm helper
__device__ __forceinline__ float wred_sum(float v) {
#pragma unroll
  for (int o = 32; o; o >>= 1) v += __shfl_xor(v, o, 64);
  return v;
}

__device__ __forceinline__ void ln_body(
    f32x4 v, const float* g, const float* b, bf16* h, size_t off, int tid)
{
  float s  = v[0] + v[1] + v[2] + v[3];
  float sq = v[0]*v[0] + v[1]*v[1] + v[2]*v[2] + v[3]*v[3];
  s  = wred_sum(s);
  sq = wred_sum(sq);
  __shared__ float rs[4], rq[4];
  int w = tid >> 6, lane = tid & 63;
  if (lane == 0) { rs[w] = s; rq[w] = sq; }
  __syncthreads();
  float S = rs[0] + rs[1] + rs[2] + rs[3];
  float Q = rq[0] + rq[1] + rq[2] + rq[3];
  float mean = S * (1.0f / E_);
  float var  = Q * (1.0f / E_) - mean * mean;
  float rstd = rsqrtf(fmaxf(var, 0.0f) + EPS_);
  f32x4 gv = *(const f32x4*)(g + tid * 4);
  f32x4 bv = *(const f32x4*)(b + tid * 4);
  f32x4 o = (v - mean) * rstd * gv + bv;
  bf16x4 ob = { (bf16)o[0], (bf16)o[1], (bf16)o[2], (bf16)o[3] };
  *(bf16x4*)(h + off) = ob;
}

// ---------------------------------------------------------------- embed + ln1(layer0) fused
__global__ __launch_bounds__(256) void embed_ln_kernel(
    const int* __restrict__ ids, const float* __restrict__ emb,
    const float* __restrict__ pos, const float* __restrict__ g,
    const float* __restrict__ b, float* __restrict__ x, bf16* __restrict__ h)
{
  int bt = blockIdx.x, tid = threadIdx.x;
  int t  = bt & (T_ - 1);
  int id = ids[bt];
  f32x4 e = *(const f32x4*)(emb + (size_t)id * E_ + tid * 4);
  f32x4 p = *(const f32x4*)(pos + (size_t)t  * E_ + tid * 4);
  f32x4 v = e + p;
  size_t off = (size_t)bt * E_ + tid * 4;
  *(f32x4*)(x + off) = v;
  ln_body(v, g, b, h, off, tid);
}

// ---------------------------------------------------------------- layernorm (f32 in, bf16 out)
__global__ __launch_bounds__(256) void ln_kernel(
    const float* __restrict__ x, const float* __restrict__ g,
    const float* __restrict__ b, bf16* __restrict__ h)
{
  int row = blockIdx.x, tid = threadIdx.x;
  size_t off = (size_t)row * E_ + tid * 4;
  f32x4 v = *(const f32x4*)(x + off);
  ln_body(v, g, b, h, off, tid);
}

// ---------------------------------------------------------------- weight transpose+convert (proj)
// W [K][N] f32 (row stride ldW) -> O [N][K] bf16
__global__ __launch_bounds__(256) void convw_kernel(
    const float* __restrict__ W0, bf16* __restrict__ O0, int K, int ldW)
{
  __shared__ float tl[32][33];
  int n0 = blockIdx.x * 32, k0 = blockIdx.y * 32;
  int c = threadIdx.x & 31, r = threadIdx.x >> 5;
#pragma unroll
  for (int p = 0; p < 4; ++p)
    tl[r + p * 8][c] = W0[(size_t)(k0 + r + p * 8) * ldW + n0 + c];
  __syncthreads();
#pragma unroll
  for (int p = 0; p < 4; ++p)
    O0[(size_t)(n0 + r + p * 8) * K + k0 + c] = (bf16)tl[c][r + p * 8];
}

// ---------------------------------------------------------------- fused per-layer weight convert
// one launch: wq,wk,wv (1024x1024), w1 (1024x4096), w2 (4096x1024) -> 11264 tiles
__global__ __launch_bounds__(256) void convw_all(
    const float* __restrict__ wq, const float* __restrict__ wk,
    const float* __restrict__ wv, const float* __restrict__ w1,
    const float* __restrict__ w2,
    bf16* __restrict__ oq, bf16* __restrict__ ok, bf16* __restrict__ ov,
    bf16* __restrict__ o1, bf16* __restrict__ o2)
{
  int bid = blockIdx.x;
  const float* W; bf16* O; int K, ldW, nx, ny;
  if (bid < 3072) {
    int z = bid >> 10, rem = bid & 1023;
    W = (z == 0) ? wq : (z == 1) ? wk : wv;
    O = (z == 0) ? oq : (z == 1) ? ok : ov;
    K = 1024; ldW = 1024; nx = rem & 31; ny = rem >> 5;
  } else if (bid < 7168) {
    int idx = bid - 3072;
    W = w1; O = o1; K = 1024; ldW = 4096;
    nx = idx & 127; ny = idx >> 7;
  } else {
    int idx = bid - 7168;
    W = w2; O = o2; K = 4096; ldW = 1024;
    nx = idx & 31; ny = idx >> 5;
  }
  __shared__ float tl[32][33];
  int n0 = nx * 32, k0 = ny * 32;
  int c = threadIdx.x & 31, r = threadIdx.x >> 5;
#pragma unroll
  for (int p = 0; p < 4; ++p)
    tl[r + p * 8][c] = W[(size_t)(k0 + r + p * 8) * ldW + n0 + c];
  __syncthreads();
#pragma unroll
  for (int p = 0; p < 4; ++p)
    O[(size_t)(n0 + r + p * 8) * K + k0 + c] = (bf16)tl[c][r + p * 8];
}

// ---------------------------------------------------------------- GEMM bf16 MFMA 128x128
// A [M][LDK] bf16, B [N][LDK] bf16. BK=32. r8-style interleaved staging:
// {issue unit0(t+1); vmcnt(2) (tile t's 4 loads landed, 2 in flight);
//  s_barrier; 8 ds_read; 8 MFMA; issue unit1(t+1); 8 MFMA; s_barrier}.
// Per-wave vmcnt + barrier = collective guarantee (each wave waited its own
// loads before joining). Stages only write buf^1, whose readers finished
// before the previous end barrier.
// MODE 1: bf16 out (+bias, opt GELU). MODE 3: f32 split-K partial (blockIdx.z).
template <int ACT, int MODE>
__global__ __launch_bounds__(256) void gemm_bf16(
    const bf16* __restrict__ A,
    const bf16* __restrict__ B0, const bf16* __restrict__ B1, const bf16* __restrict__ B2,
    const float* __restrict__ bi0, const float* __restrict__ bi1, const float* __restrict__ bi2,
    bf16* __restrict__ Cb0, bf16* __restrict__ Cb1, bf16* __restrict__ Cb2,
    float* __restrict__ Cf,
    int K, int ldc, int LDK)
{
  int z = blockIdx.z;
  const bf16*  Bm = (MODE == 3) ? B0 : (z == 0) ? B0 : (z == 1) ? B1 : B2;
  const float* bi = (z == 0) ? bi0 : (z == 1) ? bi1 : bi2;
  bf16*        Cb = (z == 0) ? Cb0 : (z == 1) ? Cb1 : Cb2;
  int koff = (MODE == 3) ? z * K : 0;

  // chunked XCD swizzle (nb multiple of 8)
  int nb  = (int)(gridDim.x * gridDim.y);
  int lin = blockIdx.x + gridDim.x * blockIdx.y;
  int per = nb >> 3;
  int b   = (lin & 7) * per + (lin >> 3);
  int mi  = b & 15;            // gridDim.x == 16 always
  int ni  = b >> 4;

  __shared__ __align__(16) char lds[2][16384];  // [buf][A 8KB | B 8KB]

  int tid = threadIdx.x;
  int lane = tid & 63, wid = tid >> 6;
  int wm = (wid >> 1) * 64, wn = (wid & 1) * 64;
  int fr = lane & 15, fb = lane >> 4;

  const bf16* Asrc = A  + (size_t)(mi * 128) * LDK + koff;
  const bf16* Bsrc = Bm + (size_t)(ni * 128) * LDK + koff;

  int NT = K >> 5;

  // one unit = 2 loads (A rows is*64.., B rows is*64..)
#define STAGE_U(buf, kk, is)                                                \
  {                                                                         \
    int rl = (is) * 64 + (tid >> 2);                                        \
    int key = (rl >> 1) & 3;                                                \
    int ck  = ((tid & 3) ^ key) * 8;                                        \
    GL2LDS(Asrc + (size_t)rl * LDK + (kk) + ck,                             \
           lds[buf] + (is) * 4096 + tid * 16);                              \
    GL2LDS(Bsrc + (size_t)rl * LDK + (kk) + ck,                             \
           lds[buf] + 8192 + (is) * 4096 + tid * 16);                       \
  }

  f32x4 acc[4][4];
#pragma unroll
  for (int i = 0; i < 4; ++i)
#pragma unroll
    for (int j = 0; j < 4; ++j) acc[i][j] = (f32x4){0.f, 0.f, 0.f, 0.f};

  STAGE_U(0, 0, 0);
  STAGE_U(0, 0, 1);

  for (int t = 0; t < NT; ++t) {
    int buf = t & 1;
    int nk  = (t + 1) << 5;
    bool pf = (t + 1 < NT);

    if (pf) {
      STAGE_U(buf ^ 1, nk, 0);
      asm volatile("s_waitcnt vmcnt(2)" ::: "memory");   // tile t's 4 landed
    } else {
      asm volatile("s_waitcnt vmcnt(0)" ::: "memory");
    }
    __builtin_amdgcn_s_barrier();
    asm volatile("" ::: "memory");

    const char* Ab = lds[buf];
    const char* Bb = lds[buf] + 8192;
    bf16x8 af[4], bfr[4];
#pragma unroll
    for (int i = 0; i < 4; ++i) {
      int rl = wm + i * 16 + fr;
      af[i] = *(const bf16x8*)(Ab + rl * 64 + ((fb ^ ((rl >> 1) & 3)) * 16));
    }
#pragma unroll
    for (int j = 0; j < 4; ++j) {
      int rl = wn + j * 16 + fr;
      bfr[j] = *(const bf16x8*)(Bb + rl * 64 + ((fb ^ ((rl >> 1) & 3)) * 16));
    }
    __builtin_amdgcn_s_setprio(1);
#pragma unroll
    for (int i = 0; i < 2; ++i)
#pragma unroll
      for (int j = 0; j < 4; ++j)
        acc[i][j] = __builtin_amdgcn_mfma_f32_16x16x32_bf16(af[i], bfr[j], acc[i][j], 0, 0, 0);
    __builtin_amdgcn_s_setprio(0);
    if (pf) STAGE_U(buf ^ 1, nk, 1);
    __builtin_amdgcn_s_setprio(1);
#pragma unroll
    for (int i = 2; i < 4; ++i)
#pragma unroll
      for (int j = 0; j < 4; ++j)
        acc[i][j] = __builtin_amdgcn_mfma_f32_16x16x32_bf16(af[i], bfr[j], acc[i][j], 0, 0, 0);
    __builtin_amdgcn_s_setprio(0);
    asm volatile("" ::: "memory");
    __builtin_amdgcn_s_barrier();   // reads of buf done before next tile stages over it
  }
#undef STAGE_U

  // epilogue: C/D layout col = lane&15, row = (lane>>4)*4 + reg
#pragma unroll
  for (int i = 0; i < 4; ++i) {
#pragma unroll
    for (int j = 0; j < 4; ++j) {
      int gc = ni * 128 + wn + j * 16 + fr;
      float bv = (MODE == 3) ? 0.f : bi[gc];
#pragma unroll
      for (int r = 0; r < 4; ++r) {
        int gr = mi * 128 + wm + i * 16 + fb * 4 + r;
        float vv = acc[i][j][r] + bv;
        if (ACT == 1) vv = 0.5f * vv * (1.0f + erff(vv * 0.70710678118654752f));
        if (MODE == 1) {
          Cb[(size_t)gr * ldc + gc] = (bf16)vv;
        } else {
          Cf[(size_t)(blockIdx.z * BT_ + gr) * ldc + gc] = vv;
        }
      }
    }
  }
}

// ---------------------------------------------------------------- FFN2 split-K combine (last layer)
__global__ __launch_bounds__(256) void combine_kernel(
    const float* __restrict__ p, const float* __restrict__ bi,
    float* __restrict__ x, bf16* __restrict__ xb)
{
  int row = blockIdx.x, tid = threadIdx.x;
  size_t off = (size_t)row * E_ + tid * 4;
  f32x4 a = *(const f32x4*)(p + off);
  f32x4 c = *(const f32x4*)(p + (size_t)BT_ * E_ + off);
  f32x4 bv = *(const f32x4*)(bi + tid * 4);
  f32x4 xv = *(const f32x4*)(x + off);
  f32x4 nv = xv + a + c + bv;
  *(f32x4*)(x + off) = nv;
  bf16x4 ob = { (bf16)nv[0], (bf16)nv[1], (bf16)nv[2], (bf16)nv[3] };
  *(bf16x4*)(xb + off) = ob;
}

// ---------------------------------------------------------------- combine + next-layer ln1 fused
__global__ __launch_bounds__(256) void combine_ln_kernel(
    const float* __restrict__ p, const float* __restrict__ bi,
    const float* __restrict__ g, const float* __restrict__ b,
    float* __restrict__ x, bf16* __restrict__ h)
{
  int row = blockIdx.x, tid = threadIdx.x;
  size_t off = (size_t)row * E_ + tid * 4;
  f32x4 a = *(const f32x4*)(p + off);
  f32x4 c = *(const f32x4*)(p + (size_t)BT_ * E_ + off);
  f32x4 bv = *(const f32x4*)(bi + tid * 4);
  f32x4 xv = *(const f32x4*)(x + off);
  f32x4 nv = xv + a + c + bv;
  *(f32x4*)(x + off) = nv;
  ln_body(nv, g, b, h, off, tid);
}

// ---------------------------------------------------------------- GEMM bf16 MFMA 256x256, BK=64
// (round-8 proven version, 157us / 35.5% MfmaUtil) — unchanged.
__global__ __launch_bounds__(512, 2) void gemm256_kernel(
    const bf16* __restrict__ A, const bf16* __restrict__ Bm,
    const float* __restrict__ bi, float* __restrict__ C, int K, int N)
{
  int nwg = (int)gridDim.x;
  int per = nwg >> 3;
  int bid = (int)blockIdx.x;
  int tl  = (bid & 7) * per + (bid >> 3);   // chunked XCD swizzle (nwg%8==0)
  int mi  = tl & 7, ni = tl >> 3;

  __shared__ __align__(16) char lds[2][65536];

  int tid = threadIdx.x;
  int lane = tid & 63, wid = tid >> 6;
  int wr = wid >> 2, wc = wid & 3;          // 2 x 4 waves
  int fr = lane & 15, fb = lane >> 4;

  const bf16* Asrc = A  + (size_t)(mi * 256) * K;
  const bf16* Bsrc = Bm + (size_t)(ni * 256) * K;

  int NT = K >> 6;   // 16

#define STGQ(buf, kk, h, is)                                               \
  {                                                                        \
    int ri  = (is) * 64 + (tid >> 3);                                      \
    int ck  = (tid & 7) ^ (ri & 7);                                        \
    int row = (h) * 128 + ri;                                              \
    GL2LDS(Asrc + (size_t)row * K + (kk) + ck * 8,                         \
           lds[buf] + (h) * 16384 + (is) * 8192 + tid * 16);               \
    GL2LDS(Bsrc + (size_t)row * K + (kk) + ck * 8,                         \
           lds[buf] + 32768 + (h) * 16384 + (is) * 8192 + tid * 16);       \
  }

  f32x4 acc[8][4];
#pragma unroll
  for (int i = 0; i < 8; ++i)
#pragma unroll
    for (int j = 0; j < 4; ++j) acc[i][j] = (f32x4){0.f, 0.f, 0.f, 0.f};

  STGQ(0, 0, 0, 0); STGQ(0, 0, 0, 1); STGQ(0, 0, 1, 0); STGQ(0, 0, 1, 1);

  for (int t = 0; t < NT; ++t) {
    int buf = t & 1;
    int nk  = (t + 1) << 6;
    bool pf = (t + 1 < NT);

    if (pf) {
      STGQ(buf ^ 1, nk, 0, 0);
      asm volatile("s_waitcnt vmcnt(2)" ::: "memory");   // tile t landed
    } else {
      asm volatile("s_waitcnt vmcnt(0)" ::: "memory");
    }
    __builtin_amdgcn_s_barrier();
    asm volatile("" ::: "memory");

    const char* Ab = lds[buf];
    const char* Bb = lds[buf] + 32768;

    bf16x8 bfr[4][2];
#pragma unroll
    for (int n2 = 0; n2 < 4; ++n2) {
      int row = wc * 64 + n2 * 16 + fr;
#pragma unroll
      for (int ks = 0; ks < 2; ++ks)
        bfr[n2][ks] = *(const bf16x8*)(Bb + (row >> 7) * 16384 + (row & 127) * 128
                                          + ((((ks * 4 + fb) ^ (fr & 7))) << 4));
    }

#pragma unroll
    for (int q = 0; q < 4; ++q) {
      bf16x8 af[2][2];
#pragma unroll
      for (int m2 = 0; m2 < 2; ++m2) {
        int ri = (q * 2 + m2) * 16 + fr;
#pragma unroll
        for (int ks = 0; ks < 2; ++ks)
          af[m2][ks] = *(const bf16x8*)(Ab + wr * 16384 + ri * 128
                                           + ((((ks * 4 + fb) ^ (fr & 7))) << 4));
      }
      __builtin_amdgcn_s_setprio(1);
#pragma unroll
      for (int m2 = 0; m2 < 2; ++m2)
#pragma unroll
        for (int n2 = 0; n2 < 4; ++n2)
#pragma unroll
          for (int ks = 0; ks < 2; ++ks)
            acc[q * 2 + m2][n2] = __builtin_amdgcn_mfma_f32_16x16x32_bf16(
                af[m2][ks], bfr[n2][ks], acc[q * 2 + m2][n2], 0, 0, 0);
      __builtin_amdgcn_s_setprio(0);
      if (pf && q == 0) STGQ(buf ^ 1, nk, 0, 1);
      if (pf && q == 1) STGQ(buf ^ 1, nk, 1, 0);
      if (pf && q == 2) STGQ(buf ^ 1, nk, 1, 1);
    }
    asm volatile("" ::: "memory");
    __builtin_amdgcn_s_barrier();
  }
#undef STGQ

#pragma unroll
  for (int i = 0; i < 8; ++i) {
#pragma unroll
    for (int j = 0; j < 4; ++j) {
      int gc = ni * 256 + wc * 64 + j * 16 + fr;
      float bv = bi[gc];
#pragma unroll
      for (int r = 0; r < 4; ++r) {
        int gr = mi * 256 + wr * 128 + i * 16 + fb * 4 + r;
        C[(size_t)gr * N + gc] = acc[i][j][r] + bv;
      }
    }
  }
}

// ---------------------------------------------------------------- attention (bf16 MFMA flash)
__global__ __launch_bounds__(256) void attn_kernel(
    const bf16* __restrict__ q, const bf16* __restrict__ k,
    const bf16* __restrict__ v, float* __restrict__ x)
{
  __shared__ __align__(16) char Ks[8192];
  __shared__ __align__(16) char Vs[8192];
  __shared__ __align__(16) char Ps[8192];

  int tid = threadIdx.x, lane = tid & 63, w = tid >> 6;
  int qt = (int)gridDim.x - 1 - (int)blockIdx.x;   // heavy first
  int bh = blockIdx.y;
  int b = bh >> 4, h = bh & 15;
  size_t hoff = (size_t)b * T_ * E_ + h * HS_;
  int fr = lane & 15, fb = lane >> 4;

  bf16x8 qa[2];
  {
    const bf16* qp = q + hoff + (size_t)(qt * 64 + w * 16 + fr) * E_ + fb * 8;
    qa[0] = *(const bf16x8*)qp;
    qa[1] = *(const bf16x8*)(qp + 32);
  }

  f32x4 O[4];
  float m_[4], l_[4];
#pragma unroll
  for (int i = 0; i < 4; ++i) { O[i] = (f32x4){0.f,0.f,0.f,0.f}; m_[i] = -1e30f; l_[i] = 0.f; }

  for (int kt = 0; kt <= qt; ++kt) {
    __syncthreads();
    {
      const bf16* kbase = k + hoff + (size_t)(kt * 64) * E_;
#pragma unroll
      for (int is = 0; is < 2; ++is) {
        int c = is * 32 + (tid >> 3);
        int key = ((c & 7) ^ (c >> 3)) & 7;
        GL2LDS(kbase + (size_t)c * E_ + (((tid & 7) ^ key) * 8),
               Ks + is * 4096 + tid * 16);
      }
    }
#pragma unroll
    for (int p = 0; p < 2; ++p) {
      int row = tid >> 2;
      int d0 = (tid & 3) * 8 + p * 32;
      bf16x8 vv = *(const bf16x8*)(v + hoff + (size_t)(kt * 64 + row) * E_ + d0);
#pragma unroll
      for (int e = 0; e < 8; ++e) {
        int d = d0 + e;
        int key = ((d & 7) ^ (d >> 3)) & 7;
        *(bf16*)(Vs + d * 128 + ((row * 2) ^ (key << 4))) = vv[e];
      }
    }
    __syncthreads();

    f32x4 s[4];
#pragma unroll
    for (int jc = 0; jc < 4; ++jc) {
      s[jc] = (f32x4){0.f, 0.f, 0.f, 0.f};
#pragma unroll
      for (int kc = 0; kc < 2; ++kc) {
        int c = jc * 16 + fr;
        int key = ((c & 7) ^ (c >> 3)) & 7;
        bf16x8 kf = *(const bf16x8*)(Ks + c * 128 + ((kc * 64 + fb * 16) ^ (key << 4)));
        s[jc] = __builtin_amdgcn_mfma_f32_16x16x32_bf16(qa[kc], kf, s[jc], 0, 0, 0);
      }
    }

    char* pbase = Ps + w * 2048;
#pragma unroll
    for (int r = 0; r < 4; ++r) {
      float s0 = s[0][r] * SCALE_, s1 = s[1][r] * SCALE_;
      float s2 = s[2][r] * SCALE_, s3 = s[3][r] * SCALE_;
      int qrow = qt * 64 + w * 16 + fb * 4 + r;
      if (kt == qt) {
        int kc0 = kt * 64 + fr;
        if (kc0      > qrow) s0 = -1e30f;
        if (kc0 + 16 > qrow) s1 = -1e30f;
        if (kc0 + 32 > qrow) s2 = -1e30f;
        if (kc0 + 48 > qrow) s3 = -1e30f;
      }
      float mx = fmaxf(fmaxf(s0, s1), fmaxf(s2, s3));
      mx = fmaxf(mx, __shfl_xor(mx, 1, 16));
      mx = fmaxf(mx, __shfl_xor(mx, 2, 16));
      mx = fmaxf(mx, __shfl_xor(mx, 4, 16));
      mx = fmaxf(mx, __shfl_xor(mx, 8, 16));
      float mnew = fmaxf(m_[r], mx);
      float p0 = __expf(s0 - mnew), p1 = __expf(s1 - mnew);
      float p2 = __expf(s2 - mnew), p3 = __expf(s3 - mnew);
      float rs = p0 + p1 + p2 + p3;
      rs += __shfl_xor(rs, 1, 16);
      rs += __shfl_xor(rs, 2, 16);
      rs += __shfl_xor(rs, 4, 16);
      rs += __shfl_xor(rs, 8, 16);
      float scl = __expf(m_[r] - mnew);
      l_[r] = l_[r] * scl + rs;
      m_[r] = mnew;
#pragma unroll
      for (int jd = 0; jd < 4; ++jd) O[jd][r] *= scl;
      int key2 = (r << 4) ^ (fb << 5);
      char* pr_ = pbase + (fb * 4 + r) * 128;
      *(bf16*)(pr_ + (( 0 + fr * 2) ^ key2)) = (bf16)p0;
      *(bf16*)(pr_ + ((32 + fr * 2) ^ key2)) = (bf16)p1;
      *(bf16*)(pr_ + ((64 + fr * 2) ^ key2)) = (bf16)p2;
      *(bf16*)(pr_ + ((96 + fr * 2) ^ key2)) = (bf16)p3;
    }

#pragma unroll
    for (int kc = 0; kc < 2; ++kc) {
      int key2 = ((fr & 3) << 4) ^ ((fr >> 2) << 5);
      bf16x8 pa = *(const bf16x8*)(pbase + fr * 128 + ((kc * 64 + fb * 16) ^ key2));
#pragma unroll
      for (int jd = 0; jd < 4; ++jd) {
        int d = jd * 16 + fr;
        int key = ((d & 7) ^ (d >> 3)) & 7;
        bf16x8 vf = *(const bf16x8*)(Vs + d * 128 + ((kc * 64 + fb * 16) ^ (key << 4)));
        O[jd] = __builtin_amdgcn_mfma_f32_16x16x32_bf16(pa, vf, O[jd], 0, 0, 0);
      }
    }
  }

#pragma unroll
  for (int r = 0; r < 4; ++r) {
    float inv = 1.0f / l_[r];
    float* xp = x + hoff + (size_t)(qt * 64 + w * 16 + fb * 4 + r) * E_;
#pragma unroll
    for (int jd = 0; jd < 4; ++jd) {
      int d = jd * 16 + fr;
      xp[d] += O[jd][r] * inv;
    }
  }
}

// ---------------------------------------------------------------- launch
extern "C" void kernel_launch(void* const* d_in, const int* in_sizes, int n_in,
                              void* d_out, int out_size, void* d_ws, size_t ws_size,
                              hipStream_t stream)
{
  const int*   ids  = (const int*)  d_in[0];
  const float* emb  = (const float*)d_in[1];
  const float* pos  = (const float*)d_in[2];
  const float* wq   = (const float*)d_in[3];
  const float* bq   = (const float*)d_in[4];
  const float* wk   = (const float*)d_in[5];
  const float* bk   = (const float*)d_in[6];
  const float* wv   = (const float*)d_in[7];
  const float* bv   = (const float*)d_in[8];
  const float* w1   = (const float*)d_in[9];
  const float* b1   = (const float*)d_in[10];
  const float* w2   = (const float*)d_in[11];
  const float* b2   = (const float*)d_in[12];
  const float* ln1g = (const float*)d_in[13];
  const float* ln1b = (const float*)d_in[14];
  const float* ln2g = (const float*)d_in[15];
  const float* ln2b = (const float*)d_in[16];
  const float* pw   = (const float*)d_in[17];
  const float* pb   = (const float*)d_in[18];
  float* out = (float*)d_out;

  // ws layout (f32 units), non-overlapping in time (round-10-proven):
  //   x   [ 0M,  2M)  f32  BTxE
  //   hb  [ 2M,  3M)  bf16 BTxE      } fp [2M,6M) aliases hb..vb
  //   qb  [ 3M,  4M)  bf16 BTxE      }   (dead at FFN2 time)
  //   kb  [ 4M,  5M)  bf16 BTxE
  //   vb  [ 5M,  6M)  bf16 BTxE
  //   ffb [ 6M, 10M)  bf16 BTxFF
  //   lwb [10M,15.5M) bf16 layer weights
  //   hb2 [15.5M,16M) bf16 BTxE  (combine_ln output; dead at proj time)
  //   xb  [16M, 17M)  bf16 BTxE
  //   pwb [ 0M,15.625M) bf16 proj weight (all below dead at proj time)
  // peak = 17M f32 = 68 MiB (round 1 proved ws >= 72 MiB)
  if (ws_size < (size_t)17 * 1024 * 1024 * 4) return;
  float* ws = (float*)d_ws;
  float* x   = ws;
  bf16*  hb  = (bf16*)(ws + (size_t) 2 * 1024 * 1024);
  bf16*  qb  = (bf16*)(ws + (size_t) 3 * 1024 * 1024);
  bf16*  kb  = (bf16*)(ws + (size_t) 4 * 1024 * 1024);
  bf16*  vb  = (bf16*)(ws + (size_t) 5 * 1024 * 1024);
  bf16*  ffb = (bf16*)(ws + (size_t) 6 * 1024 * 1024);
  float* fp  = ws + (size_t)2 * 1024 * 1024;          // 2 partials, 2M f32 each
  bf16*  lwb = (bf16*)(ws + (size_t)10 * 1024 * 1024);
  bf16*  hb2 = (bf16*)(ws + (size_t)15 * 1024 * 1024 + 512 * 1024);  // [15.5M,16M)
  bf16*  xb  = (bf16*)(ws + (size_t)16 * 1024 * 1024);
  bf16*  pwb = (bf16*)ws;
  bf16*  wqt = lwb;
  bf16*  wkt = lwb + (size_t)1 * 1024 * 1024;
  bf16*  wvt = lwb + (size_t)2 * 1024 * 1024;
  bf16*  w1t = lwb + (size_t)3 * 1024 * 1024;
  bf16*  w2t = lwb + (size_t)7 * 1024 * 1024;

  embed_ln_kernel<<<BT_, 256, 0, stream>>>(ids, emb, pos, ln1g, ln1b, x, hb);

  for (int l = 0; l < L_; ++l) {
    const size_t lEE = (size_t)l * E_ * E_;
    const size_t lEF = (size_t)l * E_ * FF_;
    const bf16* hcur = (l == 0) ? hb : hb2;   // layer-0 ln1 wrote hb; fused writes hb2

    convw_all<<<11264, 256, 0, stream>>>(
        wq + lEE, wk + lEE, wv + lEE, w1 + lEF, w2 + lEF,
        wqt, wkt, wvt, w1t, w2t);

    gemm_bf16<0,1><<<dim3(16, E_/128, 3), 256, 0, stream>>>(
        hcur, wqt, wkt, wvt, bq + l*E_, bk + l*E_, bv + l*E_,
        qb, kb, vb, nullptr, E_, E_, E_);

    attn_kernel<<<dim3(T_/64, B_*H_), 256, 0, stream>>>(qb, kb, vb, x);

    ln_kernel<<<BT_, 256, 0, stream>>>(x, ln2g + l*E_, ln2b + l*E_, hb);

    gemm_bf16<1,1><<<dim3(16, FF_/128, 1), 256, 0, stream>>>(
        hb, w1t, nullptr, nullptr, b1 + (size_t)l*FF_, nullptr, nullptr,
        ffb, nullptr, nullptr, nullptr, E_, FF_, E_);

    // FFN2: split-K=2 over blockIdx.z -> 256 blocks, then fused combine
    gemm_bf16<0,3><<<dim3(16, E_/128, 2), 256, 0, stream>>>(
        ffb, w2t, nullptr, nullptr, nullptr, nullptr, nullptr,
        nullptr, nullptr, nullptr, fp, FF_/2, E_, FF_);
    if (l < L_ - 1) {
      combine_ln_kernel<<<BT_, 256, 0, stream>>>(
          fp, b2 + l*E_, ln1g + (l+1)*E_, ln1b + (l+1)*E_, x, hb2);
    } else {
      combine_kernel<<<BT_, 256, 0, stream>>>(fp, b2 + l*E_, x, xb);
    }
  }

  // final projection: whole weight converted, 256^2 BK=64 4-phase GEMM
  convw_kernel<<<dim3(V_/32, E_/32), 256, 0, stream>>>(pw, pwb, E_, V_);
  gemm256_kernel<<<(V_/256) * 8, 512, 0, stream>>>(
      xb, pwb, pb, out, E_, V_);
}

// Round 12
// 806.571 us; speedup vs baseline: 2.1761x; 1.0212x over previous
//
#include <hip/hip_runtime.h>
#include <hip/hip_bf16.h>
#include <cstdint>

#define B_    2
#define T_    1024
#define E_    1024
#define H_    16
#define HS_   64
#define L_    4
#define V_    32000
#define FF_   4096
#define BT_   2048
#define EPS_  1e-5f
#define SCALE_ 0.03125f   // 1/sqrt(E) = 1/32

typedef __bf16 bf16;
typedef bf16  bf16x4 __attribute__((ext_vector_type(4)));
typedef bf16  bf16x8 __attribute__((ext_vector_type(8)));
typedef float f32x4  __attribute__((ext_vector_type(4)));

#define GL2LDS(gp, lp) __builtin_amdgcn_global_load_lds( \
    (const __attribute__((address_space(1))) void*)(gp), \
    (__attribute__((address_space(3))) void*)(lp), 16, 0, 0)

// ---------------------------------------------------------------- layernorm helper
__device__ __forceinline__ float wred_sum(float v) {
#pragma unroll
  for (int o = 32; o; o >>= 1) v += __shfl_xor(v, o, 64);
  return v;
}

__device__ __forceinline__ void ln_body(
    f32x4 v, const float* g, const float* b, bf16* h, size_t off, int tid)
{
  float s  = v[0] + v[1] + v[2] + v[3];
  float sq = v[0]*v[0] + v[1]*v[1] + v[2]*v[2] + v[3]*v[3];
  s  = wred_sum(s);
  sq = wred_sum(sq);
  __shared__ float rs[4], rq[4];
  int w = tid >> 6, lane = tid & 63;
  if (lane == 0) { rs[w] = s; rq[w] = sq; }
  __syncthreads();
  float S = rs[0] + rs[1] + rs[2] + rs[3];
  float Q = rq[0] + rq[1] + rq[2] + rq[3];
  float mean = S * (1.0f / E_);
  float var  = Q * (1.0f / E_) - mean * mean;
  float rstd = rsqrtf(fmaxf(var, 0.0f) + EPS_);
  f32x4 gv = *(const f32x4*)(g + tid * 4);
  f32x4 bv = *(const f32x4*)(b + tid * 4);
  f32x4 o = (v - mean) * rstd * gv + bv;
  bf16x4 ob = { (bf16)o[0], (bf16)o[1], (bf16)o[2], (bf16)o[3] };
  *(bf16x4*)(h + off) = ob;
}

// ---------------------------------------------------------------- embed + ln1(layer0) fused
__global__ __launch_bounds__(256) void embed_ln_kernel(
    const int* __restrict__ ids, const float* __restrict__ emb,
    const float* __restrict__ pos, const float* __restrict__ g,
    const float* __restrict__ b, float* __restrict__ x, bf16* __restrict__ h)
{
  int bt = blockIdx.x, tid = threadIdx.x;
  int t  = bt & (T_ - 1);
  int id = ids[bt];
  f32x4 e = *(const f32x4*)(emb + (size_t)id * E_ + tid * 4);
  f32x4 p = *(const f32x4*)(pos + (size_t)t  * E_ + tid * 4);
  f32x4 v = e + p;
  size_t off = (size_t)bt * E_ + tid * 4;
  *(f32x4*)(x + off) = v;
  ln_body(v, g, b, h, off, tid);
}

// ---------------------------------------------------------------- layernorm (f32 in, bf16 out)
__global__ __launch_bounds__(256) void ln_kernel(
    const float* __restrict__ x, const float* __restrict__ g,
    const float* __restrict__ b, bf16* __restrict__ h)
{
  int row = blockIdx.x, tid = threadIdx.x;
  size_t off = (size_t)row * E_ + tid * 4;
  f32x4 v = *(const f32x4*)(x + off);
  ln_body(v, g, b, h, off, tid);
}

// ---------------------------------------------------------------- weight transpose+convert (proj)
// W [K][N] f32 (row stride ldW) -> O [N][K] bf16
__global__ __launch_bounds__(256) void convw_kernel(
    const float* __restrict__ W0, bf16* __restrict__ O0, int K, int ldW)
{
  __shared__ float tl[32][33];
  int n0 = blockIdx.x * 32, k0 = blockIdx.y * 32;
  int c = threadIdx.x & 31, r = threadIdx.x >> 5;
#pragma unroll
  for (int p = 0; p < 4; ++p)
    tl[r + p * 8][c] = W0[(size_t)(k0 + r + p * 8) * ldW + n0 + c];
  __syncthreads();
#pragma unroll
  for (int p = 0; p < 4; ++p)
    O0[(size_t)(n0 + r + p * 8) * K + k0 + c] = (bf16)tl[c][r + p * 8];
}

// ---------------------------------------------------------------- fused per-layer weight convert
__global__ __launch_bounds__(256) void convw_all(
    const float* __restrict__ wq, const float* __restrict__ wk,
    const float* __restrict__ wv, const float* __restrict__ w1,
    const float* __restrict__ w2,
    bf16* __restrict__ oq, bf16* __restrict__ ok, bf16* __restrict__ ov,
    bf16* __restrict__ o1, bf16* __restrict__ o2)
{
  int bid = blockIdx.x;
  const float* W; bf16* O; int K, ldW, nx, ny;
  if (bid < 3072) {
    int z = bid >> 10, rem = bid & 1023;
    W = (z == 0) ? wq : (z == 1) ? wk : wv;
    O = (z == 0) ? oq : (z == 1) ? ok : ov;
    K = 1024; ldW = 1024; nx = rem & 31; ny = rem >> 5;
  } else if (bid < 7168) {
    int idx = bid - 3072;
    W = w1; O = o1; K = 1024; ldW = 4096;
    nx = idx & 127; ny = idx >> 7;
  } else {
    int idx = bid - 7168;
    W = w2; O = o2; K = 4096; ldW = 1024;
    nx = idx & 31; ny = idx >> 5;
  }
  __shared__ float tl[32][33];
  int n0 = nx * 32, k0 = ny * 32;
  int c = threadIdx.x & 31, r = threadIdx.x >> 5;
#pragma unroll
  for (int p = 0; p < 4; ++p)
    tl[r + p * 8][c] = W[(size_t)(k0 + r + p * 8) * ldW + n0 + c];
  __syncthreads();
#pragma unroll
  for (int p = 0; p < 4; ++p)
    O[(size_t)(n0 + r + p * 8) * K + k0 + c] = (bf16)tl[c][r + p * 8];
}

// ---------------------------------------------------------------- GEMM bf16 MFMA 128x128 (r11-proven)
template <int ACT, int MODE>
__global__ __launch_bounds__(256) void gemm_bf16(
    const bf16* __restrict__ A,
    const bf16* __restrict__ B0, const bf16* __restrict__ B1, const bf16* __restrict__ B2,
    const float* __restrict__ bi0, const float* __restrict__ bi1, const float* __restrict__ bi2,
    bf16* __restrict__ Cb0, bf16* __restrict__ Cb1, bf16* __restrict__ Cb2,
    float* __restrict__ Cf,
    int K, int ldc, int LDK)
{
  int z = blockIdx.z;
  const bf16*  Bm = (MODE == 3) ? B0 : (z == 0) ? B0 : (z == 1) ? B1 : B2;
  const float* bi = (z == 0) ? bi0 : (z == 1) ? bi1 : bi2;
  bf16*        Cb = (z == 0) ? Cb0 : (z == 1) ? Cb1 : Cb2;
  int koff = (MODE == 3) ? z * K : 0;

  int nb  = (int)(gridDim.x * gridDim.y);
  int lin = blockIdx.x + gridDim.x * blockIdx.y;
  int per = nb >> 3;
  int b   = (lin & 7) * per + (lin >> 3);
  int mi  = b & 15;
  int ni  = b >> 4;

  __shared__ __align__(16) char lds[2][16384];

  int tid = threadIdx.x;
  int lane = tid & 63, wid = tid >> 6;
  int wm = (wid >> 1) * 64, wn = (wid & 1) * 64;
  int fr = lane & 15, fb = lane >> 4;

  const bf16* Asrc = A  + (size_t)(mi * 128) * LDK + koff;
  const bf16* Bsrc = Bm + (size_t)(ni * 128) * LDK + koff;

  int NT = K >> 5;

#define STAGE_U(buf, kk, is)                                                \
  {                                                                         \
    int rl = (is) * 64 + (tid >> 2);                                        \
    int key = (rl >> 1) & 3;                                                \
    int ck  = ((tid & 3) ^ key) * 8;                                        \
    GL2LDS(Asrc + (size_t)rl * LDK + (kk) + ck,                             \
           lds[buf] + (is) * 4096 + tid * 16);                              \
    GL2LDS(Bsrc + (size_t)rl * LDK + (kk) + ck,                             \
           lds[buf] + 8192 + (is) * 4096 + tid * 16);                       \
  }

  f32x4 acc[4][4];
#pragma unroll
  for (int i = 0; i < 4; ++i)
#pragma unroll
    for (int j = 0; j < 4; ++j) acc[i][j] = (f32x4){0.f, 0.f, 0.f, 0.f};

  STAGE_U(0, 0, 0);
  STAGE_U(0, 0, 1);

  for (int t = 0; t < NT; ++t) {
    int buf = t & 1;
    int nk  = (t + 1) << 5;
    bool pf = (t + 1 < NT);

    if (pf) {
      STAGE_U(buf ^ 1, nk, 0);
      asm volatile("s_waitcnt vmcnt(2)" ::: "memory");
    } else {
      asm volatile("s_waitcnt vmcnt(0)" ::: "memory");
    }
    __builtin_amdgcn_s_barrier();
    asm volatile("" ::: "memory");

    const char* Ab = lds[buf];
    const char* Bb = lds[buf] + 8192;
    bf16x8 af[4], bfr[4];
#pragma unroll
    for (int i = 0; i < 4; ++i) {
      int rl = wm + i * 16 + fr;
      af[i] = *(const bf16x8*)(Ab + rl * 64 + ((fb ^ ((rl >> 1) & 3)) * 16));
    }
#pragma unroll
    for (int j = 0; j < 4; ++j) {
      int rl = wn + j * 16 + fr;
      bfr[j] = *(const bf16x8*)(Bb + rl * 64 + ((fb ^ ((rl >> 1) & 3)) * 16));
    }
    __builtin_amdgcn_s_setprio(1);
#pragma unroll
    for (int i = 0; i < 2; ++i)
#pragma unroll
      for (int j = 0; j < 4; ++j)
        acc[i][j] = __builtin_amdgcn_mfma_f32_16x16x32_bf16(af[i], bfr[j], acc[i][j], 0, 0, 0);
    __builtin_amdgcn_s_setprio(0);
    if (pf) STAGE_U(buf ^ 1, nk, 1);
    __builtin_amdgcn_s_setprio(1);
#pragma unroll
    for (int i = 2; i < 4; ++i)
#pragma unroll
      for (int j = 0; j < 4; ++j)
        acc[i][j] = __builtin_amdgcn_mfma_f32_16x16x32_bf16(af[i], bfr[j], acc[i][j], 0, 0, 0);
    __builtin_amdgcn_s_setprio(0);
    asm volatile("" ::: "memory");
    __builtin_amdgcn_s_barrier();
  }
#undef STAGE_U

#pragma unroll
  for (int i = 0; i < 4; ++i) {
#pragma unroll
    for (int j = 0; j < 4; ++j) {
      int gc = ni * 128 + wn + j * 16 + fr;
      float bv = (MODE == 3) ? 0.f : bi[gc];
#pragma unroll
      for (int r = 0; r < 4; ++r) {
        int gr = mi * 128 + wm + i * 16 + fb * 4 + r;
        float vv = acc[i][j][r] + bv;
        if (ACT == 1) vv = 0.5f * vv * (1.0f + erff(vv * 0.70710678118654752f));
        if (MODE == 1) {
          Cb[(size_t)gr * ldc + gc] = (bf16)vv;
        } else {
          Cf[(size_t)(blockIdx.z * BT_ + gr) * ldc + gc] = vv;
        }
      }
    }
  }
}

// ---------------------------------------------------------------- FFN2 split-K combine (last layer)
__global__ __launch_bounds__(256) void combine_kernel(
    const float* __restrict__ p, const float* __restrict__ bi,
    float* __restrict__ x, bf16* __restrict__ xb)
{
  int row = blockIdx.x, tid = threadIdx.x;
  size_t off = (size_t)row * E_ + tid * 4;
  f32x4 a = *(const f32x4*)(p + off);
  f32x4 c = *(const f32x4*)(p + (size_t)BT_ * E_ + off);
  f32x4 bv = *(const f32x4*)(bi + tid * 4);
  f32x4 xv = *(const f32x4*)(x + off);
  f32x4 nv = xv + a + c + bv;
  *(f32x4*)(x + off) = nv;
  bf16x4 ob = { (bf16)nv[0], (bf16)nv[1], (bf16)nv[2], (bf16)nv[3] };
  *(bf16x4*)(xb + off) = ob;
}

// ---------------------------------------------------------------- combine + next-layer ln1 fused
__global__ __launch_bounds__(256) void combine_ln_kernel(
    const float* __restrict__ p, const float* __restrict__ bi,
    const float* __restrict__ g, const float* __restrict__ b,
    float* __restrict__ x, bf16* __restrict__ h)
{
  int row = blockIdx.x, tid = threadIdx.x;
  size_t off = (size_t)row * E_ + tid * 4;
  f32x4 a = *(const f32x4*)(p + off);
  f32x4 c = *(const f32x4*)(p + (size_t)BT_ * E_ + off);
  f32x4 bv = *(const f32x4*)(bi + tid * 4);
  f32x4 xv = *(const f32x4*)(x + off);
  f32x4 nv = xv + a + c + bv;
  *(f32x4*)(x + off) = nv;
  ln_body(nv, g, b, h, off, tid);
}

// ---------------------------------------------------------------- GEMM bf16 MFMA 256x256, BK=64
// (round-8 proven version, 157us / 35.5% MfmaUtil) — unchanged.
__global__ __launch_bounds__(512, 2) void gemm256_kernel(
    const bf16* __restrict__ A, const bf16* __restrict__ Bm,
    const float* __restrict__ bi, float* __restrict__ C, int K, int N)
{
  int nwg = (int)gridDim.x;
  int per = nwg >> 3;
  int bid = (int)blockIdx.x;
  int tl  = (bid & 7) * per + (bid >> 3);
  int mi  = tl & 7, ni = tl >> 3;

  __shared__ __align__(16) char lds[2][65536];

  int tid = threadIdx.x;
  int lane = tid & 63, wid = tid >> 6;
  int wr = wid >> 2, wc = wid & 3;
  int fr = lane & 15, fb = lane >> 4;

  const bf16* Asrc = A  + (size_t)(mi * 256) * K;
  const bf16* Bsrc = Bm + (size_t)(ni * 256) * K;

  int NT = K >> 6;

#define STGQ(buf, kk, h, is)                                               \
  {                                                                        \
    int ri  = (is) * 64 + (tid >> 3);                                      \
    int ck  = (tid & 7) ^ (ri & 7);                                        \
    int row = (h) * 128 + ri;                                              \
    GL2LDS(Asrc + (size_t)row * K + (kk) + ck * 8,                         \
           lds[buf] + (h) * 16384 + (is) * 8192 + tid * 16);               \
    GL2LDS(Bsrc + (size_t)row * K + (kk) + ck * 8,                         \
           lds[buf] + 32768 + (h) * 16384 + (is) * 8192 + tid * 16);       \
  }

  f32x4 acc[8][4];
#pragma unroll
  for (int i = 0; i < 8; ++i)
#pragma unroll
    for (int j = 0; j < 4; ++j) acc[i][j] = (f32x4){0.f, 0.f, 0.f, 0.f};

  STGQ(0, 0, 0, 0); STGQ(0, 0, 0, 1); STGQ(0, 0, 1, 0); STGQ(0, 0, 1, 1);

  for (int t = 0; t < NT; ++t) {
    int buf = t & 1;
    int nk  = (t + 1) << 6;
    bool pf = (t + 1 < NT);

    if (pf) {
      STGQ(buf ^ 1, nk, 0, 0);
      asm volatile("s_waitcnt vmcnt(2)" ::: "memory");
    } else {
      asm volatile("s_waitcnt vmcnt(0)" ::: "memory");
    }
    __builtin_amdgcn_s_barrier();
    asm volatile("" ::: "memory");

    const char* Ab = lds[buf];
    const char* Bb = lds[buf] + 32768;

    bf16x8 bfr[4][2];
#pragma unroll
    for (int n2 = 0; n2 < 4; ++n2) {
      int row = wc * 64 + n2 * 16 + fr;
#pragma unroll
      for (int ks = 0; ks < 2; ++ks)
        bfr[n2][ks] = *(const bf16x8*)(Bb + (row >> 7) * 16384 + (row & 127) * 128
                                          + ((((ks * 4 + fb) ^ (fr & 7))) << 4));
    }

#pragma unroll
    for (int q = 0; q < 4; ++q) {
      bf16x8 af[2][2];
#pragma unroll
      for (int m2 = 0; m2 < 2; ++m2) {
        int ri = (q * 2 + m2) * 16 + fr;
#pragma unroll
        for (int ks = 0; ks < 2; ++ks)
          af[m2][ks] = *(const bf16x8*)(Ab + wr * 16384 + ri * 128
                                           + ((((ks * 4 + fb) ^ (fr & 7))) << 4));
      }
      __builtin_amdgcn_s_setprio(1);
#pragma unroll
      for (int m2 = 0; m2 < 2; ++m2)
#pragma unroll
        for (int n2 = 0; n2 < 4; ++n2)
#pragma unroll
          for (int ks = 0; ks < 2; ++ks)
            acc[q * 2 + m2][n2] = __builtin_amdgcn_mfma_f32_16x16x32_bf16(
                af[m2][ks], bfr[n2][ks], acc[q * 2 + m2][n2], 0, 0, 0);
      __builtin_amdgcn_s_setprio(0);
      if (pf && q == 0) STGQ(buf ^ 1, nk, 0, 1);
      if (pf && q == 1) STGQ(buf ^ 1, nk, 1, 0);
      if (pf && q == 2) STGQ(buf ^ 1, nk, 1, 1);
    }
    asm volatile("" ::: "memory");
    __builtin_amdgcn_s_barrier();
  }
#undef STGQ

#pragma unroll
  for (int i = 0; i < 8; ++i) {
#pragma unroll
    for (int j = 0; j < 4; ++j) {
      int gc = ni * 256 + wc * 64 + j * 16 + fr;
      float bv = bi[gc];
#pragma unroll
      for (int r = 0; r < 4; ++r) {
        int gr = mi * 256 + wr * 128 + i * 16 + fb * 4 + r;
        C[(size_t)gr * N + gc] = acc[i][j][r] + bv;
      }
    }
  }
}

// ---------------------------------------------------------------- attention (bf16 MFMA flash)
// Double-buffered K/V, T14 issue-early/write-late, ONE barrier per tile.
// Per tile kt: QK^T(buf) -> issue K-DMA(kt+1)+V-reg loads(kt+1) -> softmax
// -> PV(buf) -> vmcnt(0) -> V scatter-write(buf^1) -> __syncthreads.
// Safety: buf^1's readers (tile kt-1) finished before the syncthreads at
// top of kt; __syncthreads drains lgkm (ds_writes visible) + collectivizes
// each wave's vmcnt(0) (its K-DMA arrived). P buffer is wave-local.
__global__ __launch_bounds__(256) void attn_kernel(
    const bf16* __restrict__ q, const bf16* __restrict__ k,
    const bf16* __restrict__ v, float* __restrict__ x)
{
  __shared__ __align__(16) char Ks[2][8192];
  __shared__ __align__(16) char Vs[2][8192];
  __shared__ __align__(16) char Ps[8192];

  int tid = threadIdx.x, lane = tid & 63, w = tid >> 6;
  int qt = (int)gridDim.x - 1 - (int)blockIdx.x;   // heavy first
  int bh = blockIdx.y;
  int b = bh >> 4, h = bh & 15;
  size_t hoff = (size_t)b * T_ * E_ + h * HS_;
  int fr = lane & 15, fb = lane >> 4;

  // K staging constants (per thread)
  const int kc_c0  = tid >> 3;                  // row within 32-row half
  const int kc_key = ((kc_c0 & 7) ^ (kc_c0 >> 3)) & 7;  // for is=0 row c0
  // V staging constants
  const int v_row = tid >> 2;
  const int v_d0  = (tid & 3) * 8;

#define STAGE_K(bufi, kt_)                                                  \
  {                                                                         \
    const bf16* kbase = k + hoff + (size_t)((kt_) * 64) * E_;               \
    _Pragma("unroll")                                                       \
    for (int is = 0; is < 2; ++is) {                                        \
      int c = is * 32 + kc_c0;                                              \
      int key = ((c & 7) ^ (c >> 3)) & 7;                                   \
      GL2LDS(kbase + (size_t)c * E_ + (((tid & 7) ^ key) * 8),              \
             Ks[bufi] + is * 4096 + tid * 16);                              \
    }                                                                       \
  }
#define LOAD_V(kt_)                                                         \
  {                                                                         \
    const bf16* vbase = v + hoff + (size_t)((kt_) * 64 + v_row) * E_;       \
    vv0 = *(const bf16x8*)(vbase + v_d0);                                   \
    vv1 = *(const bf16x8*)(vbase + v_d0 + 32);                              \
  }
#define WRITE_V(bufi)                                                       \
  {                                                                         \
    _Pragma("unroll")                                                       \
    for (int p = 0; p < 2; ++p) {                                           \
      bf16x8 vvp = p ? vv1 : vv0;                                           \
      _Pragma("unroll")                                                     \
      for (int e = 0; e < 8; ++e) {                                         \
        int d = v_d0 + p * 32 + e;                                          \
        int key = ((d & 7) ^ (d >> 3)) & 7;                                 \
        *(bf16*)(Vs[bufi] + d * 128 + ((v_row * 2) ^ (key << 4))) = vvp[e]; \
      }                                                                     \
    }                                                                       \
  }

  bf16x8 qa[2];
  {
    const bf16* qp = q + hoff + (size_t)(qt * 64 + w * 16 + fr) * E_ + fb * 8;
    qa[0] = *(const bf16x8*)qp;
    qa[1] = *(const bf16x8*)(qp + 32);
  }

  f32x4 O[4];
  float m_[4], l_[4];
#pragma unroll
  for (int i = 0; i < 4; ++i) { O[i] = (f32x4){0.f,0.f,0.f,0.f}; m_[i] = -1e30f; l_[i] = 0.f; }

  bf16x8 vv0, vv1;

  // prologue: stage tile 0 into buf 0
  STAGE_K(0, 0);
  LOAD_V(0);
  asm volatile("s_waitcnt vmcnt(0)" ::: "memory");
  WRITE_V(0);
  __syncthreads();

  for (int kt = 0; kt <= qt; ++kt) {
    int buf = kt & 1;
    bool pf = (kt < qt);

    // --- S = Q K^T from Ks[buf]
    f32x4 s[4];
#pragma unroll
    for (int jc = 0; jc < 4; ++jc) {
      s[jc] = (f32x4){0.f, 0.f, 0.f, 0.f};
#pragma unroll
      for (int kc = 0; kc < 2; ++kc) {
        int c = jc * 16 + fr;
        int key = ((c & 7) ^ (c >> 3)) & 7;
        bf16x8 kf = *(const bf16x8*)(Ks[buf] + c * 128 + ((kc * 64 + fb * 16) ^ (key << 4)));
        s[jc] = __builtin_amdgcn_mfma_f32_16x16x32_bf16(qa[kc], kf, s[jc], 0, 0, 0);
      }
    }

    // --- issue next tile's loads early (hide under softmax+PV)
    if (pf) {
      STAGE_K(buf ^ 1, kt + 1);
      LOAD_V(kt + 1);
    }

    // --- online softmax, P write (per-wave LDS region)
    char* pbase = Ps + w * 2048;
#pragma unroll
    for (int r = 0; r < 4; ++r) {
      float s0 = s[0][r] * SCALE_, s1 = s[1][r] * SCALE_;
      float s2 = s[2][r] * SCALE_, s3 = s[3][r] * SCALE_;
      int qrow = qt * 64 + w * 16 + fb * 4 + r;
      if (kt == qt) {
        int kc0 = kt * 64 + fr;
        if (kc0      > qrow) s0 = -1e30f;
        if (kc0 + 16 > qrow) s1 = -1e30f;
        if (kc0 + 32 > qrow) s2 = -1e30f;
        if (kc0 + 48 > qrow) s3 = -1e30f;
      }
      float mx = fmaxf(fmaxf(s0, s1), fmaxf(s2, s3));
      mx = fmaxf(mx, __shfl_xor(mx, 1, 16));
      mx = fmaxf(mx, __shfl_xor(mx, 2, 16));
      mx = fmaxf(mx, __shfl_xor(mx, 4, 16));
      mx = fmaxf(mx, __shfl_xor(mx, 8, 16));
      float mnew = fmaxf(m_[r], mx);
      float p0 = __expf(s0 - mnew), p1 = __expf(s1 - mnew);
      float p2 = __expf(s2 - mnew), p3 = __expf(s3 - mnew);
      float rs = p0 + p1 + p2 + p3;
      rs += __shfl_xor(rs, 1, 16);
      rs += __shfl_xor(rs, 2, 16);
      rs += __shfl_xor(rs, 4, 16);
      rs += __shfl_xor(rs, 8, 16);
      float scl = __expf(m_[r] - mnew);
      l_[r] = l_[r] * scl + rs;
      m_[r] = mnew;
#pragma unroll
      for (int jd = 0; jd < 4; ++jd) O[jd][r] *= scl;
      int key2 = (r << 4) ^ (fb << 5);
      char* pr_ = pbase + (fb * 4 + r) * 128;
      *(bf16*)(pr_ + (( 0 + fr * 2) ^ key2)) = (bf16)p0;
      *(bf16*)(pr_ + ((32 + fr * 2) ^ key2)) = (bf16)p1;
      *(bf16*)(pr_ + ((64 + fr * 2) ^ key2)) = (bf16)p2;
      *(bf16*)(pr_ + ((96 + fr * 2) ^ key2)) = (bf16)p3;
    }

    // --- O += P V from Vs[buf]
#pragma unroll
    for (int kc = 0; kc < 2; ++kc) {
      int key2 = ((fr & 3) << 4) ^ ((fr >> 2) << 5);
      bf16x8 pa = *(const bf16x8*)(pbase + fr * 128 + ((kc * 64 + fb * 16) ^ key2));
#pragma unroll
      for (int jd = 0; jd < 4; ++jd) {
        int d = jd * 16 + fr;
        int key = ((d & 7) ^ (d >> 3)) & 7;
        bf16x8 vf = *(const bf16x8*)(Vs[buf] + d * 128 + ((kc * 64 + fb * 16) ^ (key << 4)));
        O[jd] = __builtin_amdgcn_mfma_f32_16x16x32_bf16(pa, vf, O[jd], 0, 0, 0);
      }
    }

    // --- land next tile: V regs arrived (and our K-DMA), scatter V, sync
    if (pf) {
      asm volatile("s_waitcnt vmcnt(0)" ::: "memory");
      WRITE_V(buf ^ 1);
    }
    __syncthreads();
  }
#undef STAGE_K
#undef LOAD_V
#undef WRITE_V

#pragma unroll
  for (int r = 0; r < 4; ++r) {
    float inv = 1.0f / l_[r];
    float* xp = x + hoff + (size_t)(qt * 64 + w * 16 + fb * 4 + r) * E_;
#pragma unroll
    for (int jd = 0; jd < 4; ++jd) {
      int d = jd * 16 + fr;
      xp[d] += O[jd][r] * inv;
    }
  }
}

// ---------------------------------------------------------------- launch
extern "C" void kernel_launch(void* const* d_in, const int* in_sizes, int n_in,
                              void* d_out, int out_size, void* d_ws, size_t ws_size,
                              hipStream_t stream)
{
  const int*   ids  = (const int*)  d_in[0];
  const float* emb  = (const float*)d_in[1];
  const float* pos  = (const float*)d_in[2];
  const float* wq   = (const float*)d_in[3];
  const float* bq   = (const float*)d_in[4];
  const float* wk   = (const float*)d_in[5];
  const float* bk   = (const float*)d_in[6];
  const float* wv   = (const float*)d_in[7];
  const float* bv   = (const float*)d_in[8];
  const float* w1   = (const float*)d_in[9];
  const float* b1   = (const float*)d_in[10];
  const float* w2   = (const float*)d_in[11];
  const float* b2   = (const float*)d_in[12];
  const float* ln1g = (const float*)d_in[13];
  const float* ln1b = (const float*)d_in[14];
  const float* ln2g = (const float*)d_in[15];
  const float* ln2b = (const float*)d_in[16];
  const float* pw   = (const float*)d_in[17];
  const float* pb   = (const float*)d_in[18];
  float* out = (float*)d_out;

  // ws layout (f32 units), non-overlapping in time (round-10-proven):
  //   x   [ 0M,  2M)  f32  BTxE
  //   hb  [ 2M,  3M)  bf16 BTxE      } fp [2M,6M) aliases hb..vb
  //   qb  [ 3M,  4M)  bf16 BTxE      }   (dead at FFN2 time)
  //   kb  [ 4M,  5M)  bf16 BTxE
  //   vb  [ 5M,  6M)  bf16 BTxE
  //   ffb [ 6M, 10M)  bf16 BTxFF
  //   lwb [10M,15.5M) bf16 layer weights
  //   hb2 [15.5M,16M) bf16 BTxE  (combine_ln output; dead at proj time)
  //   xb  [16M, 17M)  bf16 BTxE
  //   pwb [ 0M,15.625M) bf16 proj weight (all below dead at proj time)
  if (ws_size < (size_t)17 * 1024 * 1024 * 4) return;
  float* ws = (float*)d_ws;
  float* x   = ws;
  bf16*  hb  = (bf16*)(ws + (size_t) 2 * 1024 * 1024);
  bf16*  qb  = (bf16*)(ws + (size_t) 3 * 1024 * 1024);
  bf16*  kb  = (bf16*)(ws + (size_t) 4 * 1024 * 1024);
  bf16*  vb  = (bf16*)(ws + (size_t) 5 * 1024 * 1024);
  bf16*  ffb = (bf16*)(ws + (size_t) 6 * 1024 * 1024);
  float* fp  = ws + (size_t)2 * 1024 * 1024;
  bf16*  lwb = (bf16*)(ws + (size_t)10 * 1024 * 1024);
  bf16*  hb2 = (bf16*)(ws + (size_t)15 * 1024 * 1024 + 512 * 1024);
  bf16*  xb  = (bf16*)(ws + (size_t)16 * 1024 * 1024);
  bf16*  pwb = (bf16*)ws;
  bf16*  wqt = lwb;
  bf16*  wkt = lwb + (size_t)1 * 1024 * 1024;
  bf16*  wvt = lwb + (size_t)2 * 1024 * 1024;
  bf16*  w1t = lwb + (size_t)3 * 1024 * 1024;
  bf16*  w2t = lwb + (size_t)7 * 1024 * 1024;

  embed_ln_kernel<<<BT_, 256, 0, stream>>>(ids, emb, pos, ln1g, ln1b, x, hb);

  for (int l = 0; l < L_; ++l) {
    const size_t lEE = (size_t)l * E_ * E_;
    const size_t lEF = (size_t)l * E_ * FF_;
    const bf16* hcur = (l == 0) ? hb : hb2;

    convw_all<<<11264, 256, 0, stream>>>(
        wq + lEE, wk + lEE, wv + lEE, w1 + lEF, w2 + lEF,
        wqt, wkt, wvt, w1t, w2t);

    gemm_bf16<0,1><<<dim3(16, E_/128, 3), 256, 0, stream>>>(
        hcur, wqt, wkt, wvt, bq + l*E_, bk + l*E_, bv + l*E_,
        qb, kb, vb, nullptr, E_, E_, E_);

    attn_kernel<<<dim3(T_/64, B_*H_), 256, 0, stream>>>(qb, kb, vb, x);

    ln_kernel<<<BT_, 256, 0, stream>>>(x, ln2g + l*E_, ln2b + l*E_, hb);

    gemm_bf16<1,1><<<dim3(16, FF_/128, 1), 256, 0, stream>>>(
        hb, w1t, nullptr, nullptr, b1 + (size_t)l*FF_, nullptr, nullptr,
        ffb, nullptr, nullptr, nullptr, E_, FF_, E_);

    gemm_bf16<0,3><<<dim3(16, E_/128, 2), 256, 0, stream>>>(
        ffb, w2t, nullptr, nullptr, nullptr, nullptr, nullptr,
        nullptr, nullptr, nullptr, fp, FF_/2, E_, FF_);
    if (l < L_ - 1) {
      combine_ln_kernel<<<BT_, 256, 0, stream>>>(
          fp, b2 + l*E_, ln1g + (l+1)*E_, ln1b + (l+1)*E_, x, hb2);
    } else {
      combine_kernel<<<BT_, 256, 0, stream>>>(fp, b2 + l*E_, x, xb);
    }
  }

  // final projection: whole weight converted, 256^2 BK=64 4-phase GEMM
  convw_kernel<<<dim3(V_/32, E_/32), 256, 0, stream>>>(pw, pwb, E_, V_);
  gemm256_kernel<<<(V_/256) * 8, 512, 0, stream>>>(
      xb, pwb, pb, out, E_, V_);
}

// Round 13
// 804.774 us; speedup vs baseline: 2.1809x; 1.0022x over previous
//
#include <hip/hip_runtime.h>
#include <hip/hip_bf16.h>
#include <cstdint>

#define B_    2
#define T_    1024
#define E_    1024
#define H_    16
#define HS_   64
#define L_    4
#define V_    32000
#define FF_   4096
#define BT_   2048
#define EPS_  1e-5f
#define SCALE_ 0.03125f   // 1/sqrt(E) = 1/32

typedef __bf16 bf16;
typedef bf16  bf16x4 __attribute__((ext_vector_type(4)));
typedef bf16  bf16x8 __attribute__((ext_vector_type(8)));
typedef float f32x4  __attribute__((ext_vector_type(4)));

#define GL2LDS(gp, lp) __builtin_amdgcn_global_load_lds( \
    (const __attribute__((address_space(1))) void*)(gp), \
    (__attribute__((address_space(3))) void*)(lp), 16, 0, 0)

// ---------------------------------------------------------------- layernorm helper
__device__ __forceinline__ float wred_sum(float v) {
#pragma unroll
  for (int o = 32; o; o >>= 1) v += __shfl_xor(v, o, 64);
  return v;
}

__device__ __forceinline__ void ln_body(
    f32x4 v, const float* g, const float* b, bf16* h, size_t off, int tid)
{
  float s  = v[0] + v[1] + v[2] + v[3];
  float sq = v[0]*v[0] + v[1]*v[1] + v[2]*v[2] + v[3]*v[3];
  s  = wred_sum(s);
  sq = wred_sum(sq);
  __shared__ float rs[4], rq[4];
  int w = tid >> 6, lane = tid & 63;
  if (lane == 0) { rs[w] = s; rq[w] = sq; }
  __syncthreads();
  float S = rs[0] + rs[1] + rs[2] + rs[3];
  float Q = rq[0] + rq[1] + rq[2] + rq[3];
  float mean = S * (1.0f / E_);
  float var  = Q * (1.0f / E_) - mean * mean;
  float rstd = rsqrtf(fmaxf(var, 0.0f) + EPS_);
  f32x4 gv = *(const f32x4*)(g + tid * 4);
  f32x4 bv = *(const f32x4*)(b + tid * 4);
  f32x4 o = (v - mean) * rstd * gv + bv;
  bf16x4 ob = { (bf16)o[0], (bf16)o[1], (bf16)o[2], (bf16)o[3] };
  *(bf16x4*)(h + off) = ob;
}

// ---------------------------------------------------------------- embed + ln1(layer0) fused
__global__ __launch_bounds__(256) void embed_ln_kernel(
    const int* __restrict__ ids, const float* __restrict__ emb,
    const float* __restrict__ pos, const float* __restrict__ g,
    const float* __restrict__ b, float* __restrict__ x, bf16* __restrict__ h)
{
  int bt = blockIdx.x, tid = threadIdx.x;
  int t  = bt & (T_ - 1);
  int id = ids[bt];
  f32x4 e = *(const f32x4*)(emb + (size_t)id * E_ + tid * 4);
  f32x4 p = *(const f32x4*)(pos + (size_t)t  * E_ + tid * 4);
  f32x4 v = e + p;
  size_t off = (size_t)bt * E_ + tid * 4;
  *(f32x4*)(x + off) = v;
  ln_body(v, g, b, h, off, tid);
}

// ---------------------------------------------------------------- layernorm (f32 in, bf16 out)
__global__ __launch_bounds__(256) void ln_kernel(
    const float* __restrict__ x, const float* __restrict__ g,
    const float* __restrict__ b, bf16* __restrict__ h)
{
  int row = blockIdx.x, tid = threadIdx.x;
  size_t off = (size_t)row * E_ + tid * 4;
  f32x4 v = *(const f32x4*)(x + off);
  ln_body(v, g, b, h, off, tid);
}

// ---------------------------------------------------------------- weight transpose+convert (proj)
// W [K][N] f32 (row stride ldW) -> O [N][K] bf16. Store phase: one bf16x4
// per thread (k-quad), 8B aligned stores, same 64B/8-lane coalescing as the
// old 2B-store version but 4x fewer/wider stores.
__global__ __launch_bounds__(256) void convw_kernel(
    const float* __restrict__ W0, bf16* __restrict__ O0, int K, int ldW)
{
  __shared__ float tl[32][33];
  int n0 = blockIdx.x * 32, k0 = blockIdx.y * 32;
  int c = threadIdx.x & 31, r = threadIdx.x >> 5;
#pragma unroll
  for (int p = 0; p < 4; ++p)
    tl[r + p * 8][c] = W0[(size_t)(k0 + r + p * 8) * ldW + n0 + c];
  __syncthreads();
  int n2 = threadIdx.x >> 3, kq = threadIdx.x & 7;
  bf16x4 ov = { (bf16)tl[kq * 4 + 0][n2], (bf16)tl[kq * 4 + 1][n2],
                (bf16)tl[kq * 4 + 2][n2], (bf16)tl[kq * 4 + 3][n2] };
  *(bf16x4*)(O0 + (size_t)(n0 + n2) * K + k0 + kq * 4) = ov;
}

// ---------------------------------------------------------------- fused per-layer weight convert
__global__ __launch_bounds__(256) void convw_all(
    const float* __restrict__ wq, const float* __restrict__ wk,
    const float* __restrict__ wv, const float* __restrict__ w1,
    const float* __restrict__ w2,
    bf16* __restrict__ oq, bf16* __restrict__ ok, bf16* __restrict__ ov,
    bf16* __restrict__ o1, bf16* __restrict__ o2)
{
  int bid = blockIdx.x;
  const float* W; bf16* O; int K, ldW, nx, ny;
  if (bid < 3072) {
    int z = bid >> 10, rem = bid & 1023;
    W = (z == 0) ? wq : (z == 1) ? wk : wv;
    O = (z == 0) ? oq : (z == 1) ? ok : ov;
    K = 1024; ldW = 1024; nx = rem & 31; ny = rem >> 5;
  } else if (bid < 7168) {
    int idx = bid - 3072;
    W = w1; O = o1; K = 1024; ldW = 4096;
    nx = idx & 127; ny = idx >> 7;
  } else {
    int idx = bid - 7168;
    W = w2; O = o2; K = 4096; ldW = 1024;
    nx = idx & 31; ny = idx >> 5;
  }
  __shared__ float tl[32][33];
  int n0 = nx * 32, k0 = ny * 32;
  int c = threadIdx.x & 31, r = threadIdx.x >> 5;
#pragma unroll
  for (int p = 0; p < 4; ++p)
    tl[r + p * 8][c] = W[(size_t)(k0 + r + p * 8) * ldW + n0 + c];
  __syncthreads();
  int n2 = threadIdx.x >> 3, kq = threadIdx.x & 7;
  bf16x4 ovv = { (bf16)tl[kq * 4 + 0][n2], (bf16)tl[kq * 4 + 1][n2],
                 (bf16)tl[kq * 4 + 2][n2], (bf16)tl[kq * 4 + 3][n2] };
  *(bf16x4*)(O + (size_t)(n0 + n2) * K + k0 + kq * 4) = ovv;
}

// ---------------------------------------------------------------- GEMM bf16 MFMA 128x128 (r11-proven)
template <int ACT, int MODE>
__global__ __launch_bounds__(256) void gemm_bf16(
    const bf16* __restrict__ A,
    const bf16* __restrict__ B0, const bf16* __restrict__ B1, const bf16* __restrict__ B2,
    const float* __restrict__ bi0, const float* __restrict__ bi1, const float* __restrict__ bi2,
    bf16* __restrict__ Cb0, bf16* __restrict__ Cb1, bf16* __restrict__ Cb2,
    float* __restrict__ Cf,
    int K, int ldc, int LDK)
{
  int z = blockIdx.z;
  const bf16*  Bm = (MODE == 3) ? B0 : (z == 0) ? B0 : (z == 1) ? B1 : B2;
  const float* bi = (z == 0) ? bi0 : (z == 1) ? bi1 : bi2;
  bf16*        Cb = (z == 0) ? Cb0 : (z == 1) ? Cb1 : Cb2;
  int koff = (MODE == 3) ? z * K : 0;

  int nb  = (int)(gridDim.x * gridDim.y);
  int lin = blockIdx.x + gridDim.x * blockIdx.y;
  int per = nb >> 3;
  int b   = (lin & 7) * per + (lin >> 3);
  int mi  = b & 15;
  int ni  = b >> 4;

  __shared__ __align__(16) char lds[2][16384];

  int tid = threadIdx.x;
  int lane = tid & 63, wid = tid >> 6;
  int wm = (wid >> 1) * 64, wn = (wid & 1) * 64;
  int fr = lane & 15, fb = lane >> 4;

  const bf16* Asrc = A  + (size_t)(mi * 128) * LDK + koff;
  const bf16* Bsrc = Bm + (size_t)(ni * 128) * LDK + koff;

  int NT = K >> 5;

#define STAGE_U(buf, kk, is)                                                \
  {                                                                         \
    int rl = (is) * 64 + (tid >> 2);                                        \
    int key = (rl >> 1) & 3;                                                \
    int ck  = ((tid & 3) ^ key) * 8;                                        \
    GL2LDS(Asrc + (size_t)rl * LDK + (kk) + ck,                             \
           lds[buf] + (is) * 4096 + tid * 16);                              \
    GL2LDS(Bsrc + (size_t)rl * LDK + (kk) + ck,                             \
           lds[buf] + 8192 + (is) * 4096 + tid * 16);                       \
  }

  f32x4 acc[4][4];
#pragma unroll
  for (int i = 0; i < 4; ++i)
#pragma unroll
    for (int j = 0; j < 4; ++j) acc[i][j] = (f32x4){0.f, 0.f, 0.f, 0.f};

  STAGE_U(0, 0, 0);
  STAGE_U(0, 0, 1);

  for (int t = 0; t < NT; ++t) {
    int buf = t & 1;
    int nk  = (t + 1) << 5;
    bool pf = (t + 1 < NT);

    if (pf) {
      STAGE_U(buf ^ 1, nk, 0);
      asm volatile("s_waitcnt vmcnt(2)" ::: "memory");
    } else {
      asm volatile("s_waitcnt vmcnt(0)" ::: "memory");
    }
    __builtin_amdgcn_s_barrier();
    asm volatile("" ::: "memory");

    const char* Ab = lds[buf];
    const char* Bb = lds[buf] + 8192;
    bf16x8 af[4], bfr[4];
#pragma unroll
    for (int i = 0; i < 4; ++i) {
      int rl = wm + i * 16 + fr;
      af[i] = *(const bf16x8*)(Ab + rl * 64 + ((fb ^ ((rl >> 1) & 3)) * 16));
    }
#pragma unroll
    for (int j = 0; j < 4; ++j) {
      int rl = wn + j * 16 + fr;
      bfr[j] = *(const bf16x8*)(Bb + rl * 64 + ((fb ^ ((rl >> 1) & 3)) * 16));
    }
    __builtin_amdgcn_s_setprio(1);
#pragma unroll
    for (int i = 0; i < 2; ++i)
#pragma unroll
      for (int j = 0; j < 4; ++j)
        acc[i][j] = __builtin_amdgcn_mfma_f32_16x16x32_bf16(af[i], bfr[j], acc[i][j], 0, 0, 0);
    __builtin_amdgcn_s_setprio(0);
    if (pf) STAGE_U(buf ^ 1, nk, 1);
    __builtin_amdgcn_s_setprio(1);
#pragma unroll
    for (int i = 2; i < 4; ++i)
#pragma unroll
      for (int j = 0; j < 4; ++j)
        acc[i][j] = __builtin_amdgcn_mfma_f32_16x16x32_bf16(af[i], bfr[j], acc[i][j], 0, 0, 0);
    __builtin_amdgcn_s_setprio(0);
    asm volatile("" ::: "memory");
    __builtin_amdgcn_s_barrier();
  }
#undef STAGE_U

#pragma unroll
  for (int i = 0; i < 4; ++i) {
#pragma unroll
    for (int j = 0; j < 4; ++j) {
      int gc = ni * 128 + wn + j * 16 + fr;
      float bv = (MODE == 3) ? 0.f : bi[gc];
#pragma unroll
      for (int r = 0; r < 4; ++r) {
        int gr = mi * 128 + wm + i * 16 + fb * 4 + r;
        float vv = acc[i][j][r] + bv;
        if (ACT == 1) vv = 0.5f * vv * (1.0f + erff(vv * 0.70710678118654752f));
        if (MODE == 1) {
          Cb[(size_t)gr * ldc + gc] = (bf16)vv;
        } else {
          Cf[(size_t)(blockIdx.z * BT_ + gr) * ldc + gc] = vv;
        }
      }
    }
  }
}

// ---------------------------------------------------------------- FFN2 split-K combine (last layer)
__global__ __launch_bounds__(256) void combine_kernel(
    const float* __restrict__ p, const float* __restrict__ bi,
    float* __restrict__ x, bf16* __restrict__ xb)
{
  int row = blockIdx.x, tid = threadIdx.x;
  size_t off = (size_t)row * E_ + tid * 4;
  f32x4 a = *(const f32x4*)(p + off);
  f32x4 c = *(const f32x4*)(p + (size_t)BT_ * E_ + off);
  f32x4 bv = *(const f32x4*)(bi + tid * 4);
  f32x4 xv = *(const f32x4*)(x + off);
  f32x4 nv = xv + a + c + bv;
  *(f32x4*)(x + off) = nv;
  bf16x4 ob = { (bf16)nv[0], (bf16)nv[1], (bf16)nv[2], (bf16)nv[3] };
  *(bf16x4*)(xb + off) = ob;
}

// ---------------------------------------------------------------- combine + next-layer ln1 fused
__global__ __launch_bounds__(256) void combine_ln_kernel(
    const float* __restrict__ p, const float* __restrict__ bi,
    const float* __restrict__ g, const float* __restrict__ b,
    float* __restrict__ x, bf16* __restrict__ h)
{
  int row = blockIdx.x, tid = threadIdx.x;
  size_t off = (size_t)row * E_ + tid * 4;
  f32x4 a = *(const f32x4*)(p + off);
  f32x4 c = *(const f32x4*)(p + (size_t)BT_ * E_ + off);
  f32x4 bv = *(const f32x4*)(bi + tid * 4);
  f32x4 xv = *(const f32x4*)(x + off);
  f32x4 nv = xv + a + c + bv;
  *(f32x4*)(x + off) = nv;
  ln_body(nv, g, b, h, off, tid);
}

// ---------------------------------------------------------------- GEMM bf16 MFMA 256x256, BK=64
// (round-8 proven version, 157us / 35.5% MfmaUtil) — unchanged.
__global__ __launch_bounds__(512, 2) void gemm256_kernel(
    const bf16* __restrict__ A, const bf16* __restrict__ Bm,
    const float* __restrict__ bi, float* __restrict__ C, int K, int N)
{
  int nwg = (int)gridDim.x;
  int per = nwg >> 3;
  int bid = (int)blockIdx.x;
  int tl  = (bid & 7) * per + (bid >> 3);
  int mi  = tl & 7, ni = tl >> 3;

  __shared__ __align__(16) char lds[2][65536];

  int tid = threadIdx.x;
  int lane = tid & 63, wid = tid >> 6;
  int wr = wid >> 2, wc = wid & 3;
  int fr = lane & 15, fb = lane >> 4;

  const bf16* Asrc = A  + (size_t)(mi * 256) * K;
  const bf16* Bsrc = Bm + (size_t)(ni * 256) * K;

  int NT = K >> 6;

#define STGQ(buf, kk, h, is)                                               \
  {                                                                        \
    int ri  = (is) * 64 + (tid >> 3);                                      \
    int ck  = (tid & 7) ^ (ri & 7);                                        \
    int row = (h) * 128 + ri;                                              \
    GL2LDS(Asrc + (size_t)row * K + (kk) + ck * 8,                         \
           lds[buf] + (h) * 16384 + (is) * 8192 + tid * 16);               \
    GL2LDS(Bsrc + (size_t)row * K + (kk) + ck * 8,                         \
           lds[buf] + 32768 + (h) * 16384 + (is) * 8192 + tid * 16);       \
  }

  f32x4 acc[8][4];
#pragma unroll
  for (int i = 0; i < 8; ++i)
#pragma unroll
    for (int j = 0; j < 4; ++j) acc[i][j] = (f32x4){0.f, 0.f, 0.f, 0.f};

  STGQ(0, 0, 0, 0); STGQ(0, 0, 0, 1); STGQ(0, 0, 1, 0); STGQ(0, 0, 1, 1);

  for (int t = 0; t < NT; ++t) {
    int buf = t & 1;
    int nk  = (t + 1) << 6;
    bool pf = (t + 1 < NT);

    if (pf) {
      STGQ(buf ^ 1, nk, 0, 0);
      asm volatile("s_waitcnt vmcnt(2)" ::: "memory");
    } else {
      asm volatile("s_waitcnt vmcnt(0)" ::: "memory");
    }
    __builtin_amdgcn_s_barrier();
    asm volatile("" ::: "memory");

    const char* Ab = lds[buf];
    const char* Bb = lds[buf] + 32768;

    bf16x8 bfr[4][2];
#pragma unroll
    for (int n2 = 0; n2 < 4; ++n2) {
      int row = wc * 64 + n2 * 16 + fr;
#pragma unroll
      for (int ks = 0; ks < 2; ++ks)
        bfr[n2][ks] = *(const bf16x8*)(Bb + (row >> 7) * 16384 + (row & 127) * 128
                                          + ((((ks * 4 + fb) ^ (fr & 7))) << 4));
    }

#pragma unroll
    for (int q = 0; q < 4; ++q) {
      bf16x8 af[2][2];
#pragma unroll
      for (int m2 = 0; m2 < 2; ++m2) {
        int ri = (q * 2 + m2) * 16 + fr;
#pragma unroll
        for (int ks = 0; ks < 2; ++ks)
          af[m2][ks] = *(const bf16x8*)(Ab + wr * 16384 + ri * 128
                                           + ((((ks * 4 + fb) ^ (fr & 7))) << 4));
      }
      __builtin_amdgcn_s_setprio(1);
#pragma unroll
      for (int m2 = 0; m2 < 2; ++m2)
#pragma unroll
        for (int n2 = 0; n2 < 4; ++n2)
#pragma unroll
          for (int ks = 0; ks < 2; ++ks)
            acc[q * 2 + m2][n2] = __builtin_amdgcn_mfma_f32_16x16x32_bf16(
                af[m2][ks], bfr[n2][ks], acc[q * 2 + m2][n2], 0, 0, 0);
      __builtin_amdgcn_s_setprio(0);
      if (pf && q == 0) STGQ(buf ^ 1, nk, 0, 1);
      if (pf && q == 1) STGQ(buf ^ 1, nk, 1, 0);
      if (pf && q == 2) STGQ(buf ^ 1, nk, 1, 1);
    }
    asm volatile("" ::: "memory");
    __builtin_amdgcn_s_barrier();
  }
#undef STGQ

#pragma unroll
  for (int i = 0; i < 8; ++i) {
#pragma unroll
    for (int j = 0; j < 4; ++j) {
      int gc = ni * 256 + wc * 64 + j * 16 + fr;
      float bv = bi[gc];
#pragma unroll
      for (int r = 0; r < 4; ++r) {
        int gr = mi * 256 + wr * 128 + i * 16 + fb * 4 + r;
        C[(size_t)gr * N + gc] = acc[i][j][r] + bv;
      }
    }
  }
}

// ---------------------------------------------------------------- attention (bf16 MFMA flash)
// r12-proven double-buffered K/V, T14 issue-early/write-late, one barrier
// per tile; + setprio around the MFMA clusters (m191: attn-specific win).
__global__ __launch_bounds__(256) void attn_kernel(
    const bf16* __restrict__ q, const bf16* __restrict__ k,
    const bf16* __restrict__ v, float* __restrict__ x)
{
  __shared__ __align__(16) char Ks[2][8192];
  __shared__ __align__(16) char Vs[2][8192];
  __shared__ __align__(16) char Ps[8192];

  int tid = threadIdx.x, lane = tid & 63, w = tid >> 6;
  int qt = (int)gridDim.x - 1 - (int)blockIdx.x;   // heavy first
  int bh = blockIdx.y;
  int b = bh >> 4, h = bh & 15;
  size_t hoff = (size_t)b * T_ * E_ + h * HS_;
  int fr = lane & 15, fb = lane >> 4;

  const int kc_c0 = tid >> 3;
  const int v_row = tid >> 2;
  const int v_d0  = (tid & 3) * 8;

#define STAGE_K(bufi, kt_)                                                  \
  {                                                                         \
    const bf16* kbase = k + hoff + (size_t)((kt_) * 64) * E_;               \
    _Pragma("unroll")                                                       \
    for (int is = 0; is < 2; ++is) {                                        \
      int c = is * 32 + kc_c0;                                              \
      int key = ((c & 7) ^ (c >> 3)) & 7;                                   \
      GL2LDS(kbase + (size_t)c * E_ + (((tid & 7) ^ key) * 8),              \
             Ks[bufi] + is * 4096 + tid * 16);                              \
    }                                                                       \
  }
#define LOAD_V(kt_)                                                         \
  {                                                                         \
    const bf16* vbase = v + hoff + (size_t)((kt_) * 64 + v_row) * E_;       \
    vv0 = *(const bf16x8*)(vbase + v_d0);                                   \
    vv1 = *(const bf16x8*)(vbase + v_d0 + 32);                              \
  }
#define WRITE_V(bufi)                                                       \
  {                                                                         \
    _Pragma("unroll")                                                       \
    for (int p = 0; p < 2; ++p) {                                           \
      bf16x8 vvp = p ? vv1 : vv0;                                           \
      _Pragma("unroll")                                                     \
      for (int e = 0; e < 8; ++e) {                                         \
        int d = v_d0 + p * 32 + e;                                          \
        int key = ((d & 7) ^ (d >> 3)) & 7;                                 \
        *(bf16*)(Vs[bufi] + d * 128 + ((v_row * 2) ^ (key << 4))) = vvp[e]; \
      }                                                                     \
    }                                                                       \
  }

  bf16x8 qa[2];
  {
    const bf16* qp = q + hoff + (size_t)(qt * 64 + w * 16 + fr) * E_ + fb * 8;
    qa[0] = *(const bf16x8*)qp;
    qa[1] = *(const bf16x8*)(qp + 32);
  }

  f32x4 O[4];
  float m_[4], l_[4];
#pragma unroll
  for (int i = 0; i < 4; ++i) { O[i] = (f32x4){0.f,0.f,0.f,0.f}; m_[i] = -1e30f; l_[i] = 0.f; }

  bf16x8 vv0, vv1;

  STAGE_K(0, 0);
  LOAD_V(0);
  asm volatile("s_waitcnt vmcnt(0)" ::: "memory");
  WRITE_V(0);
  __syncthreads();

  for (int kt = 0; kt <= qt; ++kt) {
    int buf = kt & 1;
    bool pf = (kt < qt);

    // --- S = Q K^T from Ks[buf]
    f32x4 s[4];
    __builtin_amdgcn_s_setprio(1);
#pragma unroll
    for (int jc = 0; jc < 4; ++jc) {
      s[jc] = (f32x4){0.f, 0.f, 0.f, 0.f};
#pragma unroll
      for (int kc = 0; kc < 2; ++kc) {
        int c = jc * 16 + fr;
        int key = ((c & 7) ^ (c >> 3)) & 7;
        bf16x8 kf = *(const bf16x8*)(Ks[buf] + c * 128 + ((kc * 64 + fb * 16) ^ (key << 4)));
        s[jc] = __builtin_amdgcn_mfma_f32_16x16x32_bf16(qa[kc], kf, s[jc], 0, 0, 0);
      }
    }
    __builtin_amdgcn_s_setprio(0);

    // --- issue next tile's loads early (hide under softmax+PV)
    if (pf) {
      STAGE_K(buf ^ 1, kt + 1);
      LOAD_V(kt + 1);
    }

    // --- online softmax, P write (per-wave LDS region)
    char* pbase = Ps + w * 2048;
#pragma unroll
    for (int r = 0; r < 4; ++r) {
      float s0 = s[0][r] * SCALE_, s1 = s[1][r] * SCALE_;
      float s2 = s[2][r] * SCALE_, s3 = s[3][r] * SCALE_;
      int qrow = qt * 64 + w * 16 + fb * 4 + r;
      if (kt == qt) {
        int kc0 = kt * 64 + fr;
        if (kc0      > qrow) s0 = -1e30f;
        if (kc0 + 16 > qrow) s1 = -1e30f;
        if (kc0 + 32 > qrow) s2 = -1e30f;
        if (kc0 + 48 > qrow) s3 = -1e30f;
      }
      float mx = fmaxf(fmaxf(s0, s1), fmaxf(s2, s3));
      mx = fmaxf(mx, __shfl_xor(mx, 1, 16));
      mx = fmaxf(mx, __shfl_xor(mx, 2, 16));
      mx = fmaxf(mx, __shfl_xor(mx, 4, 16));
      mx = fmaxf(mx, __shfl_xor(mx, 8, 16));
      float mnew = fmaxf(m_[r], mx);
      float p0 = __expf(s0 - mnew), p1 = __expf(s1 - mnew);
      float p2 = __expf(s2 - mnew), p3 = __expf(s3 - mnew);
      float rs = p0 + p1 + p2 + p3;
      rs += __shfl_xor(rs, 1, 16);
      rs += __shfl_xor(rs, 2, 16);
      rs += __shfl_xor(rs, 4, 16);
      rs += __shfl_xor(rs, 8, 16);
      float scl = __expf(m_[r] - mnew);
      l_[r] = l_[r] * scl + rs;
      m_[r] = mnew;
#pragma unroll
      for (int jd = 0; jd < 4; ++jd) O[jd][r] *= scl;
      int key2 = (r << 4) ^ (fb << 5);
      char* pr_ = pbase + (fb * 4 + r) * 128;
      *(bf16*)(pr_ + (( 0 + fr * 2) ^ key2)) = (bf16)p0;
      *(bf16*)(pr_ + ((32 + fr * 2) ^ key2)) = (bf16)p1;
      *(bf16*)(pr_ + ((64 + fr * 2) ^ key2)) = (bf16)p2;
      *(bf16*)(pr_ + ((96 + fr * 2) ^ key2)) = (bf16)p3;
    }

    // --- O += P V from Vs[buf]
    __builtin_amdgcn_s_setprio(1);
#pragma unroll
    for (int kc = 0; kc < 2; ++kc) {
      int key2 = ((fr & 3) << 4) ^ ((fr >> 2) << 5);
      bf16x8 pa = *(const bf16x8*)(pbase + fr * 128 + ((kc * 64 + fb * 16) ^ key2));
#pragma unroll
      for (int jd = 0; jd < 4; ++jd) {
        int d = jd * 16 + fr;
        int key = ((d & 7) ^ (d >> 3)) & 7;
        bf16x8 vf = *(const bf16x8*)(Vs[buf] + d * 128 + ((kc * 64 + fb * 16) ^ (key << 4)));
        O[jd] = __builtin_amdgcn_mfma_f32_16x16x32_bf16(pa, vf, O[jd], 0, 0, 0);
      }
    }
    __builtin_amdgcn_s_setprio(0);

    if (pf) {
      asm volatile("s_waitcnt vmcnt(0)" ::: "memory");
      WRITE_V(buf ^ 1);
    }
    __syncthreads();
  }
#undef STAGE_K
#undef LOAD_V
#undef WRITE_V

#pragma unroll
  for (int r = 0; r < 4; ++r) {
    float inv = 1.0f / l_[r];
    float* xp = x + hoff + (size_t)(qt * 64 + w * 16 + fb * 4 + r) * E_;
#pragma unroll
    for (int jd = 0; jd < 4; ++jd) {
      int d = jd * 16 + fr;
      xp[d] += O[jd][r] * inv;
    }
  }
}

// ---------------------------------------------------------------- launch
extern "C" void kernel_launch(void* const* d_in, const int* in_sizes, int n_in,
                              void* d_out, int out_size, void* d_ws, size_t ws_size,
                              hipStream_t stream)
{
  const int*   ids  = (const int*)  d_in[0];
  const float* emb  = (const float*)d_in[1];
  const float* pos  = (const float*)d_in[2];
  const float* wq   = (const float*)d_in[3];
  const float* bq   = (const float*)d_in[4];
  const float* wk   = (const float*)d_in[5];
  const float* bk   = (const float*)d_in[6];
  const float* wv   = (const float*)d_in[7];
  const float* bv   = (const float*)d_in[8];
  const float* w1   = (const float*)d_in[9];
  const float* b1   = (const float*)d_in[10];
  const float* w2   = (const float*)d_in[11];
  const float* b2   = (const float*)d_in[12];
  const float* ln1g = (const float*)d_in[13];
  const float* ln1b = (const float*)d_in[14];
  const float* ln2g = (const float*)d_in[15];
  const float* ln2b = (const float*)d_in[16];
  const float* pw   = (const float*)d_in[17];
  const float* pb   = (const float*)d_in[18];
  float* out = (float*)d_out;

  // ws layout (f32 units), non-overlapping in time (round-10-proven):
  //   x   [ 0M,  2M)  f32  BTxE
  //   hb  [ 2M,  3M)  bf16 BTxE      } fp [2M,6M) aliases hb..vb
  //   qb  [ 3M,  4M)  bf16 BTxE      }   (dead at FFN2 time)
  //   kb  [ 4M,  5M)  bf16 BTxE
  //   vb  [ 5M,  6M)  bf16 BTxE
  //   ffb [ 6M, 10M)  bf16 BTxFF
  //   lwb [10M,15.5M) bf16 layer weights
  //   hb2 [15.5M,16M) bf16 BTxE  (combine_ln output; dead at proj time)
  //   xb  [16M, 17M)  bf16 BTxE
  //   pwb [ 0M,15.625M) bf16 proj weight (all below dead at proj time)
  if (ws_size < (size_t)17 * 1024 * 1024 * 4) return;
  float* ws = (float*)d_ws;
  float* x   = ws;
  bf16*  hb  = (bf16*)(ws + (size_t) 2 * 1024 * 1024);
  bf16*  qb  = (bf16*)(ws + (size_t) 3 * 1024 * 1024);
  bf16*  kb  = (bf16*)(ws + (size_t) 4 * 1024 * 1024);
  bf16*  vb  = (bf16*)(ws + (size_t) 5 * 1024 * 1024);
  bf16*  ffb = (bf16*)(ws + (size_t) 6 * 1024 * 1024);
  float* fp  = ws + (size_t)2 * 1024 * 1024;
  bf16*  lwb = (bf16*)(ws + (size_t)10 * 1024 * 1024);
  bf16*  hb2 = (bf16*)(ws + (size_t)15 * 1024 * 1024 + 512 * 1024);
  bf16*  xb  = (bf16*)(ws + (size_t)16 * 1024 * 1024);
  bf16*  pwb = (bf16*)ws;
  bf16*  wqt = lwb;
  bf16*  wkt = lwb + (size_t)1 * 1024 * 1024;
  bf16*  wvt = lwb + (size_t)2 * 1024 * 1024;
  bf16*  w1t = lwb + (size_t)3 * 1024 * 1024;
  bf16*  w2t = lwb + (size_t)7 * 1024 * 1024;

  embed_ln_kernel<<<BT_, 256, 0, stream>>>(ids, emb, pos, ln1g, ln1b, x, hb);

  for (int l = 0; l < L_; ++l) {
    const size_t lEE = (size_t)l * E_ * E_;
    const size_t lEF = (size_t)l * E_ * FF_;
    const bf16* hcur = (l == 0) ? hb : hb2;

    convw_all<<<11264, 256, 0, stream>>>(
        wq + lEE, wk + lEE, wv + lEE, w1 + lEF, w2 + lEF,
        wqt, wkt, wvt, w1t, w2t);

    gemm_bf16<0,1><<<dim3(16, E_/128, 3), 256, 0, stream>>>(
        hcur, wqt, wkt, wvt, bq + l*E_, bk + l*E_, bv + l*E_,
        qb, kb, vb, nullptr, E_, E_, E_);

    attn_kernel<<<dim3(T_/64, B_*H_), 256, 0, stream>>>(qb, kb, vb, x);

    ln_kernel<<<BT_, 256, 0, stream>>>(x, ln2g + l*E_, ln2b + l*E_, hb);

    gemm_bf16<1,1><<<dim3(16, FF_/128, 1), 256, 0, stream>>>(
        hb, w1t, nullptr, nullptr, b1 + (size_t)l*FF_, nullptr, nullptr,
        ffb, nullptr, nullptr, nullptr, E_, FF_, E_);

    gemm_bf16<0,3><<<dim3(16, E_/128, 2), 256, 0, stream>>>(
        ffb, w2t, nullptr, nullptr, nullptr, nullptr, nullptr,
        nullptr, nullptr, nullptr, fp, FF_/2, E_, FF_);
    if (l < L_ - 1) {
      combine_ln_kernel<<<BT_, 256, 0, stream>>>(
          fp, b2 + l*E_, ln1g + (l+1)*E_, ln1b + (l+1)*E_, x, hb2);
    } else {
      combine_kernel<<<BT_, 256, 0, stream>>>(fp, b2 + l*E_, x, xb);
    }
  }

  // final projection: whole weight converted, 256^2 BK=64 4-phase GEMM
  convw_kernel<<<dim3(V_/32, E_/32), 256, 0, stream>>>(pw, pwb, E_, V_);
  gemm256_kernel<<<(V_/256) * 8, 512, 0, stream>>>(
      xb, pwb, pb, out, E_, V_);
}

// Round 14
// 797.065 us; speedup vs baseline: 2.2020x; 1.0097x over previous
//
#include <hip/hip_runtime.h>
#include <hip/hip_bf16.h>
#include <cstdint>

#define B_    2
#define T_    1024
#define E_    1024
#define H_    16
#define HS_   64
#define L_    4
#define V_    32000
#define FF_   4096
#define BT_   2048
#define EPS_  1e-5f
#define SCALE_ 0.03125f   // 1/sqrt(E) = 1/32

typedef __bf16 bf16;
typedef bf16  bf16x4 __attribute__((ext_vector_type(4)));
typedef bf16  bf16x8 __attribute__((ext_vector_type(8)));
typedef float f32x4  __attribute__((ext_vector_type(4)));

#define GL2LDS(gp, lp) __builtin_amdgcn_global_load_lds( \
    (const __attribute__((address_space(1))) void*)(gp), \
    (__attribute__((address_space(3))) void*)(lp), 16, 0, 0)

// ---------------------------------------------------------------- layernorm helper
__device__ __forceinline__ float wred_sum(float v) {
#pragma unroll
  for (int o = 32; o; o >>= 1) v += __shfl_xor(v, o, 64);
  return v;
}

__device__ __forceinline__ void ln_body(
    f32x4 v, const float* g, const float* b, bf16* h, size_t off, int tid)
{
  float s  = v[0] + v[1] + v[2] + v[3];
  float sq = v[0]*v[0] + v[1]*v[1] + v[2]*v[2] + v[3]*v[3];
  s  = wred_sum(s);
  sq = wred_sum(sq);
  __shared__ float rs[4], rq[4];
  int w = tid >> 6, lane = tid & 63;
  if (lane == 0) { rs[w] = s; rq[w] = sq; }
  __syncthreads();
  float S = rs[0] + rs[1] + rs[2] + rs[3];
  float Q = rq[0] + rq[1] + rq[2] + rq[3];
  float mean = S * (1.0f / E_);
  float var  = Q * (1.0f / E_) - mean * mean;
  float rstd = rsqrtf(fmaxf(var, 0.0f) + EPS_);
  f32x4 gv = *(const f32x4*)(g + tid * 4);
  f32x4 bv = *(const f32x4*)(b + tid * 4);
  f32x4 o = (v - mean) * rstd * gv + bv;
  bf16x4 ob = { (bf16)o[0], (bf16)o[1], (bf16)o[2], (bf16)o[3] };
  *(bf16x4*)(h + off) = ob;
}

// ---------------------------------------------------------------- embed + ln1(layer0) fused
__global__ __launch_bounds__(256) void embed_ln_kernel(
    const int* __restrict__ ids, const float* __restrict__ emb,
    const float* __restrict__ pos, const float* __restrict__ g,
    const float* __restrict__ b, float* __restrict__ x, bf16* __restrict__ h)
{
  int bt = blockIdx.x, tid = threadIdx.x;
  int t  = bt & (T_ - 1);
  int id = ids[bt];
  f32x4 e = *(const f32x4*)(emb + (size_t)id * E_ + tid * 4);
  f32x4 p = *(const f32x4*)(pos + (size_t)t  * E_ + tid * 4);
  f32x4 v = e + p;
  size_t off = (size_t)bt * E_ + tid * 4;
  *(f32x4*)(x + off) = v;
  ln_body(v, g, b, h, off, tid);
}

// ---------------------------------------------------------------- layernorm (f32 in, bf16 out)
__global__ __launch_bounds__(256) void ln_kernel(
    const float* __restrict__ x, const float* __restrict__ g,
    const float* __restrict__ b, bf16* __restrict__ h)
{
  int row = blockIdx.x, tid = threadIdx.x;
  size_t off = (size_t)row * E_ + tid * 4;
  f32x4 v = *(const f32x4*)(x + off);
  ln_body(v, g, b, h, off, tid);
}

// ---------------------------------------------------------------- weight transpose+convert (proj)
__global__ __launch_bounds__(256) void convw_kernel(
    const float* __restrict__ W0, bf16* __restrict__ O0, int K, int ldW)
{
  __shared__ float tl[32][33];
  int n0 = blockIdx.x * 32, k0 = blockIdx.y * 32;
  int c = threadIdx.x & 31, r = threadIdx.x >> 5;
#pragma unroll
  for (int p = 0; p < 4; ++p)
    tl[r + p * 8][c] = W0[(size_t)(k0 + r + p * 8) * ldW + n0 + c];
  __syncthreads();
  int n2 = threadIdx.x >> 3, kq = threadIdx.x & 7;
  bf16x4 ov = { (bf16)tl[kq * 4 + 0][n2], (bf16)tl[kq * 4 + 1][n2],
                (bf16)tl[kq * 4 + 2][n2], (bf16)tl[kq * 4 + 3][n2] };
  *(bf16x4*)(O0 + (size_t)(n0 + n2) * K + k0 + kq * 4) = ov;
}

// ---------------------------------------------------------------- fused per-layer weight convert
__global__ __launch_bounds__(256) void convw_all(
    const float* __restrict__ wq, const float* __restrict__ wk,
    const float* __restrict__ wv, const float* __restrict__ w1,
    const float* __restrict__ w2,
    bf16* __restrict__ oq, bf16* __restrict__ ok, bf16* __restrict__ ov,
    bf16* __restrict__ o1, bf16* __restrict__ o2)
{
  int bid = blockIdx.x;
  const float* W; bf16* O; int K, ldW, nx, ny;
  if (bid < 3072) {
    int z = bid >> 10, rem = bid & 1023;
    W = (z == 0) ? wq : (z == 1) ? wk : wv;
    O = (z == 0) ? oq : (z == 1) ? ok : ov;
    K = 1024; ldW = 1024; nx = rem & 31; ny = rem >> 5;
  } else if (bid < 7168) {
    int idx = bid - 3072;
    W = w1; O = o1; K = 1024; ldW = 4096;
    nx = idx & 127; ny = idx >> 7;
  } else {
    int idx = bid - 7168;
    W = w2; O = o2; K = 4096; ldW = 1024;
    nx = idx & 31; ny = idx >> 5;
  }
  __shared__ float tl[32][33];
  int n0 = nx * 32, k0 = ny * 32;
  int c = threadIdx.x & 31, r = threadIdx.x >> 5;
#pragma unroll
  for (int p = 0; p < 4; ++p)
    tl[r + p * 8][c] = W[(size_t)(k0 + r + p * 8) * ldW + n0 + c];
  __syncthreads();
  int n2 = threadIdx.x >> 3, kq = threadIdx.x & 7;
  bf16x4 ovv = { (bf16)tl[kq * 4 + 0][n2], (bf16)tl[kq * 4 + 1][n2],
                 (bf16)tl[kq * 4 + 2][n2], (bf16)tl[kq * 4 + 3][n2] };
  *(bf16x4*)(O + (size_t)(n0 + n2) * K + k0 + kq * 4) = ovv;
}

// ---------------------------------------------------------------- GEMM bf16 MFMA 128x128 (r11-proven)
// MODE 1: bf16 out (+bias, opt GELU). MODE 3: bf16 split-K partial (blockIdx.z).
template <int ACT, int MODE>
__global__ __launch_bounds__(256) void gemm_bf16(
    const bf16* __restrict__ A,
    const bf16* __restrict__ B0, const bf16* __restrict__ B1, const bf16* __restrict__ B2,
    const float* __restrict__ bi0, const float* __restrict__ bi1, const float* __restrict__ bi2,
    bf16* __restrict__ Cb0, bf16* __restrict__ Cb1, bf16* __restrict__ Cb2,
    int K, int ldc, int LDK)
{
  int z = blockIdx.z;
  const bf16*  Bm = (MODE == 3) ? B0 : (z == 0) ? B0 : (z == 1) ? B1 : B2;
  const float* bi = (z == 0) ? bi0 : (z == 1) ? bi1 : bi2;
  bf16*        Cb = (MODE == 3) ? Cb0 : (z == 0) ? Cb0 : (z == 1) ? Cb1 : Cb2;
  int koff = (MODE == 3) ? z * K : 0;

  int nb  = (int)(gridDim.x * gridDim.y);
  int lin = blockIdx.x + gridDim.x * blockIdx.y;
  int per = nb >> 3;
  int b   = (lin & 7) * per + (lin >> 3);
  int mi  = b & 15;
  int ni  = b >> 4;

  __shared__ __align__(16) char lds[2][16384];

  int tid = threadIdx.x;
  int lane = tid & 63, wid = tid >> 6;
  int wm = (wid >> 1) * 64, wn = (wid & 1) * 64;
  int fr = lane & 15, fb = lane >> 4;

  const bf16* Asrc = A  + (size_t)(mi * 128) * LDK + koff;
  const bf16* Bsrc = Bm + (size_t)(ni * 128) * LDK + koff;

  int NT = K >> 5;

#define STAGE_U(buf, kk, is)                                                \
  {                                                                         \
    int rl = (is) * 64 + (tid >> 2);                                        \
    int key = (rl >> 1) & 3;                                                \
    int ck  = ((tid & 3) ^ key) * 8;                                        \
    GL2LDS(Asrc + (size_t)rl * LDK + (kk) + ck,                             \
           lds[buf] + (is) * 4096 + tid * 16);                              \
    GL2LDS(Bsrc + (size_t)rl * LDK + (kk) + ck,                             \
           lds[buf] + 8192 + (is) * 4096 + tid * 16);                       \
  }

  f32x4 acc[4][4];
#pragma unroll
  for (int i = 0; i < 4; ++i)
#pragma unroll
    for (int j = 0; j < 4; ++j) acc[i][j] = (f32x4){0.f, 0.f, 0.f, 0.f};

  STAGE_U(0, 0, 0);
  STAGE_U(0, 0, 1);

  for (int t = 0; t < NT; ++t) {
    int buf = t & 1;
    int nk  = (t + 1) << 5;
    bool pf = (t + 1 < NT);

    if (pf) {
      STAGE_U(buf ^ 1, nk, 0);
      asm volatile("s_waitcnt vmcnt(2)" ::: "memory");
    } else {
      asm volatile("s_waitcnt vmcnt(0)" ::: "memory");
    }
    __builtin_amdgcn_s_barrier();
    asm volatile("" ::: "memory");

    const char* Ab = lds[buf];
    const char* Bb = lds[buf] + 8192;
    bf16x8 af[4], bfr[4];
#pragma unroll
    for (int i = 0; i < 4; ++i) {
      int rl = wm + i * 16 + fr;
      af[i] = *(const bf16x8*)(Ab + rl * 64 + ((fb ^ ((rl >> 1) & 3)) * 16));
    }
#pragma unroll
    for (int j = 0; j < 4; ++j) {
      int rl = wn + j * 16 + fr;
      bfr[j] = *(const bf16x8*)(Bb + rl * 64 + ((fb ^ ((rl >> 1) & 3)) * 16));
    }
    __builtin_amdgcn_s_setprio(1);
#pragma unroll
    for (int i = 0; i < 2; ++i)
#pragma unroll
      for (int j = 0; j < 4; ++j)
        acc[i][j] = __builtin_amdgcn_mfma_f32_16x16x32_bf16(af[i], bfr[j], acc[i][j], 0, 0, 0);
    __builtin_amdgcn_s_setprio(0);
    if (pf) STAGE_U(buf ^ 1, nk, 1);
    __builtin_amdgcn_s_setprio(1);
#pragma unroll
    for (int i = 2; i < 4; ++i)
#pragma unroll
      for (int j = 0; j < 4; ++j)
        acc[i][j] = __builtin_amdgcn_mfma_f32_16x16x32_bf16(af[i], bfr[j], acc[i][j], 0, 0, 0);
    __builtin_amdgcn_s_setprio(0);
    asm volatile("" ::: "memory");
    __builtin_amdgcn_s_barrier();
  }
#undef STAGE_U

  // epilogue: C/D layout col = lane&15, row = (lane>>4)*4 + reg
#pragma unroll
  for (int i = 0; i < 4; ++i) {
#pragma unroll
    for (int j = 0; j < 4; ++j) {
      int gc = ni * 128 + wn + j * 16 + fr;
      float bv = (MODE == 3) ? 0.f : bi[gc];
#pragma unroll
      for (int r = 0; r < 4; ++r) {
        int gr = mi * 128 + wm + i * 16 + fb * 4 + r;
        float vv = acc[i][j][r] + bv;
        if (ACT == 1) vv = 0.5f * vv * (1.0f + erff(vv * 0.70710678118654752f));
        if (MODE == 1) {
          Cb[(size_t)gr * ldc + gc] = (bf16)vv;
        } else {
          Cb[(size_t)(blockIdx.z * BT_ + gr) * ldc + gc] = (bf16)vv;
        }
      }
    }
  }
}

// ---------------------------------------------------------------- FFN2 split-K combine (last layer)
// x += p0 + p1 + bias ; xb = bf16(x)   (partials now bf16)
__global__ __launch_bounds__(256) void combine_kernel(
    const bf16* __restrict__ p, const float* __restrict__ bi,
    float* __restrict__ x, bf16* __restrict__ xb)
{
  int row = blockIdx.x, tid = threadIdx.x;
  size_t off = (size_t)row * E_ + tid * 4;
  bf16x4 a4 = *(const bf16x4*)(p + off);
  bf16x4 c4 = *(const bf16x4*)(p + (size_t)BT_ * E_ + off);
  f32x4 bv = *(const f32x4*)(bi + tid * 4);
  f32x4 xv = *(const f32x4*)(x + off);
  f32x4 nv;
#pragma unroll
  for (int e = 0; e < 4; ++e)
    nv[e] = xv[e] + (float)a4[e] + (float)c4[e] + bv[e];
  *(f32x4*)(x + off) = nv;
  bf16x4 ob = { (bf16)nv[0], (bf16)nv[1], (bf16)nv[2], (bf16)nv[3] };
  *(bf16x4*)(xb + off) = ob;
}

// ---------------------------------------------------------------- combine + next-layer ln1 fused
__global__ __launch_bounds__(256) void combine_ln_kernel(
    const bf16* __restrict__ p, const float* __restrict__ bi,
    const float* __restrict__ g, const float* __restrict__ b,
    float* __restrict__ x, bf16* __restrict__ h)
{
  int row = blockIdx.x, tid = threadIdx.x;
  size_t off = (size_t)row * E_ + tid * 4;
  bf16x4 a4 = *(const bf16x4*)(p + off);
  bf16x4 c4 = *(const bf16x4*)(p + (size_t)BT_ * E_ + off);
  f32x4 bv = *(const f32x4*)(bi + tid * 4);
  f32x4 xv = *(const f32x4*)(x + off);
  f32x4 nv;
#pragma unroll
  for (int e = 0; e < 4; ++e)
    nv[e] = xv[e] + (float)a4[e] + (float)c4[e] + bv[e];
  *(f32x4*)(x + off) = nv;
  ln_body(nv, g, b, h, off, tid);
}

// ---------------------------------------------------------------- GEMM bf16 MFMA 256x256, BK=64
// (round-8 proven version, ~155us / 35.5% MfmaUtil) — unchanged.
__global__ __launch_bounds__(512, 2) void gemm256_kernel(
    const bf16* __restrict__ A, const bf16* __restrict__ Bm,
    const float* __restrict__ bi, float* __restrict__ C, int K, int N)
{
  int nwg = (int)gridDim.x;
  int per = nwg >> 3;
  int bid = (int)blockIdx.x;
  int tl  = (bid & 7) * per + (bid >> 3);
  int mi  = tl & 7, ni = tl >> 3;

  __shared__ __align__(16) char lds[2][65536];

  int tid = threadIdx.x;
  int lane = tid & 63, wid = tid >> 6;
  int wr = wid >> 2, wc = wid & 3;
  int fr = lane & 15, fb = lane >> 4;

  const bf16* Asrc = A  + (size_t)(mi * 256) * K;
  const bf16* Bsrc = Bm + (size_t)(ni * 256) * K;

  int NT = K >> 6;

#define STGQ(buf, kk, h, is)                                               \
  {                                                                        \
    int ri  = (is) * 64 + (tid >> 3);                                      \
    int ck  = (tid & 7) ^ (ri & 7);                                        \
    int row = (h) * 128 + ri;                                              \
    GL2LDS(Asrc + (size_t)row * K + (kk) + ck * 8,                         \
           lds[buf] + (h) * 16384 + (is) * 8192 + tid * 16);               \
    GL2LDS(Bsrc + (size_t)row * K + (kk) + ck * 8,                         \
           lds[buf] + 32768 + (h) * 16384 + (is) * 8192 + tid * 16);       \
  }

  f32x4 acc[8][4];
#pragma unroll
  for (int i = 0; i < 8; ++i)
#pragma unroll
    for (int j = 0; j < 4; ++j) acc[i][j] = (f32x4){0.f, 0.f, 0.f, 0.f};

  STGQ(0, 0, 0, 0); STGQ(0, 0, 0, 1); STGQ(0, 0, 1, 0); STGQ(0, 0, 1, 1);

  for (int t = 0; t < NT; ++t) {
    int buf = t & 1;
    int nk  = (t + 1) << 6;
    bool pf = (t + 1 < NT);

    if (pf) {
      STGQ(buf ^ 1, nk, 0, 0);
      asm volatile("s_waitcnt vmcnt(2)" ::: "memory");
    } else {
      asm volatile("s_waitcnt vmcnt(0)" ::: "memory");
    }
    __builtin_amdgcn_s_barrier();
    asm volatile("" ::: "memory");

    const char* Ab = lds[buf];
    const char* Bb = lds[buf] + 32768;

    bf16x8 bfr[4][2];
#pragma unroll
    for (int n2 = 0; n2 < 4; ++n2) {
      int row = wc * 64 + n2 * 16 + fr;
#pragma unroll
      for (int ks = 0; ks < 2; ++ks)
        bfr[n2][ks] = *(const bf16x8*)(Bb + (row >> 7) * 16384 + (row & 127) * 128
                                          + ((((ks * 4 + fb) ^ (fr & 7))) << 4));
    }

#pragma unroll
    for (int q = 0; q < 4; ++q) {
      bf16x8 af[2][2];
#pragma unroll
      for (int m2 = 0; m2 < 2; ++m2) {
        int ri = (q * 2 + m2) * 16 + fr;
#pragma unroll
        for (int ks = 0; ks < 2; ++ks)
          af[m2][ks] = *(const bf16x8*)(Ab + wr * 16384 + ri * 128
                                           + ((((ks * 4 + fb) ^ (fr & 7))) << 4));
      }
      __builtin_amdgcn_s_setprio(1);
#pragma unroll
      for (int m2 = 0; m2 < 2; ++m2)
#pragma unroll
        for (int n2 = 0; n2 < 4; ++n2)
#pragma unroll
          for (int ks = 0; ks < 2; ++ks)
            acc[q * 2 + m2][n2] = __builtin_amdgcn_mfma_f32_16x16x32_bf16(
                af[m2][ks], bfr[n2][ks], acc[q * 2 + m2][n2], 0, 0, 0);
      __builtin_amdgcn_s_setprio(0);
      if (pf && q == 0) STGQ(buf ^ 1, nk, 0, 1);
      if (pf && q == 1) STGQ(buf ^ 1, nk, 1, 0);
      if (pf && q == 2) STGQ(buf ^ 1, nk, 1, 1);
    }
    asm volatile("" ::: "memory");
    __builtin_amdgcn_s_barrier();
  }
#undef STGQ

#pragma unroll
  for (int i = 0; i < 8; ++i) {
#pragma unroll
    for (int j = 0; j < 4; ++j) {
      int gc = ni * 256 + wc * 64 + j * 16 + fr;
      float bv = bi[gc];
#pragma unroll
      for (int r = 0; r < 4; ++r) {
        int gr = mi * 256 + wr * 128 + i * 16 + fb * 4 + r;
        C[(size_t)gr * N + gc] = acc[i][j][r] + bv;
      }
    }
  }
}

// ---------------------------------------------------------------- attention (bf16 MFMA flash)
// r12/r13-proven: double-buffered K/V, T14 issue-early/write-late, one
// barrier per tile, setprio on MFMA clusters.
__global__ __launch_bounds__(256) void attn_kernel(
    const bf16* __restrict__ q, const bf16* __restrict__ k,
    const bf16* __restrict__ v, float* __restrict__ x)
{
  __shared__ __align__(16) char Ks[2][8192];
  __shared__ __align__(16) char Vs[2][8192];
  __shared__ __align__(16) char Ps[8192];

  int tid = threadIdx.x, lane = tid & 63, w = tid >> 6;
  int qt = (int)gridDim.x - 1 - (int)blockIdx.x;   // heavy first
  int bh = blockIdx.y;
  int b = bh >> 4, h = bh & 15;
  size_t hoff = (size_t)b * T_ * E_ + h * HS_;
  int fr = lane & 15, fb = lane >> 4;

  const int kc_c0 = tid >> 3;
  const int v_row = tid >> 2;
  const int v_d0  = (tid & 3) * 8;

#define STAGE_K(bufi, kt_)                                                  \
  {                                                                         \
    const bf16* kbase = k + hoff + (size_t)((kt_) * 64) * E_;               \
    _Pragma("unroll")                                                       \
    for (int is = 0; is < 2; ++is) {                                        \
      int c = is * 32 + kc_c0;                                              \
      int key = ((c & 7) ^ (c >> 3)) & 7;                                   \
      GL2LDS(kbase + (size_t)c * E_ + (((tid & 7) ^ key) * 8),              \
             Ks[bufi] + is * 4096 + tid * 16);                              \
    }                                                                       \
  }
#define LOAD_V(kt_)                                                         \
  {                                                                         \
    const bf16* vbase = v + hoff + (size_t)((kt_) * 64 + v_row) * E_;       \
    vv0 = *(const bf16x8*)(vbase + v_d0);                                   \
    vv1 = *(const bf16x8*)(vbase + v_d0 + 32);                              \
  }
#define WRITE_V(bufi)                                                       \
  {                                                                         \
    _Pragma("unroll")                                                       \
    for (int p = 0; p < 2; ++p) {                                           \
      bf16x8 vvp = p ? vv1 : vv0;                                           \
      _Pragma("unroll")                                                     \
      for (int e = 0; e < 8; ++e) {                                         \
        int d = v_d0 + p * 32 + e;                                          \
        int key = ((d & 7) ^ (d >> 3)) & 7;                                 \
        *(bf16*)(Vs[bufi] + d * 128 + ((v_row * 2) ^ (key << 4))) = vvp[e]; \
      }                                                                     \
    }                                                                       \
  }

  bf16x8 qa[2];
  {
    const bf16* qp = q + hoff + (size_t)(qt * 64 + w * 16 + fr) * E_ + fb * 8;
    qa[0] = *(const bf16x8*)qp;
    qa[1] = *(const bf16x8*)(qp + 32);
  }

  f32x4 O[4];
  float m_[4], l_[4];
#pragma unroll
  for (int i = 0; i < 4; ++i) { O[i] = (f32x4){0.f,0.f,0.f,0.f}; m_[i] = -1e30f; l_[i] = 0.f; }

  bf16x8 vv0, vv1;

  STAGE_K(0, 0);
  LOAD_V(0);
  asm volatile("s_waitcnt vmcnt(0)" ::: "memory");
  WRITE_V(0);
  __syncthreads();

  for (int kt = 0; kt <= qt; ++kt) {
    int buf = kt & 1;
    bool pf = (kt < qt);

    f32x4 s[4];
    __builtin_amdgcn_s_setprio(1);
#pragma unroll
    for (int jc = 0; jc < 4; ++jc) {
      s[jc] = (f32x4){0.f, 0.f, 0.f, 0.f};
#pragma unroll
      for (int kc = 0; kc < 2; ++kc) {
        int c = jc * 16 + fr;
        int key = ((c & 7) ^ (c >> 3)) & 7;
        bf16x8 kf = *(const bf16x8*)(Ks[buf] + c * 128 + ((kc * 64 + fb * 16) ^ (key << 4)));
        s[jc] = __builtin_amdgcn_mfma_f32_16x16x32_bf16(qa[kc], kf, s[jc], 0, 0, 0);
      }
    }
    __builtin_amdgcn_s_setprio(0);

    if (pf) {
      STAGE_K(buf ^ 1, kt + 1);
      LOAD_V(kt + 1);
    }

    char* pbase = Ps + w * 2048;
#pragma unroll
    for (int r = 0; r < 4; ++r) {
      float s0 = s[0][r] * SCALE_, s1 = s[1][r] * SCALE_;
      float s2 = s[2][r] * SCALE_, s3 = s[3][r] * SCALE_;
      int qrow = qt * 64 + w * 16 + fb * 4 + r;
      if (kt == qt) {
        int kc0 = kt * 64 + fr;
        if (kc0      > qrow) s0 = -1e30f;
        if (kc0 + 16 > qrow) s1 = -1e30f;
        if (kc0 + 32 > qrow) s2 = -1e30f;
        if (kc0 + 48 > qrow) s3 = -1e30f;
      }
      float mx = fmaxf(fmaxf(s0, s1), fmaxf(s2, s3));
      mx = fmaxf(mx, __shfl_xor(mx, 1, 16));
      mx = fmaxf(mx, __shfl_xor(mx, 2, 16));
      mx = fmaxf(mx, __shfl_xor(mx, 4, 16));
      mx = fmaxf(mx, __shfl_xor(mx, 8, 16));
      float mnew = fmaxf(m_[r], mx);
      float p0 = __expf(s0 - mnew), p1 = __expf(s1 - mnew);
      float p2 = __expf(s2 - mnew), p3 = __expf(s3 - mnew);
      float rs = p0 + p1 + p2 + p3;
      rs += __shfl_xor(rs, 1, 16);
      rs += __shfl_xor(rs, 2, 16);
      rs += __shfl_xor(rs, 4, 16);
      rs += __shfl_xor(rs, 8, 16);
      float scl = __expf(m_[r] - mnew);
      l_[r] = l_[r] * scl + rs;
      m_[r] = mnew;
#pragma unroll
      for (int jd = 0; jd < 4; ++jd) O[jd][r] *= scl;
      int key2 = (r << 4) ^ (fb << 5);
      char* pr_ = pbase + (fb * 4 + r) * 128;
      *(bf16*)(pr_ + (( 0 + fr * 2) ^ key2)) = (bf16)p0;
      *(bf16*)(pr_ + ((32 + fr * 2) ^ key2)) = (bf16)p1;
      *(bf16*)(pr_ + ((64 + fr * 2) ^ key2)) = (bf16)p2;
      *(bf16*)(pr_ + ((96 + fr * 2) ^ key2)) = (bf16)p3;
    }

    __builtin_amdgcn_s_setprio(1);
#pragma unroll
    for (int kc = 0; kc < 2; ++kc) {
      int key2 = ((fr & 3) << 4) ^ ((fr >> 2) << 5);
      bf16x8 pa = *(const bf16x8*)(pbase + fr * 128 + ((kc * 64 + fb * 16) ^ key2));
#pragma unroll
      for (int jd = 0; jd < 4; ++jd) {
        int d = jd * 16 + fr;
        int key = ((d & 7) ^ (d >> 3)) & 7;
        bf16x8 vf = *(const bf16x8*)(Vs[buf] + d * 128 + ((kc * 64 + fb * 16) ^ (key << 4)));
        O[jd] = __builtin_amdgcn_mfma_f32_16x16x32_bf16(pa, vf, O[jd], 0, 0, 0);
      }
    }
    __builtin_amdgcn_s_setprio(0);

    if (pf) {
      asm volatile("s_waitcnt vmcnt(0)" ::: "memory");
      WRITE_V(buf ^ 1);
    }
    __syncthreads();
  }
#undef STAGE_K
#undef LOAD_V
#undef WRITE_V

#pragma unroll
  for (int r = 0; r < 4; ++r) {
    float inv = 1.0f / l_[r];
    float* xp = x + hoff + (size_t)(qt * 64 + w * 16 + fb * 4 + r) * E_;
#pragma unroll
    for (int jd = 0; jd < 4; ++jd) {
      int d = jd * 16 + fr;
      xp[d] += O[jd][r] * inv;
    }
  }
}

// ---------------------------------------------------------------- launch
extern "C" void kernel_launch(void* const* d_in, const int* in_sizes, int n_in,
                              void* d_out, int out_size, void* d_ws, size_t ws_size,
                              hipStream_t stream)
{
  const int*   ids  = (const int*)  d_in[0];
  const float* emb  = (const float*)d_in[1];
  const float* pos  = (const float*)d_in[2];
  const float* wq   = (const float*)d_in[3];
  const float* bq   = (const float*)d_in[4];
  const float* wk   = (const float*)d_in[5];
  const float* bk   = (const float*)d_in[6];
  const float* wv   = (const float*)d_in[7];
  const float* bv   = (const float*)d_in[8];
  const float* w1   = (const float*)d_in[9];
  const float* b1   = (const float*)d_in[10];
  const float* w2   = (const float*)d_in[11];
  const float* b2   = (const float*)d_in[12];
  const float* ln1g = (const float*)d_in[13];
  const float* ln1b = (const float*)d_in[14];
  const float* ln2g = (const float*)d_in[15];
  const float* ln2b = (const float*)d_in[16];
  const float* pw   = (const float*)d_in[17];
  const float* pb   = (const float*)d_in[18];
  float* out = (float*)d_out;

  // ws layout (f32 units), non-overlapping in time:
  //   x   [ 0M,  2M)  f32  BTxE
  //   hb  [ 2M,  3M)  bf16 BTxE      } fpb [2M,4M) = 2 bf16 partials of
  //   qb  [ 3M,  4M)  bf16 BTxE      }   BTxE each (hb,qb dead at FFN2 time)
  //   kb  [ 4M,  5M)  bf16 BTxE
  //   vb  [ 5M,  6M)  bf16 BTxE
  //   ffb [ 6M, 10M)  bf16 BTxFF
  //   lwb [10M,15.5M) bf16 layer weights
  //   hb2 [15.5M,16M) bf16 BTxE  (combine_ln output; dead at proj time)
  //   xb  [16M, 17M)  bf16 BTxE
  //   pwb [ 0M,15.625M) bf16 proj weight (all below dead at proj time)
  if (ws_size < (size_t)17 * 1024 * 1024 * 4) return;
  float* ws = (float*)d_ws;
  float* x   = ws;
  bf16*  hb  = (bf16*)(ws + (size_t) 2 * 1024 * 1024);
  bf16*  qb  = (bf16*)(ws + (size_t) 3 * 1024 * 1024);
  bf16*  kb  = (bf16*)(ws + (size_t) 4 * 1024 * 1024);
  bf16*  vb  = (bf16*)(ws + (size_t) 5 * 1024 * 1024);
  bf16*  ffb = (bf16*)(ws + (size_t) 6 * 1024 * 1024);
  bf16*  fpb = (bf16*)(ws + (size_t)2 * 1024 * 1024);   // 2 bf16 partials
  bf16*  lwb = (bf16*)(ws + (size_t)10 * 1024 * 1024);
  bf16*  hb2 = (bf16*)(ws + (size_t)15 * 1024 * 1024 + 512 * 1024);
  bf16*  xb  = (bf16*)(ws + (size_t)16 * 1024 * 1024);
  bf16*  pwb = (bf16*)ws;
  bf16*  wqt = lwb;
  bf16*  wkt = lwb + (size_t)1 * 1024 * 1024;
  bf16*  wvt = lwb + (size_t)2 * 1024 * 1024;
  bf16*  w1t = lwb + (size_t)3 * 1024 * 1024;
  bf16*  w2t = lwb + (size_t)7 * 1024 * 1024;

  embed_ln_kernel<<<BT_, 256, 0, stream>>>(ids, emb, pos, ln1g, ln1b, x, hb);

  for (int l = 0; l < L_; ++l) {
    const size_t lEE = (size_t)l * E_ * E_;
    const size_t lEF = (size_t)l * E_ * FF_;
    const bf16* hcur = (l == 0) ? hb : hb2;

    convw_all<<<11264, 256, 0, stream>>>(
        wq + lEE, wk + lEE, wv + lEE, w1 + lEF, w2 + lEF,
        wqt, wkt, wvt, w1t, w2t);

    gemm_bf16<0,1><<<dim3(16, E_/128, 3), 256, 0, stream>>>(
        hcur, wqt, wkt, wvt, bq + l*E_, bk + l*E_, bv + l*E_,
        qb, kb, vb, E_, E_, E_);

    attn_kernel<<<dim3(T_/64, B_*H_), 256, 0, stream>>>(qb, kb, vb, x);

    ln_kernel<<<BT_, 256, 0, stream>>>(x, ln2g + l*E_, ln2b + l*E_, hb);

    gemm_bf16<1,1><<<dim3(16, FF_/128, 1), 256, 0, stream>>>(
        hb, w1t, nullptr, nullptr, b1 + (size_t)l*FF_, nullptr, nullptr,
        ffb, nullptr, nullptr, E_, FF_, E_);

    // FFN2: split-K=2 over blockIdx.z -> 256 blocks, bf16 partials, fused combine
    gemm_bf16<0,3><<<dim3(16, E_/128, 2), 256, 0, stream>>>(
        ffb, w2t, nullptr, nullptr, nullptr, nullptr, nullptr,
        fpb, nullptr, nullptr, FF_/2, E_, FF_);
    if (l < L_ - 1) {
      combine_ln_kernel<<<BT_, 256, 0, stream>>>(
          fpb, b2 + l*E_, ln1g + (l+1)*E_, ln1b + (l+1)*E_, x, hb2);
    } else {
      combine_kernel<<<BT_, 256, 0, stream>>>(fpb, b2 + l*E_, x, xb);
    }
  }

  // final projection: whole weight converted, 256^2 BK=64 4-phase GEMM
  convw_kernel<<<dim3(V_/32, E_/32), 256, 0, stream>>>(pw, pwb, E_, V_);
  gemm256_kernel<<<(V_/256) * 8, 512, 0, stream>>>(
      xb, pwb, pb, out, E_, V_);
}